// Round 10
// baseline (1108.236 us; speedup 1.0000x reference)
//
#include <hip/hip_runtime.h>
#include <math.h>

// ---- fixed problem dims ----
constexpr int Bb  = 16;
constexpr int Tt  = 16;
constexpr int Nn  = 196;   // patches (14x14)
constexpr int Cc  = 768;
constexpr int Aa  = 192;
constexpr int KK  = 8;     // TOPK
constexpr int NCAND = 16;  // fp32 candidates refined in f64
constexpr int BT  = Bb * Tt;            // 256
constexpr int BTN = BT * Nn;            // 50176
constexpr int BKT = Bb * KK * Tt;       // 2048 anchor-token rows
constexpr size_t SZ = (size_t)BTN * Aa; // 9,633,792 floats

typedef unsigned short ushortt;
typedef __attribute__((ext_vector_type(8))) short bf16x8;
typedef __attribute__((ext_vector_type(4))) float f32x4;
typedef __attribute__((ext_vector_type(4))) unsigned short u16x4;
typedef __attribute__((ext_vector_type(8))) unsigned short u16x8;

static __device__ __forceinline__ float gelu_f(float x) {
  return 0.5f * x * (1.0f + erff(x * 0.7071067811865476f));
}
static __device__ __forceinline__ ushortt f2bf(float f) {
  unsigned u = __float_as_uint(f);
  u += 0x7FFFu + ((u >> 16) & 1u);  // round-to-nearest-even
  return (ushortt)(u >> 16);
}
static __device__ __forceinline__ float bf2f(ushortt u) {
  return __uint_as_float(((unsigned)u) << 16);
}

// ---- weight pre-convert: all GEMM weights fp32 -> bf16, one kernel ----
constexpr int S_down   = Aa * Cc;        // 147456
constexpr int S_attnin = 3 * Aa * Aa;    // 110592
constexpr int S_sq     = Aa * Aa;        // 36864
constexpr int S_t      = 2 * Aa * Aa;    // 73728
constexpr int O1 = S_down;               // attn_in
constexpr int O2 = O1 + S_attnin;        // attn_out
constexpr int O3 = O2 + S_sq;            // aproj
constexpr int O4 = O3 + S_sq;            // lpw
constexpr int O5 = O4 + S_sq;            // tpw
constexpr int O6 = O5 + S_sq;            // tmlp1
constexpr int O7 = O6 + S_t;             // tmlp2
constexpr int O8 = O7 + S_t;             // up
constexpr int OTOT = O8 + S_down;        // 700416 (== 2736*256)

__global__ void cvtw_kernel(const float* __restrict__ w0,
                            const float* __restrict__ w1,
                            const float* __restrict__ w2,
                            const float* __restrict__ w3,
                            const float* __restrict__ w4,
                            const float* __restrict__ w5,
                            const float* __restrict__ w6,
                            const float* __restrict__ w7,
                            const float* __restrict__ w8,
                            ushortt* __restrict__ outw) {
  int e = blockIdx.x * 256 + threadIdx.x;
  const float* src;
  int off;
  if (e < O1)      { src = w0; off = 0;  }
  else if (e < O2) { src = w1; off = O1; }
  else if (e < O3) { src = w2; off = O2; }
  else if (e < O4) { src = w3; off = O3; }
  else if (e < O5) { src = w4; off = O4; }
  else if (e < O6) { src = w5; off = O5; }
  else if (e < O7) { src = w6; off = O6; }
  else if (e < O8) { src = w7; off = O7; }
  else             { src = w8; off = O8; }
  outw[e] = f2bf(src[e - off]);
}

// ============================================================
// LDS-free register GEMM for skinny N: C = A @ Wb^T (+bias)(+epi)
// 128 thr = 2 waves; BM=64 (32 rows/wave), BN=192 (12 n-frags).
// A/B MFMA fragments loaded DIRECT from global (16B/lane, 16 full
// 64B lines per wave); B (bf16 weights) is L2-resident. No barriers
// in the K-loop. LDS only for the coalesced epilogue.
// EPI: 0 plain, 1 gelu, 2 mapped residual fp32.
// Grid (Nc/192, M/64); col-fastest + bijective XCD swizzle (nwg%8==0).
// ============================================================
template <typename AT, typename CT, int ROWMAP, int BIAS, int EPI>
__global__ __launch_bounds__(128) void gemm_skinny(
    const AT* __restrict__ Ain, const ushortt* __restrict__ Wb,
    const float* __restrict__ bias, CT* __restrict__ Cout,
    const float* __restrict__ resid, int M, int Nc, int K) {
  constexpr int NF = 12;
  const int tid = threadIdx.x;
  const int w = tid >> 6;        // wave 0..1
  const int lane = tid & 63;
  const int l15 = lane & 15;
  const int kgrp = lane >> 4;    // 0..3

  const int ncb = gridDim.x;
  const int nwg = ncb * gridDim.y;
  const int bid = blockIdx.y * ncb + blockIdx.x;
  const int cpx = nwg >> 3;
  const int swz = (bid & 7) * cpx + (bid >> 3);
  const int row0 = (swz / ncb) * 64;
  const int col0 = (swz % ncb) * 192;

  // A fragment pointers (per-lane rows), kgrp folded in
  const AT* arow[2];
#pragma unroll
  for (int fm = 0; fm < 2; ++fm) {
    int r = row0 + w * 32 + fm * 16 + l15;
    if (ROWMAP) {
      int bt = r / Nn;
      int n = r - bt * Nn;
      arow[fm] = Ain + (size_t)(bt * (Nn + 1) + 1 + n) * K + kgrp * 8;
    } else {
      arow[fm] = Ain + (size_t)r * K + kgrp * 8;
    }
  }
  // B fragment pointers: 12 n-frags (bf16 weights, row-major NxK)
  const ushortt* brow[NF];
#pragma unroll
  for (int fn = 0; fn < NF; ++fn)
    brow[fn] = Wb + (size_t)(col0 + fn * 16 + l15) * K + kgrp * 8;

  f32x4 acc[2][NF];
#pragma unroll
  for (int i = 0; i < 2; ++i)
#pragma unroll
    for (int j = 0; j < NF; ++j) acc[i][j] = (f32x4){0.f, 0.f, 0.f, 0.f};

  const int nsteps = K >> 5;
  for (int step = 0; step < nsteps; ++step) {
    const int k0 = step << 5;
    bf16x8 a[2];
    if constexpr (sizeof(AT) == 4) {
#pragma unroll
      for (int fm = 0; fm < 2; ++fm) {
        float4 x0 = *(const float4*)((const float*)arow[fm] + k0);
        float4 x1 = *(const float4*)((const float*)arow[fm] + k0 + 4);
        u16x8 p = {f2bf(x0.x), f2bf(x0.y), f2bf(x0.z), f2bf(x0.w),
                   f2bf(x1.x), f2bf(x1.y), f2bf(x1.z), f2bf(x1.w)};
        a[fm] = *(bf16x8*)&p;
      }
    } else {
#pragma unroll
      for (int fm = 0; fm < 2; ++fm)
        a[fm] = *(const bf16x8*)((const ushortt*)arow[fm] + k0);
    }
#pragma unroll
    for (int fn = 0; fn < NF; ++fn) {
      bf16x8 b = *(const bf16x8*)(brow[fn] + k0);
      acc[0][fn] = __builtin_amdgcn_mfma_f32_16x16x32_bf16(
          a[0], b, acc[0][fn], 0, 0, 0);
      acc[1][fn] = __builtin_amdgcn_mfma_f32_16x16x32_bf16(
          a[1], b, acc[1][fn], 0, 0, 0);
    }
  }

  // ---- LDS-staged coalesced epilogue (64 rows x 192 cols fp32) ----
  constexpr int EP = 196;  // +4 pad
  __shared__ float epi[64 * EP];
#pragma unroll
  for (int fm = 0; fm < 2; ++fm) {
    int rl = w * 32 + fm * 16 + kgrp * 4;
#pragma unroll
    for (int fn = 0; fn < NF; ++fn) {
      int cl = fn * 16 + l15;
#pragma unroll
      for (int j = 0; j < 4; ++j)
        epi[(rl + j) * EP + cl] = acc[fm][fn][j];
    }
  }
  __syncthreads();
#pragma unroll
  for (int it = 0; it < 24; ++it) {
    int f = it * 128 + tid;        // 3072 float4 over 64 rows x 48
    int r = f / 48, c4 = f - r * 48;
    float4 v = *(const float4*)&epi[r * EP + c4 * 4];
    int c = col0 + c4 * 4;
    if (BIAS) {
      float4 bv = *(const float4*)(bias + c);
      v.x += bv.x; v.y += bv.y; v.z += bv.z; v.w += bv.w;
    }
    if (EPI == 1) {
      v.x = gelu_f(v.x); v.y = gelu_f(v.y);
      v.z = gelu_f(v.z); v.w = gelu_f(v.w);
    }
    int R = row0 + r;
    if constexpr (EPI == 2) {
      int bt2 = R / Nn, n2 = R - bt2 * Nn;
      size_t off = (size_t)(bt2 * (Nn + 1) + 1 + n2) * Nc + c;
      float4 rv = *(const float4*)(resid + off);
      v.x += rv.x; v.y += rv.y; v.z += rv.z; v.w += rv.w;
      *(float4*)((float*)Cout + off) = v;
    } else if constexpr (sizeof(CT) == 4) {
      *(float4*)((float*)Cout + (size_t)R * Nc + c) = v;
    } else {
      u16x4 ob = {f2bf(v.x), f2bf(v.y), f2bf(v.z), f2bf(v.w)};
      *(u16x4*)((ushortt*)Cout + (size_t)R * Nc + c) = ob;
    }
  }
}

// ============================================================
// delta (bf16) + per-(b,t) |delta| partials
// ============================================================
__global__ void delta_kernel(const ushortt* __restrict__ ph,
                             ushortt* __restrict__ delta,
                             float* __restrict__ dppart) {
  int bt = blockIdx.x;
  int t = bt & 15;
  int a = threadIdx.x;
  const ushortt* cur = ph + (size_t)bt * Nn * Aa + a;
  ushortt* dl = delta + (size_t)bt * Nn * Aa + a;
  float acc = 0.f;
  if (t == 0) {
    for (int n = 0; n < Nn; ++n) dl[(size_t)n * Aa] = 0;
  } else {
    const ushortt* prev = cur - (size_t)Nn * Aa;
    for (int n = 0; n < Nn; ++n) {
      float d = bf2f(cur[(size_t)n * Aa]) - bf2f(prev[(size_t)n * Aa]);
      dl[(size_t)n * Aa] = f2bf(d);
      acc += fabsf(d);
    }
  }
  dppart[bt * Aa + a] = acc;
}

// sal[row] = mean_a |delta[row,a]| (fp32, candidate stage only)
__global__ void sal_kernel(const ushortt* __restrict__ delta,
                           float* __restrict__ sal) {
  int row = blockIdx.x * 4 + (threadIdx.x >> 6);
  int lane = threadIdx.x & 63;
  const ushortt* d = delta + (size_t)row * Aa;
  float s = fabsf(bf2f(d[lane])) + fabsf(bf2f(d[lane + 64])) +
            fabsf(bf2f(d[lane + 128]));
#pragma unroll
  for (int off = 32; off > 0; off >>= 1) s += __shfl_xor(s, off, 64);
  if (lane == 0) sal[row] = s * (1.0f / 192.0f);
}

// ============================================================
// top-16 fp32 candidates per (b,t); descending val, ties -> smaller n
// ============================================================
__global__ void topcand_kernel(const float* __restrict__ sal,
                               int* __restrict__ cand) {
  int bt = blockIdx.x;
  int lane = threadIdx.x;
  unsigned long long key[4];
#pragma unroll
  for (int j = 0; j < 4; ++j) {
    int n = lane + 64 * j;
    if (n < Nn) {
      unsigned fb = __float_as_uint(sal[(size_t)bt * Nn + n]);
      key[j] = ((unsigned long long)fb << 32) |
               (unsigned long long)(0xFFFFFFFFu - (unsigned)n);
    } else {
      key[j] = 0ULL;
    }
  }
  for (int r = 0; r < NCAND; ++r) {
    unsigned long long m = key[0];
    if (key[1] > m) m = key[1];
    if (key[2] > m) m = key[2];
    if (key[3] > m) m = key[3];
#pragma unroll
    for (int off = 32; off > 0; off >>= 1) {
      unsigned long long o = __shfl_xor(m, off, 64);
      if (o > m) m = o;
    }
    if (lane == 0)
      cand[bt * NCAND + r] = (int)(0xFFFFFFFFu - (unsigned)(m & 0xFFFFFFFFull));
#pragma unroll
    for (int j = 0; j < 4; ++j)
      if (key[j] == m) key[j] = 0ULL;
  }
}

// one-time transpose: wT[c][a] = down_w[a][c]
__global__ void transpose_w(const float* __restrict__ w,
                            float* __restrict__ wT) {
  int e = blockIdx.x * 256 + threadIdx.x;  // over Cc*Aa
  int c = e / Aa, a = e - c * Aa;
  wT[e] = w[(size_t)a * Cc + c];
}

// ============================================================
// f64 refine, 8 candidates per block (grid BT x 2, 192 thr).
// diff staged once in LDS (f64); w read COALESCED via wT[c][a].
// ============================================================
__global__ __launch_bounds__(192) void refine_kernel(
    const float* __restrict__ x, const float* __restrict__ wT,
    const int* __restrict__ cand, double* __restrict__ sal64) {
  int bt = blockIdx.x;
  int grp = blockIdx.y;
  int t = bt & 15;
  int a = threadIdx.x;
  if (t == 0) {
    if (a < 8) sal64[bt * NCAND + grp * 8 + a] = 0.0;
    return;
  }
  __shared__ double sdiff[8][Cc];  // 49 KB
  const float* xt = x + ((size_t)bt * (Nn + 1) + 1) * Cc;
  const float* xp = xt - (size_t)(Nn + 1) * Cc;
  for (int g = 0; g < 8; ++g) {
    int n = cand[bt * NCAND + grp * 8 + g];
    const float* rt = xt + (size_t)n * Cc;
    const float* rp = xp + (size_t)n * Cc;
    for (int c = a; c < Cc; c += 192)
      sdiff[g][c] = (double)rt[c] - (double)rp[c];
  }
  __syncthreads();
  double acc[8] = {};
  for (int c = 0; c < Cc; ++c) {
    double wv = (double)wT[(size_t)c * Aa + a];  // coalesced across lanes
#pragma unroll
    for (int g = 0; g < 8; ++g) acc[g] = fma(wv, sdiff[g][c], acc[g]);
  }
  __shared__ double part[3][8];
  int wvx = a >> 6, ln = a & 63;
#pragma unroll
  for (int g = 0; g < 8; ++g) {
    double v = fabs(acc[g]);
#pragma unroll
    for (int off = 32; off > 0; off >>= 1) v += __shfl_xor(v, off, 64);
    if (ln == 0) part[wvx][g] = v;
  }
  __syncthreads();
  if (a < 8) {
    double s = part[0][a] + part[1][a] + part[2][a];
    sal64[bt * NCAND + grp * 8 + a] = s * (1.0 / 192.0);
  }
}

// final top-8 by (sal64 desc, n asc)
__global__ void select_kernel(const double* __restrict__ sal64,
                              const int* __restrict__ cand,
                              int* __restrict__ idx) {
  int bt = blockIdx.x;
  int t = bt & 15;
  if (threadIdx.x != 0) return;
  if (t == 0) {
    for (int r = 0; r < KK; ++r) idx[bt * KK + r] = r;
    return;
  }
  double v[NCAND];
  int nn[NCAND];
  bool used[NCAND];
  for (int i = 0; i < NCAND; ++i) {
    v[i] = sal64[bt * NCAND + i];
    nn[i] = cand[bt * NCAND + i];
    used[i] = false;
  }
  for (int r = 0; r < KK; ++r) {
    int best = -1;
    for (int i = 0; i < NCAND; ++i) {
      if (used[i]) continue;
      if (best < 0 || v[i] > v[best] ||
          (v[i] == v[best] && nn[i] < nn[best]))
        best = i;
    }
    used[best] = true;
    idx[bt * KK + r] = nn[best];
  }
}

// ============================================================
// anchor attention: gather(bf16) -> GEMM qkv -> core -> GEMMs
// ============================================================
__global__ void gather_kernel(const ushortt* __restrict__ ph,
                              const ushortt* __restrict__ delta,
                              const int* __restrict__ idx,
                              ushortt* __restrict__ tok) {
  int row = blockIdx.x;  // (b*KK+k)*16+t
  int t = row & 15;
  int bk = row >> 4;
  int b = bk >> 3, k = bk & 7;
  int a = threadIdx.x;
  int n = idx[(b * 16 + t) * KK + k];
  size_t off = ((size_t)(b * 16 + t) * Nn + n) * Aa + a;
  tok[(size_t)row * Aa + a] = f2bf(bf2f(ph[off]) + bf2f(delta[off]));
}

__global__ __launch_bounds__(256) void attn_core(
    const float* __restrict__ qkv, float* __restrict__ o) {
  constexpr int P = 580;
  __shared__ float sq[16 * P];
  __shared__ float ssc[4][16][17];
  int bk = blockIdx.x;
  int tid = threadIdx.x;
  const float* src = qkv + (size_t)bk * 16 * 576;
  for (int e = tid; e < 16 * 144; e += 256) {
    int r = e / 144, c4 = e % 144;
    float4 v = *(const float4*)(src + r * 576 + c4 * 4);
    *(float4*)(&sq[r * P + c4 * 4]) = v;
  }
  __syncthreads();
  int h = tid >> 6, lane = tid & 63;
#pragma unroll
  for (int s4 = 0; s4 < 4; ++s4) {
    int e = lane + 64 * s4;
    int i = e >> 4, j = e & 15;
    const float* q = sq + i * P + h * 48;
    const float* k2 = sq + j * P + 192 + h * 48;
    float s = 0.f;
#pragma unroll
    for (int d = 0; d < 48; ++d) s = fmaf(q[d], k2[d], s);
    ssc[h][i][j] = s * 0.14433756729740643f;  // 1/sqrt(48)
  }
  __syncthreads();
  if (lane < 16) {
    float* r = ssc[h][lane];
    float mx = r[0];
    for (int j = 1; j < 16; ++j) mx = fmaxf(mx, r[j]);
    float sum = 0.f;
    for (int j = 0; j < 16; ++j) {
      float ev = expf(r[j] - mx);
      r[j] = ev;
      sum += ev;
    }
    float inv = 1.0f / sum;
    for (int j = 0; j < 16; ++j) r[j] *= inv;
  }
  __syncthreads();
#pragma unroll
  for (int s4 = 0; s4 < 12; ++s4) {
    int e = lane + 64 * s4;
    int i = e / 48, d = e - i * 48;
    float s = 0.f;
#pragma unroll
    for (int j = 0; j < 16; ++j)
      s = fmaf(ssc[h][i][j], sq[j * P + 384 + h * 48 + d], s);
    o[((size_t)bk * 16 + i) * 192 + h * 48 + d] = s;
  }
}

__global__ void appart_kernel(const float* __restrict__ attout,
                              float* __restrict__ appart) {
  int bk = blockIdx.x;
  int a = threadIdx.x;
  float s = 0.f;
  for (int t = 0; t < Tt; ++t)
    s += attout[((size_t)bk * Tt + t) * Aa + a];
  appart[bk * Aa + a] = s;
}

// in-place fp32 LayerNorm over last dim (192); one wave per row
__global__ void ln32_kernel(float* __restrict__ buf,
                            const float* __restrict__ g,
                            const float* __restrict__ bb) {
  size_t row = (size_t)blockIdx.x * 4 + (threadIdx.x >> 6);
  int lane = threadIdx.x & 63;
  float* p = buf + row * Aa;
  float v0 = p[lane], v1 = p[lane + 64], v2 = p[lane + 128];
  float s = v0 + v1 + v2;
#pragma unroll
  for (int off = 32; off > 0; off >>= 1) s += __shfl_xor(s, off, 64);
  float m = s * (1.0f / 192.0f);
  float d0 = v0 - m, d1 = v1 - m, d2 = v2 - m;
  float ss = d0 * d0 + d1 * d1 + d2 * d2;
#pragma unroll
  for (int off = 32; off > 0; off >>= 1) ss += __shfl_xor(ss, off, 64);
  float inv = rsqrtf(ss * (1.0f / 192.0f) + 1e-5f);
  p[lane] = d0 * inv * g[lane] + bb[lane];
  p[lane + 64] = d1 * inv * g[lane + 64] + bb[lane + 64];
  p[lane + 128] = d2 * inv * g[lane + 128] + bb[lane + 128];
}

// depthwise 3x3 SAME conv over 14x14 + gelu; bf16 in/out
__global__ void conv2d_kernel(const ushortt* __restrict__ ph,
                              const float* __restrict__ ldw,
                              ushortt* __restrict__ og) {
  size_t e = (size_t)blockIdx.x * 256 + threadIdx.x;
  int a = (int)(e % Aa);
  size_t r = e / Aa;
  int n = (int)(r % Nn);
  int bt = (int)(r / Nn);
  int y = n / 14, x = n % 14;
  const ushortt* base = ph + (size_t)bt * Nn * Aa + a;
  const float* w = ldw + a * 9;
  float s = 0.f;
#pragma unroll
  for (int dy = -1; dy <= 1; ++dy) {
    int yy = y + dy;
    if (yy < 0 || yy >= 14) continue;
#pragma unroll
    for (int dx = -1; dx <= 1; ++dx) {
      int xc = x + dx;
      if (xc < 0 || xc >= 14) continue;
      s = fmaf(bf2f(base[(size_t)(yy * 14 + xc) * Aa]),
               w[(dy + 1) * 3 + (dx + 1)], s);
    }
  }
  og[e] = f2bf(gelu_f(s));
}

// depthwise k=3 SAME conv over t + gelu; bf16 in/out
__global__ void conv1d_kernel(const ushortt* __restrict__ delta,
                              const float* __restrict__ tdw,
                              ushortt* __restrict__ og) {
  size_t e = (size_t)blockIdx.x * 256 + threadIdx.x;
  int a = (int)(e % Aa);
  size_t r = e / Aa;
  int n = (int)(r % Nn);
  int bt = (int)(r / Nn);
  int t = bt & 15, b = bt >> 4;
  const float* w = tdw + a * 3;
  float s = 0.f;
#pragma unroll
  for (int j = 0; j < 3; ++j) {
    int tt = t + j - 1;
    if (tt >= 0 && tt < Tt)
      s = fmaf(bf2f(delta[((size_t)(b * Tt + tt) * Nn + n) * Aa + a]), w[j], s);
  }
  og[e] = f2bf(gelu_f(s));
}

// in-place LayerNorm over last dim (192); one wave per row (bf16)
__global__ void ln_kernel(ushortt* __restrict__ buf,
                          const float* __restrict__ g,
                          const float* __restrict__ bb) {
  size_t row = (size_t)blockIdx.x * 4 + (threadIdx.x >> 6);
  int lane = threadIdx.x & 63;
  ushortt* p = buf + row * Aa;
  float v0 = bf2f(p[lane]), v1 = bf2f(p[lane + 64]), v2 = bf2f(p[lane + 128]);
  float s = v0 + v1 + v2;
#pragma unroll
  for (int off = 32; off > 0; off >>= 1) s += __shfl_xor(s, off, 64);
  float m = s * (1.0f / 192.0f);
  float d0 = v0 - m, d1 = v1 - m, d2 = v2 - m;
  float ss = d0 * d0 + d1 * d1 + d2 * d2;
#pragma unroll
  for (int off = 32; off > 0; off >>= 1) ss += __shfl_xor(ss, off, 64);
  float inv = rsqrtf(ss * (1.0f / 192.0f) + 1e-5f);
  p[lane] = f2bf(d0 * inv * g[lane] + bb[lane]);
  p[lane + 64] = f2bf(d1 * inv * g[lane + 64] + bb[lane + 64]);
  p[lane + 128] = f2bf(d2 * inv * g[lane + 128] + bb[lane + 128]);
}

// posmap[bt*Nn + idx[bt,k]] = k+1 (posmap pre-zeroed)
__global__ void scatter_pos(const int* __restrict__ idx,
                            short* __restrict__ posmap) {
  int bt = blockIdx.x;
  int k = threadIdx.x;
  if (k < KK) posmap[bt * Nn + idx[bt * KK + k]] = (short)(k + 1);
}

// gate MLP + 3-way softmax; one block per b, 192 threads
__global__ void gate_kernel(const float* __restrict__ dppart,
                            const float* __restrict__ appart,
                            const float* __restrict__ w1,
                            const float* __restrict__ b1,
                            const float* __restrict__ w2,
                            const float* __restrict__ b2,
                            float* __restrict__ gw) {
  int b = blockIdx.x;
  __shared__ float sg[2 * Aa];
  __shared__ float sh[Aa];
  int tid = threadIdx.x;
  {
    float d = 0.f;
    for (int t2 = 0; t2 < Tt; ++t2) d += dppart[(b * Tt + t2) * Aa + tid];
    sg[tid] = d * (1.0f / 3136.0f);
    float a = 0.f;
    for (int k2 = 0; k2 < KK; ++k2) a += appart[(b * KK + k2) * Aa + tid];
    sg[Aa + tid] = a * (1.0f / 128.0f);
  }
  __syncthreads();
  {
    const float* w = w1 + (size_t)tid * 2 * Aa;
    float s = b1[tid];
#pragma unroll 8
    for (int j = 0; j < 2 * Aa; ++j) s = fmaf(sg[j], w[j], s);
    sh[tid] = gelu_f(s);
  }
  __syncthreads();
  float v[3];
#pragma unroll
  for (int i = 0; i < 3; ++i) {
    const float* w = w2 + (size_t)(i * Aa + tid) * Aa;
    float s = b2[i * Aa + tid];
#pragma unroll 8
    for (int j = 0; j < Aa; ++j) s = fmaf(sh[j], w[j], s);
    v[i] = s;
  }
  float mx = fmaxf(v[0], fmaxf(v[1], v[2]));
  float e0 = expf(v[0] - mx), e1 = expf(v[1] - mx), e2 = expf(v[2] - mx);
  float inv = 1.0f / (e0 + e1 + e2);
  gw[(b * 3 + 0) * Aa + tid] = e0 * inv;
  gw[(b * 3 + 1) * Aa + tid] = e1 * inv;
  gw[(b * 3 + 2) * Aa + tid] = e2 * inv;
}

// fused = gw0*local + gw1*trans + gw2*amap_ln; amap_ln from attln rows
// (anchors, via posmap) or anorm_b constant (non-anchors). fmean fp32.
__global__ void fused_kernel(const ushortt* __restrict__ local,
                             const ushortt* __restrict__ trans,
                             const float* __restrict__ attln,
                             const short* __restrict__ posmap,
                             const float* __restrict__ anb,
                             const float* __restrict__ gw,
                             ushortt* __restrict__ fused,
                             float* __restrict__ fmean) {
  int bt = blockIdx.x;
  int b = bt >> 4, t = bt & 15;
  int a = threadIdx.x;
  float g0 = gw[(b * 3 + 0) * Aa + a];
  float g1 = gw[(b * 3 + 1) * Aa + a];
  float g2 = gw[(b * 3 + 2) * Aa + a];
  float ab = anb[a];
  size_t base = (size_t)bt * Nn * Aa + a;
  float acc = 0.f;
  for (int n = 0; n < Nn; ++n) {
    size_t o = base + (size_t)n * Aa;
    short pos = posmap[bt * Nn + n];
    float am = pos ? attln[(((size_t)(b * KK + pos - 1) * Tt) + t) * Aa + a]
                   : ab;
    float f = g0 * bf2f(local[o]) + g1 * bf2f(trans[o]) + g2 * am;
    fused[o] = f2bf(f);
    acc += f;
  }
  fmean[bt * Aa + a] = acc;
}

// cls_out = cls_tok + (mean_n fused) @ cls_w.T + cls_b
__global__ void cls_kernel(const float* __restrict__ fmean,
                           const float* __restrict__ cw,
                           const float* __restrict__ cb,
                           const float* __restrict__ x,
                           float* __restrict__ out) {
  int bt = blockIdx.x;
  __shared__ float fm[Aa];
  int tid = threadIdx.x;
  if (tid < Aa) fm[tid] = fmean[bt * Aa + tid] * (1.0f / 196.0f);
  __syncthreads();
  for (int c = tid; c < Cc; c += 256) {
    const float* w = cw + (size_t)c * Aa;
    float s = cb[c];
#pragma unroll 8
    for (int a = 0; a < Aa; ++a) s = fmaf(fm[a], w[a], s);
    size_t off = (size_t)bt * (Nn + 1) * Cc + c;
    out[off] = x[off] + s;
  }
}

// ============================================================
extern "C" void kernel_launch(void* const* d_in, const int* in_sizes, int n_in,
                              void* d_out, int out_size, void* d_ws,
                              size_t ws_size, hipStream_t stream) {
  const float* x = (const float*)d_in[0];
  const float* down_w = (const float*)d_in[1];
  const float* down_b = (const float*)d_in[2];
  const float* ldw_w = (const float*)d_in[3];
  const float* lpw_w = (const float*)d_in[4];
  const float* lnorm_g = (const float*)d_in[5];
  const float* lnorm_b = (const float*)d_in[6];
  const float* tdw_w = (const float*)d_in[7];
  const float* tpw_w = (const float*)d_in[8];
  const float* tmlp_w1 = (const float*)d_in[9];
  const float* tmlp_b1 = (const float*)d_in[10];
  const float* tmlp_w2 = (const float*)d_in[11];
  const float* tmlp_b2 = (const float*)d_in[12];
  const float* tnorm_g = (const float*)d_in[13];
  const float* tnorm_b = (const float*)d_in[14];
  const float* attn_in_w = (const float*)d_in[15];
  const float* attn_in_b = (const float*)d_in[16];
  const float* attn_out_w = (const float*)d_in[17];
  const float* attn_out_b = (const float*)d_in[18];
  const float* aproj_w = (const float*)d_in[19];
  const float* aproj_b = (const float*)d_in[20];
  const float* anorm_g = (const float*)d_in[21];
  const float* anorm_b = (const float*)d_in[22];
  const float* gate_w1 = (const float*)d_in[23];
  const float* gate_b1 = (const float*)d_in[24];
  const float* gate_w2 = (const float*)d_in[25];
  const float* gate_b2 = (const float*)d_in[26];
  const float* up_w = (const float*)d_in[27];
  const float* up_b = (const float*)d_in[28];
  const float* cls_w = (const float*)d_in[29];
  const float* cls_b = (const float*)d_in[30];
  float* out = (float*)d_out;

  float* ws = (float*)d_ws;
  float* W0 = ws;              // ph bf16 -> trp bf16
  float* W1 = W0 + SZ;         // delta bf16 -> transition bf16
  float* W2 = W1 + SZ;         // attn scratch -> locg/trg/h1/fused bf16
  float* W3 = W2 + 2 * SZ;     // local bf16
  float* sal = W3 + SZ;
  float* attout = sal + BTN;
  float* dppart = attout + (size_t)BKT * Aa;
  float* appart = dppart + (size_t)BT * Aa;
  float* gw = appart + (size_t)Bb * KK * Aa;
  float* fmean = gw + (size_t)Bb * 3 * Aa;
  double* sal64 = (double*)(fmean + (size_t)BT * Aa);  // BT*NCAND doubles
  int* cand = (int*)(sal64 + (size_t)BT * NCAND);      // BT*NCAND ints
  int* idx = cand + (size_t)BT * NCAND;                // BT*KK ints
  float* wT = (float*)(idx + (size_t)BT * KK);         // Cc*Aa floats
  short* posmap = (short*)(wT + (size_t)Cc * Aa);      // BT*Nn shorts
  ushortt* wbuf = (ushortt*)(posmap + (size_t)BT * Nn);  // OTOT bf16

  // bf16 weight views
  ushortt* wb_down   = wbuf;
  ushortt* wb_attnin = wbuf + O1;
  ushortt* wb_attnout= wbuf + O2;
  ushortt* wb_aproj  = wbuf + O3;
  ushortt* wb_lpw    = wbuf + O4;
  ushortt* wb_tpw    = wbuf + O5;
  ushortt* wb_t1     = wbuf + O6;
  ushortt* wb_t2     = wbuf + O7;
  ushortt* wb_up     = wbuf + O8;

  // bf16 activation views
  ushortt* ph_b    = (ushortt*)W0;
  ushortt* trp_b   = (ushortt*)W0;
  ushortt* delta_b = (ushortt*)W1;
  ushortt* trans_b = (ushortt*)W1;
  ushortt* locg_b  = (ushortt*)W2;
  ushortt* trg_b   = (ushortt*)W2;
  ushortt* h1_b    = (ushortt*)W2;
  ushortt* fused_b = (ushortt*)W2;
  ushortt* local_b = (ushortt*)W3;

  // attn-phase scratch inside W2 (dead until conv2d)
  ushortt* tok_b = (ushortt*)W2;                       // 2048*192 bf16
  float* qkvb  = W2 + (size_t)BKT * Aa / 2;            // 2048*576 f32
  float* obuf  = qkvb + (size_t)BKT * 3 * Aa;          // 2048*192 f32
  float* proj1 = obuf + (size_t)BKT * Aa;              // 2048*192 f32

  // 0. weights -> bf16 (one pass), wT for refine
  cvtw_kernel<<<OTOT / 256, 256, 0, stream>>>(
      down_w, attn_in_w, attn_out_w, aproj_w, lpw_w, tpw_w, tmlp_w1,
      tmlp_w2, up_w, wbuf);
  transpose_w<<<(Cc * Aa) / 256, 256, 0, stream>>>(down_w, wT);
  // 1. ph = patch @ down_w.T + down_b (bf16 out)
  gemm_skinny<float, ushortt, 1, 1, 0><<<dim3(1, 784), 128, 0, stream>>>(
      x, wb_down, down_b, ph_b, nullptr, BTN, Aa, Cc);
  // 2. delta + dp partials
  delta_kernel<<<BT, Aa, 0, stream>>>(ph_b, delta_b, dppart);
  // 3. saliency: fp32 candidates -> f64 refine -> exact top-8
  sal_kernel<<<BTN / 4, 256, 0, stream>>>(delta_b, sal);
  topcand_kernel<<<BT, 64, 0, stream>>>(sal, cand);
  refine_kernel<<<dim3(BT, 2), 192, 0, stream>>>(x, wT, cand, sal64);
  select_kernel<<<BT, 64, 0, stream>>>(sal64, cand, idx);
  // 4. anchor attention
  gather_kernel<<<BKT, Aa, 0, stream>>>(ph_b, delta_b, idx, tok_b);
  gemm_skinny<ushortt, float, 0, 1, 0><<<dim3(3, 32), 128, 0, stream>>>(
      tok_b, wb_attnin, attn_in_b, qkvb, nullptr, BKT, 3 * Aa, Aa);
  attn_core<<<Bb * KK, 256, 0, stream>>>(qkvb, obuf);
  gemm_skinny<float, float, 0, 1, 0><<<dim3(1, 32), 128, 0, stream>>>(
      obuf, wb_attnout, attn_out_b, proj1, nullptr, BKT, Aa, Aa);
  gemm_skinny<float, float, 0, 1, 0><<<dim3(1, 32), 128, 0, stream>>>(
      proj1, wb_aproj, aproj_b, attout, nullptr, BKT, Aa, Aa);
  appart_kernel<<<Bb * KK, Aa, 0, stream>>>(attout, appart);
  // 4b. LN the 2048 anchor rows in place (replaces full anchor-map LN)
  ln32_kernel<<<BKT / 4, 256, 0, stream>>>(attout, anorm_g, anorm_b);
  hipMemsetAsync(posmap, 0, (size_t)BT * Nn * sizeof(short), stream);
  scatter_pos<<<BT, 64, 0, stream>>>(idx, posmap);
  // 5. local branch
  conv2d_kernel<<<(unsigned)(SZ / 256), 256, 0, stream>>>(ph_b, ldw_w, locg_b);
  gemm_skinny<ushortt, ushortt, 0, 0, 0><<<dim3(1, 784), 128, 0, stream>>>(
      locg_b, wb_lpw, nullptr, local_b, nullptr, BTN, Aa, Aa);
  ln_kernel<<<BTN / 4, 256, 0, stream>>>(local_b, lnorm_g, lnorm_b);
  // 6. transition branch
  conv1d_kernel<<<(unsigned)(SZ / 256), 256, 0, stream>>>(delta_b, tdw_w, trg_b);
  gemm_skinny<ushortt, ushortt, 0, 0, 0><<<dim3(1, 784), 128, 0, stream>>>(
      trg_b, wb_tpw, nullptr, trp_b, nullptr, BTN, Aa, Aa);
  gemm_skinny<ushortt, ushortt, 0, 1, 1><<<dim3(2, 784), 128, 0, stream>>>(
      trp_b, wb_t1, tmlp_b1, h1_b, nullptr, BTN, 2 * Aa, Aa);
  gemm_skinny<ushortt, ushortt, 0, 1, 0><<<dim3(1, 784), 128, 0, stream>>>(
      h1_b, wb_t2, tmlp_b2, trans_b, nullptr, BTN, Aa, 2 * Aa);
  ln_kernel<<<BTN / 4, 256, 0, stream>>>(trans_b, tnorm_g, tnorm_b);
  // 8. gate
  gate_kernel<<<Bb, Aa, 0, stream>>>(dppart, appart, gate_w1, gate_b1,
                                     gate_w2, gate_b2, gw);
  // 9. fuse + output projections
  fused_kernel<<<BT, Aa, 0, stream>>>(local_b, trans_b, attout, posmap,
                                      anorm_b, gw, fused_b, fmean);
  gemm_skinny<ushortt, float, 0, 1, 2><<<dim3(4, 784), 128, 0, stream>>>(
      fused_b, wb_up, up_b, out, x, BTN, Cc, Aa);
  cls_kernel<<<BT, 256, 0, stream>>>(fmean, cls_w, cls_b, x, out);
}

// Round 11
// 648.873 us; speedup vs baseline: 1.7079x; 1.7079x over previous
//
#include <hip/hip_runtime.h>
#include <hip/hip_bf16.h>
#include <math.h>

// ---- fixed problem dims ----
constexpr int Bb  = 16;
constexpr int Tt  = 16;
constexpr int Nn  = 196;   // patches (14x14)
constexpr int Cc  = 768;
constexpr int Aa  = 192;
constexpr int KK  = 8;     // TOPK
constexpr int NCAND = 16;  // fp32 candidates refined in f64
constexpr int BT  = Bb * Tt;            // 256
constexpr int BTN = BT * Nn;            // 50176
constexpr int BKT = Bb * KK * Tt;       // 2048 anchor-token rows
constexpr size_t SZ = (size_t)BTN * Aa; // 9,633,792 floats

typedef unsigned short ushortt;
typedef __attribute__((ext_vector_type(8))) short bf16x8;
typedef __attribute__((ext_vector_type(4))) float f32x4;
typedef __attribute__((ext_vector_type(4))) unsigned short u16x4;
typedef __attribute__((ext_vector_type(8))) unsigned short u16x8;

static __device__ __forceinline__ float gelu_f(float x) {
  return 0.5f * x * (1.0f + erff(x * 0.7071067811865476f));
}
// HARDWARE bf16 convert (v_cvt_pk_bf16_f32) via HIP cast — the software
// RNE bit-twiddle was ~5 VALU ops/value and dominated GEMM staging (r10 PM).
static __device__ __forceinline__ ushortt f2bf(float f) {
  __hip_bfloat16 h = __float2bfloat16(f);
  return *reinterpret_cast<ushortt*>(&h);
}
static __device__ __forceinline__ float bf2f(ushortt u) {
  return __uint_as_float(((unsigned)u) << 16);
}

// ============================================================
// bf16 MFMA GEMM: C[m,n] = sum_k A[m,k]*W[n,k] (+bias)(+epilogue)
// AT: float (staged->bf16) or ushort (bf16). CT: float or ushort.
// BM=64 BN=96 BK=32, 256 thr = 4 waves (2x2), wave tile 32x48.
// LDS 25.6 KB => 6 blocks/CU. Single-pass LDS-staged coalesced epilogue.
// EPI: 0 plain, 1 gelu, 2 mapped residual fp32.
// Grid (Nc/96, M/64); col-fastest + bijective XCD swizzle (nwg%8==0).
// ============================================================
template <typename AT, typename CT, int ROWMAP, int BIAS, int EPI>
__global__ __launch_bounds__(256) void gemm_mfma(
    const AT* __restrict__ Ain, const float* __restrict__ W,
    const float* __restrict__ bias, CT* __restrict__ Cout,
    const float* __restrict__ resid, int M, int Nc, int K) {
  constexpr int PIT = 40;  // bf16 pitch (32+8 pad) -> worst 2-way (free)
  __shared__ __align__(16) unsigned char smem[25600];
  ushortt (*As)[64 * PIT] = (ushortt(*)[64 * PIT])smem;
  ushortt (*Bs)[96 * PIT] = (ushortt(*)[96 * PIT])(smem + 2 * 64 * PIT * 2);
  const int tid = threadIdx.x;

  const int ncb = gridDim.x;
  const int nwg = ncb * gridDim.y;
  const int bid = blockIdx.y * ncb + blockIdx.x;
  const int cpx = nwg >> 3;
  const int swz = (bid & 7) * cpx + (bid >> 3);
  const int row0 = (swz / ncb) * 64;
  const int col0 = (swz % ncb) * 96;

  const int wid = tid >> 6;
  const int lane = tid & 63;
  const int wr = wid >> 1;       // 0..1 -> +32 rows
  const int wc = wid & 1;        // 0..1 -> +48 cols
  const int l15 = lane & 15;
  const int kgrp = lane >> 4;    // 0..3

  const int nsteps = K >> 5;

  const float* arowf[2];
  const ushortt* arowb[1];
  if constexpr (sizeof(AT) == 4) {
    const int srow = tid >> 3;   // 0..31
#pragma unroll
    for (int p = 0; p < 2; ++p) {
      int r = row0 + srow + 32 * p;
      if (ROWMAP) {
        int bt = r / Nn;
        int n = r - bt * Nn;
        arowf[p] = (const float*)Ain + (size_t)(bt * (Nn + 1) + 1 + n) * K;
      } else {
        arowf[p] = (const float*)Ain + (size_t)r * K;
      }
    }
  } else {
    const int srow2 = tid >> 2;  // 0..63
    arowb[0] = (const ushortt*)Ain + (size_t)(row0 + srow2) * K;
  }
  const float* browp[3];
  {
    const int srow = tid >> 3;
#pragma unroll
    for (int p = 0; p < 3; ++p)
      browp[p] = W + (size_t)(col0 + srow + 32 * p) * K;
  }

  f32x4 acc[2][3];
#pragma unroll
  for (int i = 0; i < 2; ++i)
#pragma unroll
    for (int j = 0; j < 3; ++j) acc[i][j] = (f32x4){0.f, 0.f, 0.f, 0.f};

  float4 apre[2], bpre[3];
  u16x8 apreb[1];

#define STAGE_LOAD(k0)                                                       \
  if constexpr (sizeof(AT) == 4) {                                           \
    const int quad = tid & 7;                                                \
    _Pragma("unroll") for (int p = 0; p < 2; ++p)                            \
        apre[p] = *(const float4*)(arowf[p] + (k0) + quad * 4);              \
  } else {                                                                   \
    const int quad2 = tid & 3;                                               \
    apreb[0] = *(const u16x8*)(arowb[0] + (k0) + quad2 * 8);                 \
  }                                                                          \
  {                                                                          \
    const int quad = tid & 7;                                                \
    _Pragma("unroll") for (int p = 0; p < 3; ++p)                            \
        bpre[p] = *(const float4*)(browp[p] + (k0) + quad * 4);              \
  }

#define STAGE_WRITE(buf)                                                     \
  if constexpr (sizeof(AT) == 4) {                                           \
    const int quad = tid & 7, srow = tid >> 3;                               \
    _Pragma("unroll") for (int p = 0; p < 2; ++p) {                          \
      u16x4 b = {f2bf(apre[p].x), f2bf(apre[p].y), f2bf(apre[p].z),          \
                 f2bf(apre[p].w)};                                           \
      *(u16x4*)&As[buf][(srow + 32 * p) * PIT + quad * 4] = b;               \
    }                                                                        \
  } else {                                                                   \
    const int quad2 = tid & 3, srow2 = tid >> 2;                             \
    *(u16x8*)&As[buf][srow2 * PIT + quad2 * 8] = apreb[0];                   \
  }                                                                          \
  {                                                                          \
    const int quad = tid & 7, srow = tid >> 3;                               \
    _Pragma("unroll") for (int p = 0; p < 3; ++p) {                          \
      u16x4 b = {f2bf(bpre[p].x), f2bf(bpre[p].y), f2bf(bpre[p].z),          \
                 f2bf(bpre[p].w)};                                           \
      *(u16x4*)&Bs[buf][(srow + 32 * p) * PIT + quad * 4] = b;               \
    }                                                                        \
  }

  STAGE_LOAD(0);
  STAGE_WRITE(0);
  __syncthreads();

  int cur = 0;
  for (int step = 0; step < nsteps; ++step) {
    const bool pref = (step + 1 < nsteps);
    if (pref) {
      int k0 = (step + 1) << 5;
      STAGE_LOAD(k0);
    }
    bf16x8 af[2], bfv[3];
#pragma unroll
    for (int fm = 0; fm < 2; ++fm)
      af[fm] = *(const bf16x8*)&As[cur][(wr * 32 + fm * 16 + l15) * PIT + kgrp * 8];
#pragma unroll
    for (int fn = 0; fn < 3; ++fn)
      bfv[fn] = *(const bf16x8*)&Bs[cur][(wc * 48 + fn * 16 + l15) * PIT + kgrp * 8];
#pragma unroll
    for (int fm = 0; fm < 2; ++fm)
#pragma unroll
      for (int fn = 0; fn < 3; ++fn)
        acc[fm][fn] = __builtin_amdgcn_mfma_f32_16x16x32_bf16(
            af[fm], bfv[fn], acc[fm][fn], 0, 0, 0);
    if (pref) {
      STAGE_WRITE(cur ^ 1);
    }
    __syncthreads();
    cur ^= 1;
  }
#undef STAGE_LOAD
#undef STAGE_WRITE

  // ---- single-pass LDS-staged epilogue: coalesced global stores ----
  constexpr int EP = 100;  // fp32 pitch for 96 cols (+4 pad)
  float* epi = (float*)smem;  // 64*100*4 = 25600 B
#pragma unroll
  for (int fm = 0; fm < 2; ++fm) {
    int rl = wr * 32 + fm * 16 + kgrp * 4;
#pragma unroll
    for (int fn = 0; fn < 3; ++fn) {
      int cl = wc * 48 + fn * 16 + l15;
#pragma unroll
      for (int j = 0; j < 4; ++j)
        epi[(rl + j) * EP + cl] = acc[fm][fn][j];
    }
  }
  __syncthreads();
#pragma unroll
  for (int it = 0; it < 6; ++it) {
    int f = it * 256 + tid;        // 0..1535 over 64 rows x 24 float4
    int r = f / 24, c4 = f - r * 24;
    float4 v = *(const float4*)&epi[r * EP + c4 * 4];
    int c = col0 + c4 * 4;
    if (BIAS) {
      float4 bv = *(const float4*)(bias + c);
      v.x += bv.x; v.y += bv.y; v.z += bv.z; v.w += bv.w;
    }
    if (EPI == 1) {
      v.x = gelu_f(v.x); v.y = gelu_f(v.y);
      v.z = gelu_f(v.z); v.w = gelu_f(v.w);
    }
    int R = row0 + r;
    if constexpr (EPI == 2) {
      int bt2 = R / Nn, n2 = R - bt2 * Nn;
      size_t off = (size_t)(bt2 * (Nn + 1) + 1 + n2) * Nc + c;
      float4 rv = *(const float4*)(resid + off);
      v.x += rv.x; v.y += rv.y; v.z += rv.z; v.w += rv.w;
      *(float4*)((float*)Cout + off) = v;
    } else if constexpr (sizeof(CT) == 4) {
      *(float4*)((float*)Cout + (size_t)R * Nc + c) = v;
    } else {
      u16x4 ob = {f2bf(v.x), f2bf(v.y), f2bf(v.z), f2bf(v.w)};
      *(u16x4*)((ushortt*)Cout + (size_t)R * Nc + c) = ob;
    }
  }
}

// ============================================================
// delta (bf16) + per-(b,t) |delta| partials
// ============================================================
__global__ void delta_kernel(const ushortt* __restrict__ ph,
                             ushortt* __restrict__ delta,
                             float* __restrict__ dppart) {
  int bt = blockIdx.x;
  int t = bt & 15;
  int a = threadIdx.x;
  const ushortt* cur = ph + (size_t)bt * Nn * Aa + a;
  ushortt* dl = delta + (size_t)bt * Nn * Aa + a;
  float acc = 0.f;
  if (t == 0) {
    for (int n = 0; n < Nn; ++n) dl[(size_t)n * Aa] = 0;
  } else {
    const ushortt* prev = cur - (size_t)Nn * Aa;
    for (int n = 0; n < Nn; ++n) {
      float d = bf2f(cur[(size_t)n * Aa]) - bf2f(prev[(size_t)n * Aa]);
      dl[(size_t)n * Aa] = f2bf(d);
      acc += fabsf(d);
    }
  }
  dppart[bt * Aa + a] = acc;
}

// sal[row] = mean_a |delta[row,a]| (fp32, candidate stage only)
__global__ void sal_kernel(const ushortt* __restrict__ delta,
                           float* __restrict__ sal) {
  int row = blockIdx.x * 4 + (threadIdx.x >> 6);
  int lane = threadIdx.x & 63;
  const ushortt* d = delta + (size_t)row * Aa;
  float s = fabsf(bf2f(d[lane])) + fabsf(bf2f(d[lane + 64])) +
            fabsf(bf2f(d[lane + 128]));
#pragma unroll
  for (int off = 32; off > 0; off >>= 1) s += __shfl_xor(s, off, 64);
  if (lane == 0) sal[row] = s * (1.0f / 192.0f);
}

// ============================================================
// top-16 fp32 candidates per (b,t); descending val, ties -> smaller n
// ============================================================
__global__ void topcand_kernel(const float* __restrict__ sal,
                               int* __restrict__ cand) {
  int bt = blockIdx.x;
  int lane = threadIdx.x;
  unsigned long long key[4];
#pragma unroll
  for (int j = 0; j < 4; ++j) {
    int n = lane + 64 * j;
    if (n < Nn) {
      unsigned fb = __float_as_uint(sal[(size_t)bt * Nn + n]);
      key[j] = ((unsigned long long)fb << 32) |
               (unsigned long long)(0xFFFFFFFFu - (unsigned)n);
    } else {
      key[j] = 0ULL;
    }
  }
  for (int r = 0; r < NCAND; ++r) {
    unsigned long long m = key[0];
    if (key[1] > m) m = key[1];
    if (key[2] > m) m = key[2];
    if (key[3] > m) m = key[3];
#pragma unroll
    for (int off = 32; off > 0; off >>= 1) {
      unsigned long long o = __shfl_xor(m, off, 64);
      if (o > m) m = o;
    }
    if (lane == 0)
      cand[bt * NCAND + r] = (int)(0xFFFFFFFFu - (unsigned)(m & 0xFFFFFFFFull));
#pragma unroll
    for (int j = 0; j < 4; ++j)
      if (key[j] == m) key[j] = 0ULL;
  }
}

// one-time transpose: wT[c][a] = down_w[a][c]
__global__ void transpose_w(const float* __restrict__ w,
                            float* __restrict__ wT) {
  int e = blockIdx.x * 256 + threadIdx.x;  // over Cc*Aa
  int c = e / Aa, a = e - c * Aa;
  wT[e] = w[(size_t)a * Cc + c];
}

// ============================================================
// f64 refine, 8 candidates per block (grid BT x 2, 192 thr).
// diff staged once in LDS (f64); w read COALESCED via wT[c][a].
// ============================================================
__global__ __launch_bounds__(192) void refine_kernel(
    const float* __restrict__ x, const float* __restrict__ wT,
    const int* __restrict__ cand, double* __restrict__ sal64) {
  int bt = blockIdx.x;
  int grp = blockIdx.y;
  int t = bt & 15;
  int a = threadIdx.x;
  if (t == 0) {
    if (a < 8) sal64[bt * NCAND + grp * 8 + a] = 0.0;
    return;
  }
  __shared__ double sdiff[8][Cc];  // 49 KB
  const float* xt = x + ((size_t)bt * (Nn + 1) + 1) * Cc;
  const float* xp = xt - (size_t)(Nn + 1) * Cc;
  for (int g = 0; g < 8; ++g) {
    int n = cand[bt * NCAND + grp * 8 + g];
    const float* rt = xt + (size_t)n * Cc;
    const float* rp = xp + (size_t)n * Cc;
    for (int c = a; c < Cc; c += 192)
      sdiff[g][c] = (double)rt[c] - (double)rp[c];
  }
  __syncthreads();
  double acc[8] = {};
  for (int c = 0; c < Cc; ++c) {
    double wv = (double)wT[(size_t)c * Aa + a];  // coalesced across lanes
#pragma unroll
    for (int g = 0; g < 8; ++g) acc[g] = fma(wv, sdiff[g][c], acc[g]);
  }
  __shared__ double part[3][8];
  int wvx = a >> 6, ln = a & 63;
#pragma unroll
  for (int g = 0; g < 8; ++g) {
    double v = fabs(acc[g]);
#pragma unroll
    for (int off = 32; off > 0; off >>= 1) v += __shfl_xor(v, off, 64);
    if (ln == 0) part[wvx][g] = v;
  }
  __syncthreads();
  if (a < 8) {
    double s = part[0][a] + part[1][a] + part[2][a];
    sal64[bt * NCAND + grp * 8 + a] = s * (1.0 / 192.0);
  }
}

// final top-8 by (sal64 desc, n asc)
__global__ void select_kernel(const double* __restrict__ sal64,
                              const int* __restrict__ cand,
                              int* __restrict__ idx) {
  int bt = blockIdx.x;
  int t = bt & 15;
  if (threadIdx.x != 0) return;
  if (t == 0) {
    for (int r = 0; r < KK; ++r) idx[bt * KK + r] = r;
    return;
  }
  double v[NCAND];
  int nn[NCAND];
  bool used[NCAND];
  for (int i = 0; i < NCAND; ++i) {
    v[i] = sal64[bt * NCAND + i];
    nn[i] = cand[bt * NCAND + i];
    used[i] = false;
  }
  for (int r = 0; r < KK; ++r) {
    int best = -1;
    for (int i = 0; i < NCAND; ++i) {
      if (used[i]) continue;
      if (best < 0 || v[i] > v[best] ||
          (v[i] == v[best] && nn[i] < nn[best]))
        best = i;
    }
    used[best] = true;
    idx[bt * KK + r] = nn[best];
  }
}

// ============================================================
// anchor attention: gather(bf16) -> GEMM qkv -> core -> GEMMs
// ============================================================
__global__ void gather_kernel(const ushortt* __restrict__ ph,
                              const ushortt* __restrict__ delta,
                              const int* __restrict__ idx,
                              ushortt* __restrict__ tok) {
  int row = blockIdx.x;  // (b*KK+k)*16+t
  int t = row & 15;
  int bk = row >> 4;
  int b = bk >> 3, k = bk & 7;
  int a = threadIdx.x;
  int n = idx[(b * 16 + t) * KK + k];
  size_t off = ((size_t)(b * 16 + t) * Nn + n) * Aa + a;
  tok[(size_t)row * Aa + a] = f2bf(bf2f(ph[off]) + bf2f(delta[off]));
}

__global__ __launch_bounds__(256) void attn_core(
    const float* __restrict__ qkv, float* __restrict__ o) {
  constexpr int P = 580;
  __shared__ float sq[16 * P];
  __shared__ float ssc[4][16][17];
  int bk = blockIdx.x;
  int tid = threadIdx.x;
  const float* src = qkv + (size_t)bk * 16 * 576;
  for (int e = tid; e < 16 * 144; e += 256) {
    int r = e / 144, c4 = e % 144;
    float4 v = *(const float4*)(src + r * 576 + c4 * 4);
    *(float4*)(&sq[r * P + c4 * 4]) = v;
  }
  __syncthreads();
  int h = tid >> 6, lane = tid & 63;
#pragma unroll
  for (int s4 = 0; s4 < 4; ++s4) {
    int e = lane + 64 * s4;
    int i = e >> 4, j = e & 15;
    const float* q = sq + i * P + h * 48;
    const float* k2 = sq + j * P + 192 + h * 48;
    float s = 0.f;
#pragma unroll
    for (int d = 0; d < 48; ++d) s = fmaf(q[d], k2[d], s);
    ssc[h][i][j] = s * 0.14433756729740643f;  // 1/sqrt(48)
  }
  __syncthreads();
  if (lane < 16) {
    float* r = ssc[h][lane];
    float mx = r[0];
    for (int j = 1; j < 16; ++j) mx = fmaxf(mx, r[j]);
    float sum = 0.f;
    for (int j = 0; j < 16; ++j) {
      float ev = expf(r[j] - mx);
      r[j] = ev;
      sum += ev;
    }
    float inv = 1.0f / sum;
    for (int j = 0; j < 16; ++j) r[j] *= inv;
  }
  __syncthreads();
#pragma unroll
  for (int s4 = 0; s4 < 12; ++s4) {
    int e = lane + 64 * s4;
    int i = e / 48, d = e - i * 48;
    float s = 0.f;
#pragma unroll
    for (int j = 0; j < 16; ++j)
      s = fmaf(ssc[h][i][j], sq[j * P + 384 + h * 48 + d], s);
    o[((size_t)bk * 16 + i) * 192 + h * 48 + d] = s;
  }
}

__global__ void appart_kernel(const float* __restrict__ attout,
                              float* __restrict__ appart) {
  int bk = blockIdx.x;
  int a = threadIdx.x;
  float s = 0.f;
  for (int t = 0; t < Tt; ++t)
    s += attout[((size_t)bk * Tt + t) * Aa + a];
  appart[bk * Aa + a] = s;
}

// in-place fp32 LayerNorm over last dim (192); one wave per row
__global__ void ln32_kernel(float* __restrict__ buf,
                            const float* __restrict__ g,
                            const float* __restrict__ bb) {
  size_t row = (size_t)blockIdx.x * 4 + (threadIdx.x >> 6);
  int lane = threadIdx.x & 63;
  float* p = buf + row * Aa;
  float v0 = p[lane], v1 = p[lane + 64], v2 = p[lane + 128];
  float s = v0 + v1 + v2;
#pragma unroll
  for (int off = 32; off > 0; off >>= 1) s += __shfl_xor(s, off, 64);
  float m = s * (1.0f / 192.0f);
  float d0 = v0 - m, d1 = v1 - m, d2 = v2 - m;
  float ss = d0 * d0 + d1 * d1 + d2 * d2;
#pragma unroll
  for (int off = 32; off > 0; off >>= 1) ss += __shfl_xor(ss, off, 64);
  float inv = rsqrtf(ss * (1.0f / 192.0f) + 1e-5f);
  p[lane] = d0 * inv * g[lane] + bb[lane];
  p[lane + 64] = d1 * inv * g[lane + 64] + bb[lane + 64];
  p[lane + 128] = d2 * inv * g[lane + 128] + bb[lane + 128];
}

// depthwise 3x3 SAME conv over 14x14 + gelu; bf16 in/out
__global__ void conv2d_kernel(const ushortt* __restrict__ ph,
                              const float* __restrict__ ldw,
                              ushortt* __restrict__ og) {
  size_t e = (size_t)blockIdx.x * 256 + threadIdx.x;
  int a = (int)(e % Aa);
  size_t r = e / Aa;
  int n = (int)(r % Nn);
  int bt = (int)(r / Nn);
  int y = n / 14, x = n % 14;
  const ushortt* base = ph + (size_t)bt * Nn * Aa + a;
  const float* w = ldw + a * 9;
  float s = 0.f;
#pragma unroll
  for (int dy = -1; dy <= 1; ++dy) {
    int yy = y + dy;
    if (yy < 0 || yy >= 14) continue;
#pragma unroll
    for (int dx = -1; dx <= 1; ++dx) {
      int xc = x + dx;
      if (xc < 0 || xc >= 14) continue;
      s = fmaf(bf2f(base[(size_t)(yy * 14 + xc) * Aa]),
               w[(dy + 1) * 3 + (dx + 1)], s);
    }
  }
  og[e] = f2bf(gelu_f(s));
}

// depthwise k=3 SAME conv over t + gelu; bf16 in/out
__global__ void conv1d_kernel(const ushortt* __restrict__ delta,
                              const float* __restrict__ tdw,
                              ushortt* __restrict__ og) {
  size_t e = (size_t)blockIdx.x * 256 + threadIdx.x;
  int a = (int)(e % Aa);
  size_t r = e / Aa;
  int n = (int)(r % Nn);
  int bt = (int)(r / Nn);
  int t = bt & 15, b = bt >> 4;
  const float* w = tdw + a * 3;
  float s = 0.f;
#pragma unroll
  for (int j = 0; j < 3; ++j) {
    int tt = t + j - 1;
    if (tt >= 0 && tt < Tt)
      s = fmaf(bf2f(delta[((size_t)(b * Tt + tt) * Nn + n) * Aa + a]), w[j], s);
  }
  og[e] = f2bf(gelu_f(s));
}

// in-place LayerNorm over last dim (192); one wave per row (bf16)
__global__ void ln_kernel(ushortt* __restrict__ buf,
                          const float* __restrict__ g,
                          const float* __restrict__ bb) {
  size_t row = (size_t)blockIdx.x * 4 + (threadIdx.x >> 6);
  int lane = threadIdx.x & 63;
  ushortt* p = buf + row * Aa;
  float v0 = bf2f(p[lane]), v1 = bf2f(p[lane + 64]), v2 = bf2f(p[lane + 128]);
  float s = v0 + v1 + v2;
#pragma unroll
  for (int off = 32; off > 0; off >>= 1) s += __shfl_xor(s, off, 64);
  float m = s * (1.0f / 192.0f);
  float d0 = v0 - m, d1 = v1 - m, d2 = v2 - m;
  float ss = d0 * d0 + d1 * d1 + d2 * d2;
#pragma unroll
  for (int off = 32; off > 0; off >>= 1) ss += __shfl_xor(ss, off, 64);
  float inv = rsqrtf(ss * (1.0f / 192.0f) + 1e-5f);
  p[lane] = f2bf(d0 * inv * g[lane] + bb[lane]);
  p[lane + 64] = f2bf(d1 * inv * g[lane + 64] + bb[lane + 64]);
  p[lane + 128] = f2bf(d2 * inv * g[lane + 128] + bb[lane + 128]);
}

// posmap[bt*Nn + idx[bt,k]] = k+1 (posmap pre-zeroed)
__global__ void scatter_pos(const int* __restrict__ idx,
                            short* __restrict__ posmap) {
  int bt = blockIdx.x;
  int k = threadIdx.x;
  if (k < KK) posmap[bt * Nn + idx[bt * KK + k]] = (short)(k + 1);
}

// gate MLP + 3-way softmax; one block per b, 192 threads
__global__ void gate_kernel(const float* __restrict__ dppart,
                            const float* __restrict__ appart,
                            const float* __restrict__ w1,
                            const float* __restrict__ b1,
                            const float* __restrict__ w2,
                            const float* __restrict__ b2,
                            float* __restrict__ gw) {
  int b = blockIdx.x;
  __shared__ float sg[2 * Aa];
  __shared__ float sh[Aa];
  int tid = threadIdx.x;
  {
    float d = 0.f;
    for (int t2 = 0; t2 < Tt; ++t2) d += dppart[(b * Tt + t2) * Aa + tid];
    sg[tid] = d * (1.0f / 3136.0f);
    float a = 0.f;
    for (int k2 = 0; k2 < KK; ++k2) a += appart[(b * KK + k2) * Aa + tid];
    sg[Aa + tid] = a * (1.0f / 128.0f);
  }
  __syncthreads();
  {
    const float* w = w1 + (size_t)tid * 2 * Aa;
    float s = b1[tid];
#pragma unroll 8
    for (int j = 0; j < 2 * Aa; ++j) s = fmaf(sg[j], w[j], s);
    sh[tid] = gelu_f(s);
  }
  __syncthreads();
  float v[3];
#pragma unroll
  for (int i = 0; i < 3; ++i) {
    const float* w = w2 + (size_t)(i * Aa + tid) * Aa;
    float s = b2[i * Aa + tid];
#pragma unroll 8
    for (int j = 0; j < Aa; ++j) s = fmaf(sh[j], w[j], s);
    v[i] = s;
  }
  float mx = fmaxf(v[0], fmaxf(v[1], v[2]));
  float e0 = expf(v[0] - mx), e1 = expf(v[1] - mx), e2 = expf(v[2] - mx);
  float inv = 1.0f / (e0 + e1 + e2);
  gw[(b * 3 + 0) * Aa + tid] = e0 * inv;
  gw[(b * 3 + 1) * Aa + tid] = e1 * inv;
  gw[(b * 3 + 2) * Aa + tid] = e2 * inv;
}

// fused = gw0*local + gw1*trans + gw2*amap_ln; amap_ln from attln rows
// (anchors, via posmap) or anorm_b constant (non-anchors). fmean fp32.
__global__ void fused_kernel(const ushortt* __restrict__ local,
                             const ushortt* __restrict__ trans,
                             const float* __restrict__ attln,
                             const short* __restrict__ posmap,
                             const float* __restrict__ anb,
                             const float* __restrict__ gw,
                             ushortt* __restrict__ fused,
                             float* __restrict__ fmean) {
  int bt = blockIdx.x;
  int b = bt >> 4, t = bt & 15;
  int a = threadIdx.x;
  float g0 = gw[(b * 3 + 0) * Aa + a];
  float g1 = gw[(b * 3 + 1) * Aa + a];
  float g2 = gw[(b * 3 + 2) * Aa + a];
  float ab = anb[a];
  size_t base = (size_t)bt * Nn * Aa + a;
  float acc = 0.f;
  for (int n = 0; n < Nn; ++n) {
    size_t o = base + (size_t)n * Aa;
    short pos = posmap[bt * Nn + n];
    float am = pos ? attln[(((size_t)(b * KK + pos - 1) * Tt) + t) * Aa + a]
                   : ab;
    float f = g0 * bf2f(local[o]) + g1 * bf2f(trans[o]) + g2 * am;
    fused[o] = f2bf(f);
    acc += f;
  }
  fmean[bt * Aa + a] = acc;
}

// cls_out = cls_tok + (mean_n fused) @ cls_w.T + cls_b
__global__ void cls_kernel(const float* __restrict__ fmean,
                           const float* __restrict__ cw,
                           const float* __restrict__ cb,
                           const float* __restrict__ x,
                           float* __restrict__ out) {
  int bt = blockIdx.x;
  __shared__ float fm[Aa];
  int tid = threadIdx.x;
  if (tid < Aa) fm[tid] = fmean[bt * Aa + tid] * (1.0f / 196.0f);
  __syncthreads();
  for (int c = tid; c < Cc; c += 256) {
    const float* w = cw + (size_t)c * Aa;
    float s = cb[c];
#pragma unroll 8
    for (int a = 0; a < Aa; ++a) s = fmaf(fm[a], w[a], s);
    size_t off = (size_t)bt * (Nn + 1) * Cc + c;
    out[off] = x[off] + s;
  }
}

// ============================================================
extern "C" void kernel_launch(void* const* d_in, const int* in_sizes, int n_in,
                              void* d_out, int out_size, void* d_ws,
                              size_t ws_size, hipStream_t stream) {
  const float* x = (const float*)d_in[0];
  const float* down_w = (const float*)d_in[1];
  const float* down_b = (const float*)d_in[2];
  const float* ldw_w = (const float*)d_in[3];
  const float* lpw_w = (const float*)d_in[4];
  const float* lnorm_g = (const float*)d_in[5];
  const float* lnorm_b = (const float*)d_in[6];
  const float* tdw_w = (const float*)d_in[7];
  const float* tpw_w = (const float*)d_in[8];
  const float* tmlp_w1 = (const float*)d_in[9];
  const float* tmlp_b1 = (const float*)d_in[10];
  const float* tmlp_w2 = (const float*)d_in[11];
  const float* tmlp_b2 = (const float*)d_in[12];
  const float* tnorm_g = (const float*)d_in[13];
  const float* tnorm_b = (const float*)d_in[14];
  const float* attn_in_w = (const float*)d_in[15];
  const float* attn_in_b = (const float*)d_in[16];
  const float* attn_out_w = (const float*)d_in[17];
  const float* attn_out_b = (const float*)d_in[18];
  const float* aproj_w = (const float*)d_in[19];
  const float* aproj_b = (const float*)d_in[20];
  const float* anorm_g = (const float*)d_in[21];
  const float* anorm_b = (const float*)d_in[22];
  const float* gate_w1 = (const float*)d_in[23];
  const float* gate_b1 = (const float*)d_in[24];
  const float* gate_w2 = (const float*)d_in[25];
  const float* gate_b2 = (const float*)d_in[26];
  const float* up_w = (const float*)d_in[27];
  const float* up_b = (const float*)d_in[28];
  const float* cls_w = (const float*)d_in[29];
  const float* cls_b = (const float*)d_in[30];
  float* out = (float*)d_out;

  float* ws = (float*)d_ws;
  float* W0 = ws;              // ph bf16 -> trp bf16
  float* W1 = W0 + SZ;         // delta bf16 -> transition bf16
  float* W2 = W1 + SZ;         // attn scratch -> locg/trg/h1/fused bf16
  float* W3 = W2 + 2 * SZ;     // local bf16
  float* sal = W3 + SZ;
  float* attout = sal + BTN;
  float* dppart = attout + (size_t)BKT * Aa;
  float* appart = dppart + (size_t)BT * Aa;
  float* gw = appart + (size_t)Bb * KK * Aa;
  float* fmean = gw + (size_t)Bb * 3 * Aa;
  double* sal64 = (double*)(fmean + (size_t)BT * Aa);  // BT*NCAND doubles
  int* cand = (int*)(sal64 + (size_t)BT * NCAND);      // BT*NCAND ints
  int* idx = cand + (size_t)BT * NCAND;                // BT*KK ints
  float* wT = (float*)(idx + (size_t)BT * KK);         // Cc*Aa floats
  short* posmap = (short*)(wT + (size_t)Cc * Aa);      // BT*Nn shorts

  // bf16 activation views
  ushortt* ph_b    = (ushortt*)W0;
  ushortt* trp_b   = (ushortt*)W0;
  ushortt* delta_b = (ushortt*)W1;
  ushortt* trans_b = (ushortt*)W1;
  ushortt* locg_b  = (ushortt*)W2;
  ushortt* trg_b   = (ushortt*)W2;
  ushortt* h1_b    = (ushortt*)W2;
  ushortt* fused_b = (ushortt*)W2;
  ushortt* local_b = (ushortt*)W3;

  // attn-phase scratch inside W2 (dead until conv2d)
  ushortt* tok_b = (ushortt*)W2;                       // 2048*192 bf16
  float* qkvb  = W2 + (size_t)BKT * Aa / 2;            // 2048*576 f32
  float* obuf  = qkvb + (size_t)BKT * 3 * Aa;          // 2048*192 f32
  float* proj1 = obuf + (size_t)BKT * Aa;              // 2048*192 f32

  // 1. ph = patch @ down_w.T + down_b (bf16 out)
  gemm_mfma<float, ushortt, 1, 1, 0><<<dim3(2, 784), 256, 0, stream>>>(
      x, down_w, down_b, ph_b, nullptr, BTN, Aa, Cc);
  transpose_w<<<(Cc * Aa) / 256, 256, 0, stream>>>(down_w, wT);
  // 2. delta + dp partials
  delta_kernel<<<BT, Aa, 0, stream>>>(ph_b, delta_b, dppart);
  // 3. saliency: fp32 candidates -> f64 refine -> exact top-8
  sal_kernel<<<BTN / 4, 256, 0, stream>>>(delta_b, sal);
  topcand_kernel<<<BT, 64, 0, stream>>>(sal, cand);
  refine_kernel<<<dim3(BT, 2), 192, 0, stream>>>(x, wT, cand, sal64);
  select_kernel<<<BT, 64, 0, stream>>>(sal64, cand, idx);
  // 4. anchor attention
  gather_kernel<<<BKT, Aa, 0, stream>>>(ph_b, delta_b, idx, tok_b);
  gemm_mfma<ushortt, float, 0, 1, 0><<<dim3(6, 32), 256, 0, stream>>>(
      tok_b, attn_in_w, attn_in_b, qkvb, nullptr, BKT, 3 * Aa, Aa);
  attn_core<<<Bb * KK, 256, 0, stream>>>(qkvb, obuf);
  gemm_mfma<float, float, 0, 1, 0><<<dim3(2, 32), 256, 0, stream>>>(
      obuf, attn_out_w, attn_out_b, proj1, nullptr, BKT, Aa, Aa);
  gemm_mfma<float, float, 0, 1, 0><<<dim3(2, 32), 256, 0, stream>>>(
      proj1, aproj_w, aproj_b, attout, nullptr, BKT, Aa, Aa);
  appart_kernel<<<Bb * KK, Aa, 0, stream>>>(attout, appart);
  // 4b. LN the 2048 anchor rows in place (replaces full anchor-map LN)
  ln32_kernel<<<BKT / 4, 256, 0, stream>>>(attout, anorm_g, anorm_b);
  hipMemsetAsync(posmap, 0, (size_t)BT * Nn * sizeof(short), stream);
  scatter_pos<<<BT, 64, 0, stream>>>(idx, posmap);
  // 5. local branch
  conv2d_kernel<<<(unsigned)(SZ / 256), 256, 0, stream>>>(ph_b, ldw_w, locg_b);
  gemm_mfma<ushortt, ushortt, 0, 0, 0><<<dim3(2, 784), 256, 0, stream>>>(
      locg_b, lpw_w, nullptr, local_b, nullptr, BTN, Aa, Aa);
  ln_kernel<<<BTN / 4, 256, 0, stream>>>(local_b, lnorm_g, lnorm_b);
  // 6. transition branch
  conv1d_kernel<<<(unsigned)(SZ / 256), 256, 0, stream>>>(delta_b, tdw_w, trg_b);
  gemm_mfma<ushortt, ushortt, 0, 0, 0><<<dim3(2, 784), 256, 0, stream>>>(
      trg_b, tpw_w, nullptr, trp_b, nullptr, BTN, Aa, Aa);
  gemm_mfma<ushortt, ushortt, 0, 1, 1><<<dim3(4, 784), 256, 0, stream>>>(
      trp_b, tmlp_w1, tmlp_b1, h1_b, nullptr, BTN, 2 * Aa, Aa);
  gemm_mfma<ushortt, ushortt, 0, 1, 0><<<dim3(2, 784), 256, 0, stream>>>(
      h1_b, tmlp_w2, tmlp_b2, trans_b, nullptr, BTN, Aa, 2 * Aa);
  ln_kernel<<<BTN / 4, 256, 0, stream>>>(trans_b, tnorm_g, tnorm_b);
  // 8. gate
  gate_kernel<<<Bb, Aa, 0, stream>>>(dppart, appart, gate_w1, gate_b1,
                                     gate_w2, gate_b2, gw);
  // 9. fuse + output projections
  fused_kernel<<<BT, Aa, 0, stream>>>(local_b, trans_b, attout, posmap,
                                      anorm_b, gw, fused_b, fmean);
  gemm_mfma<ushortt, float, 0, 1, 2><<<dim3(8, 784), 256, 0, stream>>>(
      fused_b, up_w, up_b, out, x, BTN, Cc, Aa);
  cls_kernel<<<BT, 256, 0, stream>>>(fmean, cls_w, cls_b, x, out);
}

// Round 13
// 643.535 us; speedup vs baseline: 1.7221x; 1.0083x over previous
//
#include <hip/hip_runtime.h>
#include <hip/hip_bf16.h>
#include <math.h>

// ---- fixed problem dims ----
constexpr int Bb  = 16;
constexpr int Tt  = 16;
constexpr int Nn  = 196;   // patches (14x14)
constexpr int Cc  = 768;
constexpr int Aa  = 192;
constexpr int KK  = 8;     // TOPK
constexpr int NCAND = 16;  // fp32 candidates refined in f64
constexpr int BT  = Bb * Tt;            // 256
constexpr int BTN = BT * Nn;            // 50176
constexpr int BKT = Bb * KK * Tt;       // 2048 anchor-token rows
constexpr size_t SZ = (size_t)BTN * Aa; // 9,633,792 floats

typedef unsigned short ushortt;
typedef __attribute__((ext_vector_type(8))) short bf16x8;
typedef __attribute__((ext_vector_type(4))) float f32x4;
typedef __attribute__((ext_vector_type(4))) unsigned short u16x4;
typedef __attribute__((ext_vector_type(8))) unsigned short u16x8;

static __device__ __forceinline__ float gelu_f(float x) {
  return 0.5f * x * (1.0f + erff(x * 0.7071067811865476f));
}
// HARDWARE bf16 convert (v_cvt_pk_bf16_f32 path via HIP cast)
static __device__ __forceinline__ ushortt f2bf(float f) {
  __hip_bfloat16 h = __float2bfloat16(f);
  return *reinterpret_cast<ushortt*>(&h);
}
static __device__ __forceinline__ float bf2f(ushortt u) {
  return __uint_as_float(((unsigned)u) << 16);
}

// ============================================================
// bf16 MFMA GEMM: C[m,n] = sum_k A[m,k]*W[n,k] (+bias)(+epilogue)
// AT: float (staged->bf16) or ushort (bf16). CT: float or ushort.
// BM=64 BN=96 BK=64 (r12: BK doubled to halve barrier-drain count;
// 12 MFMA/step, 12 steps at K=768). 256 thr = 4 waves (2x2), wave
// tile 32x48. LDS 46 KB -> 3 blocks/CU (12 waves, = r11 measured).
// Single-pass LDS-staged coalesced epilogue (reuses staging LDS).
// EPI: 0 plain, 1 gelu, 2 mapped residual fp32.
// Grid (Nc/96, M/64); col-fastest + bijective XCD swizzle (nwg%8==0).
// ============================================================
template <typename AT, typename CT, int ROWMAP, int BIAS, int EPI>
__global__ __launch_bounds__(256) void gemm_mfma(
    const AT* __restrict__ Ain, const float* __restrict__ W,
    const float* __restrict__ bias, CT* __restrict__ Cout,
    const float* __restrict__ resid, int M, int Nc, int K) {
  constexpr int PIT = 72;  // bf16 pitch (64+8 pad) -> worst 2-way (free)
  __shared__ __align__(16) unsigned char smem[(2 * 64 * PIT + 2 * 96 * PIT) * 2];
  ushortt (*As)[64 * PIT] = (ushortt(*)[64 * PIT])smem;
  ushortt (*Bs)[96 * PIT] = (ushortt(*)[96 * PIT])(smem + 2 * 64 * PIT * 2);
  const int tid = threadIdx.x;

  const int ncb = gridDim.x;
  const int nwg = ncb * gridDim.y;
  const int bid = blockIdx.y * ncb + blockIdx.x;
  const int cpx = nwg >> 3;
  const int swz = (bid & 7) * cpx + (bid >> 3);
  const int row0 = (swz / ncb) * 64;
  const int col0 = (swz % ncb) * 96;

  const int wid = tid >> 6;
  const int lane = tid & 63;
  const int wr = wid >> 1;       // 0..1 -> +32 rows
  const int wc = wid & 1;        // 0..1 -> +48 cols
  const int l15 = lane & 15;
  const int kgrp = lane >> 4;    // 0..3

  const int q16 = tid & 15;      // float4 index within 64-k row (16 of them)
  const int q8 = tid & 7;        // u16x8 index within 64-k row (8 of them)

  const int nsteps = K >> 6;

  // A row pointers
  const float* arowf[4];
  const ushortt* arowb[2];
  if constexpr (sizeof(AT) == 4) {
#pragma unroll
    for (int p = 0; p < 4; ++p) {
      int r = row0 + (tid >> 4) + 16 * p;
      if (ROWMAP) {
        int bt = r / Nn;
        int n = r - bt * Nn;
        arowf[p] = (const float*)Ain + (size_t)(bt * (Nn + 1) + 1 + n) * K;
      } else {
        arowf[p] = (const float*)Ain + (size_t)r * K;
      }
    }
  } else {
#pragma unroll
    for (int p = 0; p < 2; ++p)
      arowb[p] = (const ushortt*)Ain + (size_t)(row0 + (tid >> 3) + 32 * p) * K;
  }
  const float* browp[6];
#pragma unroll
  for (int p = 0; p < 6; ++p)
    browp[p] = W + (size_t)(col0 + (tid >> 4) + 16 * p) * K;

  f32x4 acc[2][3];
#pragma unroll
  for (int i = 0; i < 2; ++i)
#pragma unroll
    for (int j = 0; j < 3; ++j) acc[i][j] = (f32x4){0.f, 0.f, 0.f, 0.f};

  float4 apre[4], bpre[6];
  u16x8 apreb[2];

#define STAGE_LOAD(k0)                                                       \
  if constexpr (sizeof(AT) == 4) {                                           \
    _Pragma("unroll") for (int p = 0; p < 4; ++p)                            \
        apre[p] = *(const float4*)(arowf[p] + (k0) + q16 * 4);               \
  } else {                                                                   \
    _Pragma("unroll") for (int p = 0; p < 2; ++p)                            \
        apreb[p] = *(const u16x8*)(arowb[p] + (k0) + q8 * 8);                \
  }                                                                          \
  _Pragma("unroll") for (int p = 0; p < 6; ++p)                              \
      bpre[p] = *(const float4*)(browp[p] + (k0) + q16 * 4);

#define STAGE_WRITE(buf)                                                     \
  if constexpr (sizeof(AT) == 4) {                                           \
    _Pragma("unroll") for (int p = 0; p < 4; ++p) {                          \
      u16x4 b = {f2bf(apre[p].x), f2bf(apre[p].y), f2bf(apre[p].z),          \
                 f2bf(apre[p].w)};                                           \
      *(u16x4*)&As[buf][((tid >> 4) + 16 * p) * PIT + q16 * 4] = b;          \
    }                                                                        \
  } else {                                                                   \
    _Pragma("unroll") for (int p = 0; p < 2; ++p)                            \
        *(u16x8*)&As[buf][((tid >> 3) + 32 * p) * PIT + q8 * 8] = apreb[p];  \
  }                                                                          \
  _Pragma("unroll") for (int p = 0; p < 6; ++p) {                            \
    u16x4 b = {f2bf(bpre[p].x), f2bf(bpre[p].y), f2bf(bpre[p].z),            \
               f2bf(bpre[p].w)};                                             \
    *(u16x4*)&Bs[buf][((tid >> 4) + 16 * p) * PIT + q16 * 4] = b;            \
  }

  STAGE_LOAD(0);
  STAGE_WRITE(0);
  __syncthreads();

  int cur = 0;
  for (int step = 0; step < nsteps; ++step) {
    const bool pref = (step + 1 < nsteps);
    if (pref) {
      int k0 = (step + 1) << 6;
      STAGE_LOAD(k0);
    }
    // two K=32 halves per step, k-order preserved (0..31 then 32..63)
#pragma unroll
    for (int kk = 0; kk < 2; ++kk) {
      bf16x8 af[2], bfv[3];
#pragma unroll
      for (int fm = 0; fm < 2; ++fm)
        af[fm] = *(const bf16x8*)&As[cur][(wr * 32 + fm * 16 + l15) * PIT +
                                          kk * 32 + kgrp * 8];
#pragma unroll
      for (int fn = 0; fn < 3; ++fn)
        bfv[fn] = *(const bf16x8*)&Bs[cur][(wc * 48 + fn * 16 + l15) * PIT +
                                           kk * 32 + kgrp * 8];
#pragma unroll
      for (int fm = 0; fm < 2; ++fm)
#pragma unroll
        for (int fn = 0; fn < 3; ++fn)
          acc[fm][fn] = __builtin_amdgcn_mfma_f32_16x16x32_bf16(
              af[fm], bfv[fn], acc[fm][fn], 0, 0, 0);
    }
    if (pref) {
      STAGE_WRITE(cur ^ 1);
    }
    __syncthreads();
    cur ^= 1;
  }
#undef STAGE_LOAD
#undef STAGE_WRITE

  // ---- single-pass LDS-staged epilogue: coalesced global stores ----
  constexpr int EP = 100;  // fp32 pitch for 96 cols (+4 pad)
  float* epi = (float*)smem;  // 64*100*4 = 25600 B <= 46080 B
#pragma unroll
  for (int fm = 0; fm < 2; ++fm) {
    int rl = wr * 32 + fm * 16 + kgrp * 4;
#pragma unroll
    for (int fn = 0; fn < 3; ++fn) {
      int cl = wc * 48 + fn * 16 + l15;
#pragma unroll
      for (int j = 0; j < 4; ++j)
        epi[(rl + j) * EP + cl] = acc[fm][fn][j];
    }
  }
  __syncthreads();
#pragma unroll
  for (int it = 0; it < 6; ++it) {
    int f = it * 256 + tid;        // 0..1535 over 64 rows x 24 float4
    int r = f / 24, c4 = f - r * 24;
    float4 v = *(const float4*)&epi[r * EP + c4 * 4];
    int c = col0 + c4 * 4;
    if (BIAS) {
      float4 bv = *(const float4*)(bias + c);
      v.x += bv.x; v.y += bv.y; v.z += bv.z; v.w += bv.w;
    }
    if (EPI == 1) {
      v.x = gelu_f(v.x); v.y = gelu_f(v.y);
      v.z = gelu_f(v.z); v.w = gelu_f(v.w);
    }
    int R = row0 + r;
    if constexpr (EPI == 2) {
      int bt2 = R / Nn, n2 = R - bt2 * Nn;
      size_t off = (size_t)(bt2 * (Nn + 1) + 1 + n2) * Nc + c;
      float4 rv = *(const float4*)(resid + off);
      v.x += rv.x; v.y += rv.y; v.z += rv.z; v.w += rv.w;
      *(float4*)((float*)Cout + off) = v;
    } else if constexpr (sizeof(CT) == 4) {
      *(float4*)((float*)Cout + (size_t)R * Nc + c) = v;
    } else {
      u16x4 ob = {f2bf(v.x), f2bf(v.y), f2bf(v.z), f2bf(v.w)};
      *(u16x4*)((ushortt*)Cout + (size_t)R * Nc + c) = ob;
    }
  }
}

// ============================================================
// delta (bf16) + per-(b,t) |delta| partials
// ============================================================
__global__ void delta_kernel(const ushortt* __restrict__ ph,
                             ushortt* __restrict__ delta,
                             float* __restrict__ dppart) {
  int bt = blockIdx.x;
  int t = bt & 15;
  int a = threadIdx.x;
  const ushortt* cur = ph + (size_t)bt * Nn * Aa + a;
  ushortt* dl = delta + (size_t)bt * Nn * Aa + a;
  float acc = 0.f;
  if (t == 0) {
    for (int n = 0; n < Nn; ++n) dl[(size_t)n * Aa] = 0;
  } else {
    const ushortt* prev = cur - (size_t)Nn * Aa;
    for (int n = 0; n < Nn; ++n) {
      float d = bf2f(cur[(size_t)n * Aa]) - bf2f(prev[(size_t)n * Aa]);
      dl[(size_t)n * Aa] = f2bf(d);
      acc += fabsf(d);
    }
  }
  dppart[bt * Aa + a] = acc;
}

// sal[row] = mean_a |delta[row,a]| (fp32, candidate stage only)
__global__ void sal_kernel(const ushortt* __restrict__ delta,
                           float* __restrict__ sal) {
  int row = blockIdx.x * 4 + (threadIdx.x >> 6);
  int lane = threadIdx.x & 63;
  const ushortt* d = delta + (size_t)row * Aa;
  float s = fabsf(bf2f(d[lane])) + fabsf(bf2f(d[lane + 64])) +
            fabsf(bf2f(d[lane + 128]));
#pragma unroll
  for (int off = 32; off > 0; off >>= 1) s += __shfl_xor(s, off, 64);
  if (lane == 0) sal[row] = s * (1.0f / 192.0f);
}

// ============================================================
// top-16 fp32 candidates per (b,t); descending val, ties -> smaller n
// ============================================================
__global__ void topcand_kernel(const float* __restrict__ sal,
                               int* __restrict__ cand) {
  int bt = blockIdx.x;
  int lane = threadIdx.x;
  unsigned long long key[4];
#pragma unroll
  for (int j = 0; j < 4; ++j) {
    int n = lane + 64 * j;
    if (n < Nn) {
      unsigned fb = __float_as_uint(sal[(size_t)bt * Nn + n]);
      key[j] = ((unsigned long long)fb << 32) |
               (unsigned long long)(0xFFFFFFFFu - (unsigned)n);
    } else {
      key[j] = 0ULL;
    }
  }
  for (int r = 0; r < NCAND; ++r) {
    unsigned long long m = key[0];
    if (key[1] > m) m = key[1];
    if (key[2] > m) m = key[2];
    if (key[3] > m) m = key[3];
#pragma unroll
    for (int off = 32; off > 0; off >>= 1) {
      unsigned long long o = __shfl_xor(m, off, 64);
      if (o > m) m = o;
    }
    if (lane == 0)
      cand[bt * NCAND + r] = (int)(0xFFFFFFFFu - (unsigned)(m & 0xFFFFFFFFull));
#pragma unroll
    for (int j = 0; j < 4; ++j)
      if (key[j] == m) key[j] = 0ULL;
  }
}

// one-time transpose: wT[c][a] = down_w[a][c]
__global__ void transpose_w(const float* __restrict__ w,
                            float* __restrict__ wT) {
  int e = blockIdx.x * 256 + threadIdx.x;  // over Cc*Aa
  int c = e / Aa, a = e - c * Aa;
  wT[e] = w[(size_t)a * Cc + c];
}

// ============================================================
// f64 refine, 8 candidates per block (grid BT x 2, 192 thr).
// diff staged once in LDS (f64); w read COALESCED via wT[c][a].
// ============================================================
__global__ __launch_bounds__(192) void refine_kernel(
    const float* __restrict__ x, const float* __restrict__ wT,
    const int* __restrict__ cand, double* __restrict__ sal64) {
  int bt = blockIdx.x;
  int grp = blockIdx.y;
  int t = bt & 15;
  int a = threadIdx.x;
  if (t == 0) {
    if (a < 8) sal64[bt * NCAND + grp * 8 + a] = 0.0;
    return;
  }
  __shared__ double sdiff[8][Cc];  // 49 KB
  const float* xt = x + ((size_t)bt * (Nn + 1) + 1) * Cc;
  const float* xp = xt - (size_t)(Nn + 1) * Cc;
  for (int g = 0; g < 8; ++g) {
    int n = cand[bt * NCAND + grp * 8 + g];
    const float* rt = xt + (size_t)n * Cc;
    const float* rp = xp + (size_t)n * Cc;
    for (int c = a; c < Cc; c += 192)
      sdiff[g][c] = (double)rt[c] - (double)rp[c];
  }
  __syncthreads();
  double acc[8] = {};
  for (int c = 0; c < Cc; ++c) {
    double wv = (double)wT[(size_t)c * Aa + a];  // coalesced across lanes
#pragma unroll
    for (int g = 0; g < 8; ++g) acc[g] = fma(wv, sdiff[g][c], acc[g]);
  }
  __shared__ double part[3][8];
  int wvx = a >> 6, ln = a & 63;
#pragma unroll
  for (int g = 0; g < 8; ++g) {
    double v = fabs(acc[g]);
#pragma unroll
    for (int off = 32; off > 0; off >>= 1) v += __shfl_xor(v, off, 64);
    if (ln == 0) part[wvx][g] = v;
  }
  __syncthreads();
  if (a < 8) {
    double s = part[0][a] + part[1][a] + part[2][a];
    sal64[bt * NCAND + grp * 8 + a] = s * (1.0 / 192.0);
  }
}

// final top-8 by (sal64 desc, n asc)
__global__ void select_kernel(const double* __restrict__ sal64,
                              const int* __restrict__ cand,
                              int* __restrict__ idx) {
  int bt = blockIdx.x;
  int t = bt & 15;
  if (threadIdx.x != 0) return;
  if (t == 0) {
    for (int r = 0; r < KK; ++r) idx[bt * KK + r] = r;
    return;
  }
  double v[NCAND];
  int nn[NCAND];
  bool used[NCAND];
  for (int i = 0; i < NCAND; ++i) {
    v[i] = sal64[bt * NCAND + i];
    nn[i] = cand[bt * NCAND + i];
    used[i] = false;
  }
  for (int r = 0; r < KK; ++r) {
    int best = -1;
    for (int i = 0; i < NCAND; ++i) {
      if (used[i]) continue;
      if (best < 0 || v[i] > v[best] ||
          (v[i] == v[best] && nn[i] < nn[best]))
        best = i;
    }
    used[best] = true;
    idx[bt * KK + r] = nn[best];
  }
}

// ============================================================
// anchor attention: gather(bf16) -> GEMM qkv -> core -> GEMMs
// ============================================================
__global__ void gather_kernel(const ushortt* __restrict__ ph,
                              const ushortt* __restrict__ delta,
                              const int* __restrict__ idx,
                              ushortt* __restrict__ tok) {
  int row = blockIdx.x;  // (b*KK+k)*16+t
  int t = row & 15;
  int bk = row >> 4;
  int b = bk >> 3, k = bk & 7;
  int a = threadIdx.x;
  int n = idx[(b * 16 + t) * KK + k];
  size_t off = ((size_t)(b * 16 + t) * Nn + n) * Aa + a;
  tok[(size_t)row * Aa + a] = f2bf(bf2f(ph[off]) + bf2f(delta[off]));
}

__global__ __launch_bounds__(256) void attn_core(
    const float* __restrict__ qkv, float* __restrict__ o) {
  constexpr int P = 580;
  __shared__ float sq[16 * P];
  __shared__ float ssc[4][16][17];
  int bk = blockIdx.x;
  int tid = threadIdx.x;
  const float* src = qkv + (size_t)bk * 16 * 576;
  for (int e = tid; e < 16 * 144; e += 256) {
    int r = e / 144, c4 = e % 144;
    float4 v = *(const float4*)(src + r * 576 + c4 * 4);
    *(float4*)(&sq[r * P + c4 * 4]) = v;
  }
  __syncthreads();
  int h = tid >> 6, lane = tid & 63;
#pragma unroll
  for (int s4 = 0; s4 < 4; ++s4) {
    int e = lane + 64 * s4;
    int i = e >> 4, j = e & 15;
    const float* q = sq + i * P + h * 48;
    const float* k2 = sq + j * P + 192 + h * 48;
    float s = 0.f;
#pragma unroll
    for (int d = 0; d < 48; ++d) s = fmaf(q[d], k2[d], s);
    ssc[h][i][j] = s * 0.14433756729740643f;  // 1/sqrt(48)
  }
  __syncthreads();
  if (lane < 16) {
    float* r = ssc[h][lane];
    float mx = r[0];
    for (int j = 1; j < 16; ++j) mx = fmaxf(mx, r[j]);
    float sum = 0.f;
    for (int j = 0; j < 16; ++j) {
      float ev = expf(r[j] - mx);
      r[j] = ev;
      sum += ev;
    }
    float inv = 1.0f / sum;
    for (int j = 0; j < 16; ++j) r[j] *= inv;
  }
  __syncthreads();
#pragma unroll
  for (int s4 = 0; s4 < 12; ++s4) {
    int e = lane + 64 * s4;
    int i = e / 48, d = e - i * 48;
    float s = 0.f;
#pragma unroll
    for (int j = 0; j < 16; ++j)
      s = fmaf(ssc[h][i][j], sq[j * P + 384 + h * 48 + d], s);
    o[((size_t)bk * 16 + i) * 192 + h * 48 + d] = s;
  }
}

__global__ void appart_kernel(const float* __restrict__ attout,
                              float* __restrict__ appart) {
  int bk = blockIdx.x;
  int a = threadIdx.x;
  float s = 0.f;
  for (int t = 0; t < Tt; ++t)
    s += attout[((size_t)bk * Tt + t) * Aa + a];
  appart[bk * Aa + a] = s;
}

// in-place fp32 LayerNorm over last dim (192); one wave per row
__global__ void ln32_kernel(float* __restrict__ buf,
                            const float* __restrict__ g,
                            const float* __restrict__ bb) {
  size_t row = (size_t)blockIdx.x * 4 + (threadIdx.x >> 6);
  int lane = threadIdx.x & 63;
  float* p = buf + row * Aa;
  float v0 = p[lane], v1 = p[lane + 64], v2 = p[lane + 128];
  float s = v0 + v1 + v2;
#pragma unroll
  for (int off = 32; off > 0; off >>= 1) s += __shfl_xor(s, off, 64);
  float m = s * (1.0f / 192.0f);
  float d0 = v0 - m, d1 = v1 - m, d2 = v2 - m;
  float ss = d0 * d0 + d1 * d1 + d2 * d2;
#pragma unroll
  for (int off = 32; off > 0; off >>= 1) ss += __shfl_xor(ss, off, 64);
  float inv = rsqrtf(ss * (1.0f / 192.0f) + 1e-5f);
  p[lane] = d0 * inv * g[lane] + bb[lane];
  p[lane + 64] = d1 * inv * g[lane + 64] + bb[lane + 64];
  p[lane + 128] = d2 * inv * g[lane + 128] + bb[lane + 128];
}

// depthwise 3x3 SAME conv over 14x14 + gelu; bf16 in/out
__global__ void conv2d_kernel(const ushortt* __restrict__ ph,
                              const float* __restrict__ ldw,
                              ushortt* __restrict__ og) {
  size_t e = (size_t)blockIdx.x * 256 + threadIdx.x;
  int a = (int)(e % Aa);
  size_t r = e / Aa;
  int n = (int)(r % Nn);
  int bt = (int)(r / Nn);
  int y = n / 14, x = n % 14;
  const ushortt* base = ph + (size_t)bt * Nn * Aa + a;
  const float* w = ldw + a * 9;
  float s = 0.f;
#pragma unroll
  for (int dy = -1; dy <= 1; ++dy) {
    int yy = y + dy;
    if (yy < 0 || yy >= 14) continue;
#pragma unroll
    for (int dx = -1; dx <= 1; ++dx) {
      int xc = x + dx;
      if (xc < 0 || xc >= 14) continue;
      s = fmaf(bf2f(base[(size_t)(yy * 14 + xc) * Aa]),
               w[(dy + 1) * 3 + (dx + 1)], s);
    }
  }
  og[e] = f2bf(gelu_f(s));
}

// depthwise k=3 SAME conv over t + gelu; bf16 in/out
__global__ void conv1d_kernel(const ushortt* __restrict__ delta,
                              const float* __restrict__ tdw,
                              ushortt* __restrict__ og) {
  size_t e = (size_t)blockIdx.x * 256 + threadIdx.x;
  int a = (int)(e % Aa);
  size_t r = e / Aa;
  int n = (int)(r % Nn);
  int bt = (int)(r / Nn);
  int t = bt & 15, b = bt >> 4;
  const float* w = tdw + a * 3;
  float s = 0.f;
#pragma unroll
  for (int j = 0; j < 3; ++j) {
    int tt = t + j - 1;
    if (tt >= 0 && tt < Tt)
      s = fmaf(bf2f(delta[((size_t)(b * Tt + tt) * Nn + n) * Aa + a]), w[j], s);
  }
  og[e] = f2bf(gelu_f(s));
}

// in-place LayerNorm over last dim (192); one wave per row (bf16)
__global__ void ln_kernel(ushortt* __restrict__ buf,
                          const float* __restrict__ g,
                          const float* __restrict__ bb) {
  size_t row = (size_t)blockIdx.x * 4 + (threadIdx.x >> 6);
  int lane = threadIdx.x & 63;
  ushortt* p = buf + row * Aa;
  float v0 = bf2f(p[lane]), v1 = bf2f(p[lane + 64]), v2 = bf2f(p[lane + 128]);
  float s = v0 + v1 + v2;
#pragma unroll
  for (int off = 32; off > 0; off >>= 1) s += __shfl_xor(s, off, 64);
  float m = s * (1.0f / 192.0f);
  float d0 = v0 - m, d1 = v1 - m, d2 = v2 - m;
  float ss = d0 * d0 + d1 * d1 + d2 * d2;
#pragma unroll
  for (int off = 32; off > 0; off >>= 1) ss += __shfl_xor(ss, off, 64);
  float inv = rsqrtf(ss * (1.0f / 192.0f) + 1e-5f);
  p[lane] = f2bf(d0 * inv * g[lane] + bb[lane]);
  p[lane + 64] = f2bf(d1 * inv * g[lane + 64] + bb[lane + 64]);
  p[lane + 128] = f2bf(d2 * inv * g[lane + 128] + bb[lane + 128]);
}

// posmap[bt*Nn + idx[bt,k]] = k+1 (posmap pre-zeroed)
__global__ void scatter_pos(const int* __restrict__ idx,
                            short* __restrict__ posmap) {
  int bt = blockIdx.x;
  int k = threadIdx.x;
  if (k < KK) posmap[bt * Nn + idx[bt * KK + k]] = (short)(k + 1);
}

// gate MLP + 3-way softmax; one block per b, 192 threads
__global__ void gate_kernel(const float* __restrict__ dppart,
                            const float* __restrict__ appart,
                            const float* __restrict__ w1,
                            const float* __restrict__ b1,
                            const float* __restrict__ w2,
                            const float* __restrict__ b2,
                            float* __restrict__ gw) {
  int b = blockIdx.x;
  __shared__ float sg[2 * Aa];
  __shared__ float sh[Aa];
  int tid = threadIdx.x;
  {
    float d = 0.f;
    for (int t2 = 0; t2 < Tt; ++t2) d += dppart[(b * Tt + t2) * Aa + tid];
    sg[tid] = d * (1.0f / 3136.0f);
    float a = 0.f;
    for (int k2 = 0; k2 < KK; ++k2) a += appart[(b * KK + k2) * Aa + tid];
    sg[Aa + tid] = a * (1.0f / 128.0f);
  }
  __syncthreads();
  {
    const float* w = w1 + (size_t)tid * 2 * Aa;
    float s = b1[tid];
#pragma unroll 8
    for (int j = 0; j < 2 * Aa; ++j) s = fmaf(sg[j], w[j], s);
    sh[tid] = gelu_f(s);
  }
  __syncthreads();
  float v[3];
#pragma unroll
  for (int i = 0; i < 3; ++i) {
    const float* w = w2 + (size_t)(i * Aa + tid) * Aa;
    float s = b2[i * Aa + tid];
#pragma unroll 8
    for (int j = 0; j < Aa; ++j) s = fmaf(sh[j], w[j], s);
    v[i] = s;
  }
  float mx = fmaxf(v[0], fmaxf(v[1], v[2]));
  float e0 = expf(v[0] - mx), e1 = expf(v[1] - mx), e2 = expf(v[2] - mx);
  float inv = 1.0f / (e0 + e1 + e2);
  gw[(b * 3 + 0) * Aa + tid] = e0 * inv;
  gw[(b * 3 + 1) * Aa + tid] = e1 * inv;
  gw[(b * 3 + 2) * Aa + tid] = e2 * inv;
}

// fused = gw0*local + gw1*trans + gw2*amap_ln; amap_ln from attln rows
// (anchors, via posmap) or anorm_b constant (non-anchors). fmean fp32.
__global__ void fused_kernel(const ushortt* __restrict__ local,
                             const ushortt* __restrict__ trans,
                             const float* __restrict__ attln,
                             const short* __restrict__ posmap,
                             const float* __restrict__ anb,
                             const float* __restrict__ gw,
                             ushortt* __restrict__ fused,
                             float* __restrict__ fmean) {
  int bt = blockIdx.x;
  int b = bt >> 4, t = bt & 15;
  int a = threadIdx.x;
  float g0 = gw[(b * 3 + 0) * Aa + a];
  float g1 = gw[(b * 3 + 1) * Aa + a];
  float g2 = gw[(b * 3 + 2) * Aa + a];
  float ab = anb[a];
  size_t base = (size_t)bt * Nn * Aa + a;
  float acc = 0.f;
  for (int n = 0; n < Nn; ++n) {
    size_t o = base + (size_t)n * Aa;
    short pos = posmap[bt * Nn + n];
    float am = pos ? attln[(((size_t)(b * KK + pos - 1) * Tt) + t) * Aa + a]
                   : ab;
    float f = g0 * bf2f(local[o]) + g1 * bf2f(trans[o]) + g2 * am;
    fused[o] = f2bf(f);
    acc += f;
  }
  fmean[bt * Aa + a] = acc;
}

// cls_out = cls_tok + (mean_n fused) @ cls_w.T + cls_b
__global__ void cls_kernel(const float* __restrict__ fmean,
                           const float* __restrict__ cw,
                           const float* __restrict__ cb,
                           const float* __restrict__ x,
                           float* __restrict__ out) {
  int bt = blockIdx.x;
  __shared__ float fm[Aa];
  int tid = threadIdx.x;
  if (tid < Aa) fm[tid] = fmean[bt * Aa + tid] * (1.0f / 196.0f);
  __syncthreads();
  for (int c = tid; c < Cc; c += 256) {
    const float* w = cw + (size_t)c * Aa;
    float s = cb[c];
#pragma unroll 8
    for (int a = 0; a < Aa; ++a) s = fmaf(fm[a], w[a], s);
    size_t off = (size_t)bt * (Nn + 1) * Cc + c;
    out[off] = x[off] + s;
  }
}

// ============================================================
extern "C" void kernel_launch(void* const* d_in, const int* in_sizes, int n_in,
                              void* d_out, int out_size, void* d_ws,
                              size_t ws_size, hipStream_t stream) {
  const float* x = (const float*)d_in[0];
  const float* down_w = (const float*)d_in[1];
  const float* down_b = (const float*)d_in[2];
  const float* ldw_w = (const float*)d_in[3];
  const float* lpw_w = (const float*)d_in[4];
  const float* lnorm_g = (const float*)d_in[5];
  const float* lnorm_b = (const float*)d_in[6];
  const float* tdw_w = (const float*)d_in[7];
  const float* tpw_w = (const float*)d_in[8];
  const float* tmlp_w1 = (const float*)d_in[9];
  const float* tmlp_b1 = (const float*)d_in[10];
  const float* tmlp_w2 = (const float*)d_in[11];
  const float* tmlp_b2 = (const float*)d_in[12];
  const float* tnorm_g = (const float*)d_in[13];
  const float* tnorm_b = (const float*)d_in[14];
  const float* attn_in_w = (const float*)d_in[15];
  const float* attn_in_b = (const float*)d_in[16];
  const float* attn_out_w = (const float*)d_in[17];
  const float* attn_out_b = (const float*)d_in[18];
  const float* aproj_w = (const float*)d_in[19];
  const float* aproj_b = (const float*)d_in[20];
  const float* anorm_g = (const float*)d_in[21];
  const float* anorm_b = (const float*)d_in[22];
  const float* gate_w1 = (const float*)d_in[23];
  const float* gate_b1 = (const float*)d_in[24];
  const float* gate_w2 = (const float*)d_in[25];
  const float* gate_b2 = (const float*)d_in[26];
  const float* up_w = (const float*)d_in[27];
  const float* up_b = (const float*)d_in[28];
  const float* cls_w = (const float*)d_in[29];
  const float* cls_b = (const float*)d_in[30];
  float* out = (float*)d_out;

  float* ws = (float*)d_ws;
  float* W0 = ws;              // ph bf16 -> trp bf16
  float* W1 = W0 + SZ;         // delta bf16 -> transition bf16
  float* W2 = W1 + SZ;         // attn scratch -> locg/trg/h1/fused bf16
  float* W3 = W2 + 2 * SZ;     // local bf16
  float* sal = W3 + SZ;
  float* attout = sal + BTN;
  float* dppart = attout + (size_t)BKT * Aa;
  float* appart = dppart + (size_t)BT * Aa;
  float* gw = appart + (size_t)Bb * KK * Aa;
  float* fmean = gw + (size_t)Bb * 3 * Aa;
  double* sal64 = (double*)(fmean + (size_t)BT * Aa);  // BT*NCAND doubles
  int* cand = (int*)(sal64 + (size_t)BT * NCAND);      // BT*NCAND ints
  int* idx = cand + (size_t)BT * NCAND;                // BT*KK ints
  float* wT = (float*)(idx + (size_t)BT * KK);         // Cc*Aa floats
  short* posmap = (short*)(wT + (size_t)Cc * Aa);      // BT*Nn shorts

  // bf16 activation views
  ushortt* ph_b    = (ushortt*)W0;
  ushortt* trp_b   = (ushortt*)W0;
  ushortt* delta_b = (ushortt*)W1;
  ushortt* trans_b = (ushortt*)W1;
  ushortt* locg_b  = (ushortt*)W2;
  ushortt* trg_b   = (ushortt*)W2;
  ushortt* h1_b    = (ushortt*)W2;
  ushortt* fused_b = (ushortt*)W2;
  ushortt* local_b = (ushortt*)W3;

  // attn-phase scratch inside W2 (dead until conv2d)
  ushortt* tok_b = (ushortt*)W2;                       // 2048*192 bf16
  float* qkvb  = W2 + (size_t)BKT * Aa / 2;            // 2048*576 f32
  float* obuf  = qkvb + (size_t)BKT * 3 * Aa;          // 2048*192 f32
  float* proj1 = obuf + (size_t)BKT * Aa;              // 2048*192 f32

  // 1. ph = patch @ down_w.T + down_b (bf16 out)
  gemm_mfma<float, ushortt, 1, 1, 0><<<dim3(2, 784), 256, 0, stream>>>(
      x, down_w, down_b, ph_b, nullptr, BTN, Aa, Cc);
  transpose_w<<<(Cc * Aa) / 256, 256, 0, stream>>>(down_w, wT);
  // 2. delta + dp partials
  delta_kernel<<<BT, Aa, 0, stream>>>(ph_b, delta_b, dppart);
  // 3. saliency: fp32 candidates -> f64 refine -> exact top-8
  sal_kernel<<<BTN / 4, 256, 0, stream>>>(delta_b, sal);
  topcand_kernel<<<BT, 64, 0, stream>>>(sal, cand);
  refine_kernel<<<dim3(BT, 2), 192, 0, stream>>>(x, wT, cand, sal64);
  select_kernel<<<BT, 64, 0, stream>>>(sal64, cand, idx);
  // 4. anchor attention
  gather_kernel<<<BKT, Aa, 0, stream>>>(ph_b, delta_b, idx, tok_b);
  gemm_mfma<ushortt, float, 0, 1, 0><<<dim3(6, 32), 256, 0, stream>>>(
      tok_b, attn_in_w, attn_in_b, qkvb, nullptr, BKT, 3 * Aa, Aa);
  attn_core<<<Bb * KK, 256, 0, stream>>>(qkvb, obuf);
  gemm_mfma<float, float, 0, 1, 0><<<dim3(2, 32), 256, 0, stream>>>(
      obuf, attn_out_w, attn_out_b, proj1, nullptr, BKT, Aa, Aa);
  gemm_mfma<float, float, 0, 1, 0><<<dim3(2, 32), 256, 0, stream>>>(
      proj1, aproj_w, aproj_b, attout, nullptr, BKT, Aa, Aa);
  appart_kernel<<<Bb * KK, Aa, 0, stream>>>(attout, appart);
  // 4b. LN the 2048 anchor rows in place
  ln32_kernel<<<BKT / 4, 256, 0, stream>>>(attout, anorm_g, anorm_b);
  hipMemsetAsync(posmap, 0, (size_t)BT * Nn * sizeof(short), stream);
  scatter_pos<<<BT, 64, 0, stream>>>(idx, posmap);
  // 5. local branch
  conv2d_kernel<<<(unsigned)(SZ / 256), 256, 0, stream>>>(ph_b, ldw_w, locg_b);
  gemm_mfma<ushortt, ushortt, 0, 0, 0><<<dim3(2, 784), 256, 0, stream>>>(
      locg_b, lpw_w, nullptr, local_b, nullptr, BTN, Aa, Aa);
  ln_kernel<<<BTN / 4, 256, 0, stream>>>(local_b, lnorm_g, lnorm_b);
  // 6. transition branch
  conv1d_kernel<<<(unsigned)(SZ / 256), 256, 0, stream>>>(delta_b, tdw_w, trg_b);
  gemm_mfma<ushortt, ushortt, 0, 0, 0><<<dim3(2, 784), 256, 0, stream>>>(
      trg_b, tpw_w, nullptr, trp_b, nullptr, BTN, Aa, Aa);
  gemm_mfma<ushortt, ushortt, 0, 1, 1><<<dim3(4, 784), 256, 0, stream>>>(
      trp_b, tmlp_w1, tmlp_b1, h1_b, nullptr, BTN, 2 * Aa, Aa);
  gemm_mfma<ushortt, ushortt, 0, 1, 0><<<dim3(2, 784), 256, 0, stream>>>(
      h1_b, tmlp_w2, tmlp_b2, trans_b, nullptr, BTN, Aa, 2 * Aa);
  ln_kernel<<<BTN / 4, 256, 0, stream>>>(trans_b, tnorm_g, tnorm_b);
  // 8. gate
  gate_kernel<<<Bb, Aa, 0, stream>>>(dppart, appart, gate_w1, gate_b1,
                                     gate_w2, gate_b2, gw);
  // 9. fuse + output projections
  fused_kernel<<<BT, Aa, 0, stream>>>(local_b, trans_b, attout, posmap,
                                      anorm_b, gw, fused_b, fmean);
  gemm_mfma<ushortt, float, 0, 1, 2><<<dim3(8, 784), 256, 0, stream>>>(
      fused_b, up_w, up_b, out, x, BTN, Cc, Aa);
  cls_kernel<<<BT, 256, 0, stream>>>(fmean, cls_w, cls_b, x, out);
}

// Round 14
// 608.252 us; speedup vs baseline: 1.8220x; 1.0580x over previous
//
#include <hip/hip_runtime.h>
#include <hip/hip_bf16.h>
#include <math.h>

// ---- fixed problem dims ----
constexpr int Bb  = 16;
constexpr int Tt  = 16;
constexpr int Nn  = 196;   // patches (14x14)
constexpr int Cc  = 768;
constexpr int Aa  = 192;
constexpr int KK  = 8;     // TOPK
constexpr int NCAND = 16;  // fp32 candidates refined in f64
constexpr int BT  = Bb * Tt;            // 256
constexpr int BTN = BT * Nn;            // 50176
constexpr int BKT = Bb * KK * Tt;       // 2048 anchor-token rows
constexpr size_t SZ = (size_t)BTN * Aa; // 9,633,792 floats

typedef unsigned short ushortt;
typedef __attribute__((ext_vector_type(8))) short bf16x8;
typedef __attribute__((ext_vector_type(4))) float f32x4;
typedef __attribute__((ext_vector_type(4))) unsigned short u16x4;
typedef __attribute__((ext_vector_type(8))) unsigned short u16x8;

static __device__ __forceinline__ float gelu_f(float x) {
  return 0.5f * x * (1.0f + erff(x * 0.7071067811865476f));
}
// HARDWARE bf16 convert (v_cvt_pk_bf16_f32 path via HIP cast)
static __device__ __forceinline__ ushortt f2bf(float f) {
  __hip_bfloat16 h = __float2bfloat16(f);
  return *reinterpret_cast<ushortt*>(&h);
}
static __device__ __forceinline__ float bf2f(ushortt u) {
  return __uint_as_float(((unsigned)u) << 16);
}

// ============================================================
// bf16 MFMA GEMM: C[m,n] = sum_k A[m,k]*W[n,k] (+bias)(+epilogue)
// AT: float (staged->bf16) or ushort (bf16). CT: float or ushort.
// BM=64 BN=96 BK=64; 256 thr = 4 waves (2x2), wave tile 32x48.
// LDS 46 KB -> 3 blocks/CU. Single-pass LDS-staged coalesced epilogue.
// EPI: 0 plain, 1 gelu, 2 mapped residual fp32.
// Grid (Nc/96, M/64); col-fastest + bijective XCD swizzle (nwg%8==0).
// ============================================================
template <typename AT, typename CT, int ROWMAP, int BIAS, int EPI>
__global__ __launch_bounds__(256) void gemm_mfma(
    const AT* __restrict__ Ain, const float* __restrict__ W,
    const float* __restrict__ bias, CT* __restrict__ Cout,
    const float* __restrict__ resid, int M, int Nc, int K) {
  constexpr int PIT = 72;  // bf16 pitch (64+8 pad) -> worst 2-way (free)
  __shared__ __align__(16) unsigned char smem[(2 * 64 * PIT + 2 * 96 * PIT) * 2];
  ushortt (*As)[64 * PIT] = (ushortt(*)[64 * PIT])smem;
  ushortt (*Bs)[96 * PIT] = (ushortt(*)[96 * PIT])(smem + 2 * 64 * PIT * 2);
  const int tid = threadIdx.x;

  const int ncb = gridDim.x;
  const int nwg = ncb * gridDim.y;
  const int bid = blockIdx.y * ncb + blockIdx.x;
  const int cpx = nwg >> 3;
  const int swz = (bid & 7) * cpx + (bid >> 3);
  const int row0 = (swz / ncb) * 64;
  const int col0 = (swz % ncb) * 96;

  const int wid = tid >> 6;
  const int lane = tid & 63;
  const int wr = wid >> 1;       // 0..1 -> +32 rows
  const int wc = wid & 1;        // 0..1 -> +48 cols
  const int l15 = lane & 15;
  const int kgrp = lane >> 4;    // 0..3

  const int q16 = tid & 15;      // float4 index within 64-k row
  const int q8 = tid & 7;        // u16x8 index within 64-k row

  const int nsteps = K >> 6;

  const float* arowf[4];
  const ushortt* arowb[2];
  if constexpr (sizeof(AT) == 4) {
#pragma unroll
    for (int p = 0; p < 4; ++p) {
      int r = row0 + (tid >> 4) + 16 * p;
      if (ROWMAP) {
        int bt = r / Nn;
        int n = r - bt * Nn;
        arowf[p] = (const float*)Ain + (size_t)(bt * (Nn + 1) + 1 + n) * K;
      } else {
        arowf[p] = (const float*)Ain + (size_t)r * K;
      }
    }
  } else {
#pragma unroll
    for (int p = 0; p < 2; ++p)
      arowb[p] = (const ushortt*)Ain + (size_t)(row0 + (tid >> 3) + 32 * p) * K;
  }
  const float* browp[6];
#pragma unroll
  for (int p = 0; p < 6; ++p)
    browp[p] = W + (size_t)(col0 + (tid >> 4) + 16 * p) * K;

  f32x4 acc[2][3];
#pragma unroll
  for (int i = 0; i < 2; ++i)
#pragma unroll
    for (int j = 0; j < 3; ++j) acc[i][j] = (f32x4){0.f, 0.f, 0.f, 0.f};

  float4 apre[4], bpre[6];
  u16x8 apreb[2];

#define STAGE_LOAD(k0)                                                       \
  if constexpr (sizeof(AT) == 4) {                                           \
    _Pragma("unroll") for (int p = 0; p < 4; ++p)                            \
        apre[p] = *(const float4*)(arowf[p] + (k0) + q16 * 4);               \
  } else {                                                                   \
    _Pragma("unroll") for (int p = 0; p < 2; ++p)                            \
        apreb[p] = *(const u16x8*)(arowb[p] + (k0) + q8 * 8);                \
  }                                                                          \
  _Pragma("unroll") for (int p = 0; p < 6; ++p)                              \
      bpre[p] = *(const float4*)(browp[p] + (k0) + q16 * 4);

#define STAGE_WRITE(buf)                                                     \
  if constexpr (sizeof(AT) == 4) {                                           \
    _Pragma("unroll") for (int p = 0; p < 4; ++p) {                          \
      u16x4 b = {f2bf(apre[p].x), f2bf(apre[p].y), f2bf(apre[p].z),          \
                 f2bf(apre[p].w)};                                           \
      *(u16x4*)&As[buf][((tid >> 4) + 16 * p) * PIT + q16 * 4] = b;          \
    }                                                                        \
  } else {                                                                   \
    _Pragma("unroll") for (int p = 0; p < 2; ++p)                            \
        *(u16x8*)&As[buf][((tid >> 3) + 32 * p) * PIT + q8 * 8] = apreb[p];  \
  }                                                                          \
  _Pragma("unroll") for (int p = 0; p < 6; ++p) {                            \
    u16x4 b = {f2bf(bpre[p].x), f2bf(bpre[p].y), f2bf(bpre[p].z),            \
               f2bf(bpre[p].w)};                                             \
    *(u16x4*)&Bs[buf][((tid >> 4) + 16 * p) * PIT + q16 * 4] = b;            \
  }

  STAGE_LOAD(0);
  STAGE_WRITE(0);
  __syncthreads();

  int cur = 0;
  for (int step = 0; step < nsteps; ++step) {
    const bool pref = (step + 1 < nsteps);
    if (pref) {
      int k0 = (step + 1) << 6;
      STAGE_LOAD(k0);
    }
#pragma unroll
    for (int kk = 0; kk < 2; ++kk) {
      bf16x8 af[2], bfv[3];
#pragma unroll
      for (int fm = 0; fm < 2; ++fm)
        af[fm] = *(const bf16x8*)&As[cur][(wr * 32 + fm * 16 + l15) * PIT +
                                          kk * 32 + kgrp * 8];
#pragma unroll
      for (int fn = 0; fn < 3; ++fn)
        bfv[fn] = *(const bf16x8*)&Bs[cur][(wc * 48 + fn * 16 + l15) * PIT +
                                           kk * 32 + kgrp * 8];
#pragma unroll
      for (int fm = 0; fm < 2; ++fm)
#pragma unroll
        for (int fn = 0; fn < 3; ++fn)
          acc[fm][fn] = __builtin_amdgcn_mfma_f32_16x16x32_bf16(
              af[fm], bfv[fn], acc[fm][fn], 0, 0, 0);
    }
    if (pref) {
      STAGE_WRITE(cur ^ 1);
    }
    __syncthreads();
    cur ^= 1;
  }
#undef STAGE_LOAD
#undef STAGE_WRITE

  // ---- single-pass LDS-staged epilogue: coalesced global stores ----
  constexpr int EP = 100;  // fp32 pitch for 96 cols (+4 pad)
  float* epi = (float*)smem;  // 64*100*4 = 25600 B <= 46080 B
#pragma unroll
  for (int fm = 0; fm < 2; ++fm) {
    int rl = wr * 32 + fm * 16 + kgrp * 4;
#pragma unroll
    for (int fn = 0; fn < 3; ++fn) {
      int cl = wc * 48 + fn * 16 + l15;
#pragma unroll
      for (int j = 0; j < 4; ++j)
        epi[(rl + j) * EP + cl] = acc[fm][fn][j];
    }
  }
  __syncthreads();
#pragma unroll
  for (int it = 0; it < 6; ++it) {
    int f = it * 256 + tid;        // 0..1535 over 64 rows x 24 float4
    int r = f / 24, c4 = f - r * 24;
    float4 v = *(const float4*)&epi[r * EP + c4 * 4];
    int c = col0 + c4 * 4;
    if (BIAS) {
      float4 bv = *(const float4*)(bias + c);
      v.x += bv.x; v.y += bv.y; v.z += bv.z; v.w += bv.w;
    }
    if (EPI == 1) {
      v.x = gelu_f(v.x); v.y = gelu_f(v.y);
      v.z = gelu_f(v.z); v.w = gelu_f(v.w);
    }
    int R = row0 + r;
    if constexpr (EPI == 2) {
      int bt2 = R / Nn, n2 = R - bt2 * Nn;
      size_t off = (size_t)(bt2 * (Nn + 1) + 1 + n2) * Nc + c;
      float4 rv = *(const float4*)(resid + off);
      v.x += rv.x; v.y += rv.y; v.z += rv.z; v.w += rv.w;
      *(float4*)((float*)Cout + off) = v;
    } else if constexpr (sizeof(CT) == 4) {
      *(float4*)((float*)Cout + (size_t)R * Nc + c) = v;
    } else {
      u16x4 ob = {f2bf(v.x), f2bf(v.y), f2bf(v.z), f2bf(v.w)};
      *(u16x4*)((ushortt*)Cout + (size_t)R * Nc + c) = ob;
    }
  }
}

// ============================================================
// delta (bf16) + per-(b,t) |delta| partials
// ============================================================
__global__ void delta_kernel(const ushortt* __restrict__ ph,
                             ushortt* __restrict__ delta,
                             float* __restrict__ dppart) {
  int bt = blockIdx.x;
  int t = bt & 15;
  int a = threadIdx.x;
  const ushortt* cur = ph + (size_t)bt * Nn * Aa + a;
  ushortt* dl = delta + (size_t)bt * Nn * Aa + a;
  float acc = 0.f;
  if (t == 0) {
    for (int n = 0; n < Nn; ++n) dl[(size_t)n * Aa] = 0;
  } else {
    const ushortt* prev = cur - (size_t)Nn * Aa;
    for (int n = 0; n < Nn; ++n) {
      float d = bf2f(cur[(size_t)n * Aa]) - bf2f(prev[(size_t)n * Aa]);
      dl[(size_t)n * Aa] = f2bf(d);
      acc += fabsf(d);
    }
  }
  dppart[bt * Aa + a] = acc;
}

// sal[row] = mean_a |delta[row,a]| (fp32, candidate stage only)
__global__ void sal_kernel(const ushortt* __restrict__ delta,
                           float* __restrict__ sal) {
  int row = blockIdx.x * 4 + (threadIdx.x >> 6);
  int lane = threadIdx.x & 63;
  const ushortt* d = delta + (size_t)row * Aa;
  float s = fabsf(bf2f(d[lane])) + fabsf(bf2f(d[lane + 64])) +
            fabsf(bf2f(d[lane + 128]));
#pragma unroll
  for (int off = 32; off > 0; off >>= 1) s += __shfl_xor(s, off, 64);
  if (lane == 0) sal[row] = s * (1.0f / 192.0f);
}

// ============================================================
// top-16 fp32 candidates per (b,t); descending val, ties -> smaller n
// ============================================================
__global__ void topcand_kernel(const float* __restrict__ sal,
                               int* __restrict__ cand) {
  int bt = blockIdx.x;
  int lane = threadIdx.x;
  unsigned long long key[4];
#pragma unroll
  for (int j = 0; j < 4; ++j) {
    int n = lane + 64 * j;
    if (n < Nn) {
      unsigned fb = __float_as_uint(sal[(size_t)bt * Nn + n]);
      key[j] = ((unsigned long long)fb << 32) |
               (unsigned long long)(0xFFFFFFFFu - (unsigned)n);
    } else {
      key[j] = 0ULL;
    }
  }
  for (int r = 0; r < NCAND; ++r) {
    unsigned long long m = key[0];
    if (key[1] > m) m = key[1];
    if (key[2] > m) m = key[2];
    if (key[3] > m) m = key[3];
#pragma unroll
    for (int off = 32; off > 0; off >>= 1) {
      unsigned long long o = __shfl_xor(m, off, 64);
      if (o > m) m = o;
    }
    if (lane == 0)
      cand[bt * NCAND + r] = (int)(0xFFFFFFFFu - (unsigned)(m & 0xFFFFFFFFull));
#pragma unroll
    for (int j = 0; j < 4; ++j)
      if (key[j] == m) key[j] = 0ULL;
  }
}

// one-time transpose: wT[c][a] = down_w[a][c]
__global__ void transpose_w(const float* __restrict__ w,
                            float* __restrict__ wT) {
  int e = blockIdx.x * 256 + threadIdx.x;  // over Cc*Aa
  int c = e / Aa, a = e - c * Aa;
  wT[e] = w[(size_t)a * Cc + c];
}

// ============================================================
// f64 refine, 8 candidates per block (grid BT x 2, 192 thr).
// diff staged once in LDS (f64); w read COALESCED via wT[c][a].
// ============================================================
__global__ __launch_bounds__(192) void refine_kernel(
    const float* __restrict__ x, const float* __restrict__ wT,
    const int* __restrict__ cand, double* __restrict__ sal64) {
  int bt = blockIdx.x;
  int grp = blockIdx.y;
  int t = bt & 15;
  int a = threadIdx.x;
  if (t == 0) {
    if (a < 8) sal64[bt * NCAND + grp * 8 + a] = 0.0;
    return;
  }
  __shared__ double sdiff[8][Cc];  // 49 KB
  const float* xt = x + ((size_t)bt * (Nn + 1) + 1) * Cc;
  const float* xp = xt - (size_t)(Nn + 1) * Cc;
  for (int g = 0; g < 8; ++g) {
    int n = cand[bt * NCAND + grp * 8 + g];
    const float* rt = xt + (size_t)n * Cc;
    const float* rp = xp + (size_t)n * Cc;
    for (int c = a; c < Cc; c += 192)
      sdiff[g][c] = (double)rt[c] - (double)rp[c];
  }
  __syncthreads();
  double acc[8] = {};
  for (int c = 0; c < Cc; ++c) {
    double wv = (double)wT[(size_t)c * Aa + a];  // coalesced across lanes
#pragma unroll
    for (int g = 0; g < 8; ++g) acc[g] = fma(wv, sdiff[g][c], acc[g]);
  }
  __shared__ double part[3][8];
  int wvx = a >> 6, ln = a & 63;
#pragma unroll
  for (int g = 0; g < 8; ++g) {
    double v = fabs(acc[g]);
#pragma unroll
    for (int off = 32; off > 0; off >>= 1) v += __shfl_xor(v, off, 64);
    if (ln == 0) part[wvx][g] = v;
  }
  __syncthreads();
  if (a < 8) {
    double s = part[0][a] + part[1][a] + part[2][a];
    sal64[bt * NCAND + grp * 8 + a] = s * (1.0 / 192.0);
  }
}

// ============================================================
// final top-8 by (sal64 desc, n asc) — wave-parallel, all in registers
// (r14: the old 1-thread selection sort had its arrays in SCRATCH —
//  156 us. Lane i holds candidate i; 8 rounds of 16-lane butterfly max.)
// ============================================================
__global__ void select_kernel(const double* __restrict__ sal64,
                              const int* __restrict__ cand,
                              int* __restrict__ idx) {
  int bt = blockIdx.x;
  int t = bt & 15;
  int lane = threadIdx.x;  // 64
  if (t == 0) {
    if (lane < KK) idx[bt * KK + lane] = lane;
    return;
  }
  double v = (lane < NCAND) ? sal64[bt * NCAND + lane] : -1.0;
  int n = (lane < NCAND) ? cand[bt * NCAND + lane] : 0x7FFFFFFF;
  for (int r = 0; r < KK; ++r) {
    double bv = v;
    int bn = n, bl = lane;
#pragma unroll
    for (int off = 8; off >= 1; off >>= 1) {
      double ov = __shfl_xor(bv, off, 64);
      int on = __shfl_xor(bn, off, 64);
      int ol = __shfl_xor(bl, off, 64);
      if (ov > bv || (ov == bv && on < bn)) { bv = ov; bn = on; bl = ol; }
    }
    if (lane == 0) idx[bt * KK + r] = bn;
    if (lane == bl) v = -1.0;  // retire winner (lanes>=16 self-noop)
  }
}

// ============================================================
// anchor attention: gather(bf16) -> GEMM qkv -> core -> GEMMs
// ============================================================
__global__ void gather_kernel(const ushortt* __restrict__ ph,
                              const ushortt* __restrict__ delta,
                              const int* __restrict__ idx,
                              ushortt* __restrict__ tok) {
  int row = blockIdx.x;  // (b*KK+k)*16+t
  int t = row & 15;
  int bk = row >> 4;
  int b = bk >> 3, k = bk & 7;
  int a = threadIdx.x;
  int n = idx[(b * 16 + t) * KK + k];
  size_t off = ((size_t)(b * 16 + t) * Nn + n) * Aa + a;
  tok[(size_t)row * Aa + a] = f2bf(bf2f(ph[off]) + bf2f(delta[off]));
}

__global__ __launch_bounds__(256) void attn_core(
    const float* __restrict__ qkv, float* __restrict__ o) {
  constexpr int P = 580;
  __shared__ float sq[16 * P];
  __shared__ float ssc[4][16][17];
  int bk = blockIdx.x;
  int tid = threadIdx.x;
  const float* src = qkv + (size_t)bk * 16 * 576;
  for (int e = tid; e < 16 * 144; e += 256) {
    int r = e / 144, c4 = e % 144;
    float4 v = *(const float4*)(src + r * 576 + c4 * 4);
    *(float4*)(&sq[r * P + c4 * 4]) = v;
  }
  __syncthreads();
  int h = tid >> 6, lane = tid & 63;
#pragma unroll
  for (int s4 = 0; s4 < 4; ++s4) {
    int e = lane + 64 * s4;
    int i = e >> 4, j = e & 15;
    const float* q = sq + i * P + h * 48;
    const float* k2 = sq + j * P + 192 + h * 48;
    float s = 0.f;
#pragma unroll
    for (int d = 0; d < 48; ++d) s = fmaf(q[d], k2[d], s);
    ssc[h][i][j] = s * 0.14433756729740643f;  // 1/sqrt(48)
  }
  __syncthreads();
  if (lane < 16) {
    float* r = ssc[h][lane];
    float mx = r[0];
    for (int j = 1; j < 16; ++j) mx = fmaxf(mx, r[j]);
    float sum = 0.f;
    for (int j = 0; j < 16; ++j) {
      float ev = expf(r[j] - mx);
      r[j] = ev;
      sum += ev;
    }
    float inv = 1.0f / sum;
    for (int j = 0; j < 16; ++j) r[j] *= inv;
  }
  __syncthreads();
#pragma unroll
  for (int s4 = 0; s4 < 12; ++s4) {
    int e = lane + 64 * s4;
    int i = e / 48, d = e - i * 48;
    float s = 0.f;
#pragma unroll
    for (int j = 0; j < 16; ++j)
      s = fmaf(ssc[h][i][j], sq[j * P + 384 + h * 48 + d], s);
    o[((size_t)bk * 16 + i) * 192 + h * 48 + d] = s;
  }
}

__global__ void appart_kernel(const float* __restrict__ attout,
                              float* __restrict__ appart) {
  int bk = blockIdx.x;
  int a = threadIdx.x;
  float s = 0.f;
  for (int t = 0; t < Tt; ++t)
    s += attout[((size_t)bk * Tt + t) * Aa + a];
  appart[bk * Aa + a] = s;
}

// in-place fp32 LayerNorm over last dim (192); one wave per row
__global__ void ln32_kernel(float* __restrict__ buf,
                            const float* __restrict__ g,
                            const float* __restrict__ bb) {
  size_t row = (size_t)blockIdx.x * 4 + (threadIdx.x >> 6);
  int lane = threadIdx.x & 63;
  float* p = buf + row * Aa;
  float v0 = p[lane], v1 = p[lane + 64], v2 = p[lane + 128];
  float s = v0 + v1 + v2;
#pragma unroll
  for (int off = 32; off > 0; off >>= 1) s += __shfl_xor(s, off, 64);
  float m = s * (1.0f / 192.0f);
  float d0 = v0 - m, d1 = v1 - m, d2 = v2 - m;
  float ss = d0 * d0 + d1 * d1 + d2 * d2;
#pragma unroll
  for (int off = 32; off > 0; off >>= 1) ss += __shfl_xor(ss, off, 64);
  float inv = rsqrtf(ss * (1.0f / 192.0f) + 1e-5f);
  p[lane] = d0 * inv * g[lane] + bb[lane];
  p[lane + 64] = d1 * inv * g[lane + 64] + bb[lane + 64];
  p[lane + 128] = d2 * inv * g[lane + 128] + bb[lane + 128];
}

// depthwise 3x3 SAME conv over 14x14 + gelu; bf16 in/out
__global__ void conv2d_kernel(const ushortt* __restrict__ ph,
                              const float* __restrict__ ldw,
                              ushortt* __restrict__ og) {
  size_t e = (size_t)blockIdx.x * 256 + threadIdx.x;
  int a = (int)(e % Aa);
  size_t r = e / Aa;
  int n = (int)(r % Nn);
  int bt = (int)(r / Nn);
  int y = n / 14, x = n % 14;
  const ushortt* base = ph + (size_t)bt * Nn * Aa + a;
  const float* w = ldw + a * 9;
  float s = 0.f;
#pragma unroll
  for (int dy = -1; dy <= 1; ++dy) {
    int yy = y + dy;
    if (yy < 0 || yy >= 14) continue;
#pragma unroll
    for (int dx = -1; dx <= 1; ++dx) {
      int xc = x + dx;
      if (xc < 0 || xc >= 14) continue;
      s = fmaf(bf2f(base[(size_t)(yy * 14 + xc) * Aa]),
               w[(dy + 1) * 3 + (dx + 1)], s);
    }
  }
  og[e] = f2bf(gelu_f(s));
}

// depthwise k=3 SAME conv over t + gelu; bf16 in/out
__global__ void conv1d_kernel(const ushortt* __restrict__ delta,
                              const float* __restrict__ tdw,
                              ushortt* __restrict__ og) {
  size_t e = (size_t)blockIdx.x * 256 + threadIdx.x;
  int a = (int)(e % Aa);
  size_t r = e / Aa;
  int n = (int)(r % Nn);
  int bt = (int)(r / Nn);
  int t = bt & 15, b = bt >> 4;
  const float* w = tdw + a * 3;
  float s = 0.f;
#pragma unroll
  for (int j = 0; j < 3; ++j) {
    int tt = t + j - 1;
    if (tt >= 0 && tt < Tt)
      s = fmaf(bf2f(delta[((size_t)(b * Tt + tt) * Nn + n) * Aa + a]), w[j], s);
  }
  og[e] = f2bf(gelu_f(s));
}

// in-place LayerNorm over last dim (192); one wave per row (bf16)
__global__ void ln_kernel(ushortt* __restrict__ buf,
                          const float* __restrict__ g,
                          const float* __restrict__ bb) {
  size_t row = (size_t)blockIdx.x * 4 + (threadIdx.x >> 6);
  int lane = threadIdx.x & 63;
  ushortt* p = buf + row * Aa;
  float v0 = bf2f(p[lane]), v1 = bf2f(p[lane + 64]), v2 = bf2f(p[lane + 128]);
  float s = v0 + v1 + v2;
#pragma unroll
  for (int off = 32; off > 0; off >>= 1) s += __shfl_xor(s, off, 64);
  float m = s * (1.0f / 192.0f);
  float d0 = v0 - m, d1 = v1 - m, d2 = v2 - m;
  float ss = d0 * d0 + d1 * d1 + d2 * d2;
#pragma unroll
  for (int off = 32; off > 0; off >>= 1) ss += __shfl_xor(ss, off, 64);
  float inv = rsqrtf(ss * (1.0f / 192.0f) + 1e-5f);
  p[lane] = f2bf(d0 * inv * g[lane] + bb[lane]);
  p[lane + 64] = f2bf(d1 * inv * g[lane + 64] + bb[lane + 64]);
  p[lane + 128] = f2bf(d2 * inv * g[lane + 128] + bb[lane + 128]);
}

// posmap[bt*Nn + idx[bt,k]] = k+1 (posmap pre-zeroed)
__global__ void scatter_pos(const int* __restrict__ idx,
                            short* __restrict__ posmap) {
  int bt = blockIdx.x;
  int k = threadIdx.x;
  if (k < KK) posmap[bt * Nn + idx[bt * KK + k]] = (short)(k + 1);
}

// gate MLP + 3-way softmax; one block per b, 192 threads
__global__ void gate_kernel(const float* __restrict__ dppart,
                            const float* __restrict__ appart,
                            const float* __restrict__ w1,
                            const float* __restrict__ b1,
                            const float* __restrict__ w2,
                            const float* __restrict__ b2,
                            float* __restrict__ gw) {
  int b = blockIdx.x;
  __shared__ float sg[2 * Aa];
  __shared__ float sh[Aa];
  int tid = threadIdx.x;
  {
    float d = 0.f;
    for (int t2 = 0; t2 < Tt; ++t2) d += dppart[(b * Tt + t2) * Aa + tid];
    sg[tid] = d * (1.0f / 3136.0f);
    float a = 0.f;
    for (int k2 = 0; k2 < KK; ++k2) a += appart[(b * KK + k2) * Aa + tid];
    sg[Aa + tid] = a * (1.0f / 128.0f);
  }
  __syncthreads();
  {
    const float* w = w1 + (size_t)tid * 2 * Aa;
    float s = b1[tid];
#pragma unroll 8
    for (int j = 0; j < 2 * Aa; ++j) s = fmaf(sg[j], w[j], s);
    sh[tid] = gelu_f(s);
  }
  __syncthreads();
  float v[3];
#pragma unroll
  for (int i = 0; i < 3; ++i) {
    const float* w = w2 + (size_t)(i * Aa + tid) * Aa;
    float s = b2[i * Aa + tid];
#pragma unroll 8
    for (int j = 0; j < Aa; ++j) s = fmaf(sh[j], w[j], s);
    v[i] = s;
  }
  float mx = fmaxf(v[0], fmaxf(v[1], v[2]));
  float e0 = expf(v[0] - mx), e1 = expf(v[1] - mx), e2 = expf(v[2] - mx);
  float inv = 1.0f / (e0 + e1 + e2);
  gw[(b * 3 + 0) * Aa + tid] = e0 * inv;
  gw[(b * 3 + 1) * Aa + tid] = e1 * inv;
  gw[(b * 3 + 2) * Aa + tid] = e2 * inv;
}

// fused = gw0*local + gw1*trans + gw2*amap_ln; amap_ln from attln rows
// (anchors, via posmap) or anorm_b constant (non-anchors). fmean fp32.
__global__ void fused_kernel(const ushortt* __restrict__ local,
                             const ushortt* __restrict__ trans,
                             const float* __restrict__ attln,
                             const short* __restrict__ posmap,
                             const float* __restrict__ anb,
                             const float* __restrict__ gw,
                             ushortt* __restrict__ fused,
                             float* __restrict__ fmean) {
  int bt = blockIdx.x;
  int b = bt >> 4, t = bt & 15;
  int a = threadIdx.x;
  float g0 = gw[(b * 3 + 0) * Aa + a];
  float g1 = gw[(b * 3 + 1) * Aa + a];
  float g2 = gw[(b * 3 + 2) * Aa + a];
  float ab = anb[a];
  size_t base = (size_t)bt * Nn * Aa + a;
  float acc = 0.f;
  for (int n = 0; n < Nn; ++n) {
    size_t o = base + (size_t)n * Aa;
    short pos = posmap[bt * Nn + n];
    float am = pos ? attln[(((size_t)(b * KK + pos - 1) * Tt) + t) * Aa + a]
                   : ab;
    float f = g0 * bf2f(local[o]) + g1 * bf2f(trans[o]) + g2 * am;
    fused[o] = f2bf(f);
    acc += f;
  }
  fmean[bt * Aa + a] = acc;
}

// cls_out = cls_tok + (mean_n fused) @ cls_w.T + cls_b
__global__ void cls_kernel(const float* __restrict__ fmean,
                           const float* __restrict__ cw,
                           const float* __restrict__ cb,
                           const float* __restrict__ x,
                           float* __restrict__ out) {
  int bt = blockIdx.x;
  __shared__ float fm[Aa];
  int tid = threadIdx.x;
  if (tid < Aa) fm[tid] = fmean[bt * Aa + tid] * (1.0f / 196.0f);
  __syncthreads();
  for (int c = tid; c < Cc; c += 256) {
    const float* w = cw + (size_t)c * Aa;
    float s = cb[c];
#pragma unroll 8
    for (int a = 0; a < Aa; ++a) s = fmaf(fm[a], w[a], s);
    size_t off = (size_t)bt * (Nn + 1) * Cc + c;
    out[off] = x[off] + s;
  }
}

// ============================================================
extern "C" void kernel_launch(void* const* d_in, const int* in_sizes, int n_in,
                              void* d_out, int out_size, void* d_ws,
                              size_t ws_size, hipStream_t stream) {
  const float* x = (const float*)d_in[0];
  const float* down_w = (const float*)d_in[1];
  const float* down_b = (const float*)d_in[2];
  const float* ldw_w = (const float*)d_in[3];
  const float* lpw_w = (const float*)d_in[4];
  const float* lnorm_g = (const float*)d_in[5];
  const float* lnorm_b = (const float*)d_in[6];
  const float* tdw_w = (const float*)d_in[7];
  const float* tpw_w = (const float*)d_in[8];
  const float* tmlp_w1 = (const float*)d_in[9];
  const float* tmlp_b1 = (const float*)d_in[10];
  const float* tmlp_w2 = (const float*)d_in[11];
  const float* tmlp_b2 = (const float*)d_in[12];
  const float* tnorm_g = (const float*)d_in[13];
  const float* tnorm_b = (const float*)d_in[14];
  const float* attn_in_w = (const float*)d_in[15];
  const float* attn_in_b = (const float*)d_in[16];
  const float* attn_out_w = (const float*)d_in[17];
  const float* attn_out_b = (const float*)d_in[18];
  const float* aproj_w = (const float*)d_in[19];
  const float* aproj_b = (const float*)d_in[20];
  const float* anorm_g = (const float*)d_in[21];
  const float* anorm_b = (const float*)d_in[22];
  const float* gate_w1 = (const float*)d_in[23];
  const float* gate_b1 = (const float*)d_in[24];
  const float* gate_w2 = (const float*)d_in[25];
  const float* gate_b2 = (const float*)d_in[26];
  const float* up_w = (const float*)d_in[27];
  const float* up_b = (const float*)d_in[28];
  const float* cls_w = (const float*)d_in[29];
  const float* cls_b = (const float*)d_in[30];
  float* out = (float*)d_out;

  float* ws = (float*)d_ws;
  float* W0 = ws;              // ph bf16 -> trp bf16
  float* W1 = W0 + SZ;         // delta bf16 -> transition bf16
  float* W2 = W1 + SZ;         // attn scratch -> locg/trg/h1/fused bf16
  float* W3 = W2 + 2 * SZ;     // local bf16
  float* sal = W3 + SZ;
  float* attout = sal + BTN;
  float* dppart = attout + (size_t)BKT * Aa;
  float* appart = dppart + (size_t)BT * Aa;
  float* gw = appart + (size_t)Bb * KK * Aa;
  float* fmean = gw + (size_t)Bb * 3 * Aa;
  double* sal64 = (double*)(fmean + (size_t)BT * Aa);  // BT*NCAND doubles
  int* cand = (int*)(sal64 + (size_t)BT * NCAND);      // BT*NCAND ints
  int* idx = cand + (size_t)BT * NCAND;                // BT*KK ints
  float* wT = (float*)(idx + (size_t)BT * KK);         // Cc*Aa floats
  short* posmap = (short*)(wT + (size_t)Cc * Aa);      // BT*Nn shorts

  // bf16 activation views
  ushortt* ph_b    = (ushortt*)W0;
  ushortt* trp_b   = (ushortt*)W0;
  ushortt* delta_b = (ushortt*)W1;
  ushortt* trans_b = (ushortt*)W1;
  ushortt* locg_b  = (ushortt*)W2;
  ushortt* trg_b   = (ushortt*)W2;
  ushortt* h1_b    = (ushortt*)W2;
  ushortt* fused_b = (ushortt*)W2;
  ushortt* local_b = (ushortt*)W3;

  // attn-phase scratch inside W2 (dead until conv2d)
  ushortt* tok_b = (ushortt*)W2;                       // 2048*192 bf16
  float* qkvb  = W2 + (size_t)BKT * Aa / 2;            // 2048*576 f32
  float* obuf  = qkvb + (size_t)BKT * 3 * Aa;          // 2048*192 f32
  float* proj1 = obuf + (size_t)BKT * Aa;              // 2048*192 f32

  // 1. ph = patch @ down_w.T + down_b (bf16 out)
  gemm_mfma<float, ushortt, 1, 1, 0><<<dim3(2, 784), 256, 0, stream>>>(
      x, down_w, down_b, ph_b, nullptr, BTN, Aa, Cc);
  transpose_w<<<(Cc * Aa) / 256, 256, 0, stream>>>(down_w, wT);
  // 2. delta + dp partials
  delta_kernel<<<BT, Aa, 0, stream>>>(ph_b, delta_b, dppart);
  // 3. saliency: fp32 candidates -> f64 refine -> exact top-8
  sal_kernel<<<BTN / 4, 256, 0, stream>>>(delta_b, sal);
  topcand_kernel<<<BT, 64, 0, stream>>>(sal, cand);
  refine_kernel<<<dim3(BT, 2), 192, 0, stream>>>(x, wT, cand, sal64);
  select_kernel<<<BT, 64, 0, stream>>>(sal64, cand, idx);
  // 4. anchor attention
  gather_kernel<<<BKT, Aa, 0, stream>>>(ph_b, delta_b, idx, tok_b);
  gemm_mfma<ushortt, float, 0, 1, 0><<<dim3(6, 32), 256, 0, stream>>>(
      tok_b, attn_in_w, attn_in_b, qkvb, nullptr, BKT, 3 * Aa, Aa);
  attn_core<<<Bb * KK, 256, 0, stream>>>(qkvb, obuf);
  gemm_mfma<float, float, 0, 1, 0><<<dim3(2, 32), 256, 0, stream>>>(
      obuf, attn_out_w, attn_out_b, proj1, nullptr, BKT, Aa, Aa);
  gemm_mfma<float, float, 0, 1, 0><<<dim3(2, 32), 256, 0, stream>>>(
      proj1, aproj_w, aproj_b, attout, nullptr, BKT, Aa, Aa);
  appart_kernel<<<Bb * KK, Aa, 0, stream>>>(attout, appart);
  // 4b. LN the 2048 anchor rows in place
  ln32_kernel<<<BKT / 4, 256, 0, stream>>>(attout, anorm_g, anorm_b);
  hipMemsetAsync(posmap, 0, (size_t)BT * Nn * sizeof(short), stream);
  scatter_pos<<<BT, 64, 0, stream>>>(idx, posmap);
  // 5. local branch
  conv2d_kernel<<<(unsigned)(SZ / 256), 256, 0, stream>>>(ph_b, ldw_w, locg_b);
  gemm_mfma<ushortt, ushortt, 0, 0, 0><<<dim3(2, 784), 256, 0, stream>>>(
      locg_b, lpw_w, nullptr, local_b, nullptr, BTN, Aa, Aa);
  ln_kernel<<<BTN / 4, 256, 0, stream>>>(local_b, lnorm_g, lnorm_b);
  // 6. transition branch
  conv1d_kernel<<<(unsigned)(SZ / 256), 256, 0, stream>>>(delta_b, tdw_w, trg_b);
  gemm_mfma<ushortt, ushortt, 0, 0, 0><<<dim3(2, 784), 256, 0, stream>>>(
      trg_b, tpw_w, nullptr, trp_b, nullptr, BTN, Aa, Aa);
  gemm_mfma<ushortt, ushortt, 0, 1, 1><<<dim3(4, 784), 256, 0, stream>>>(
      trp_b, tmlp_w1, tmlp_b1, h1_b, nullptr, BTN, 2 * Aa, Aa);
  gemm_mfma<ushortt, ushortt, 0, 1, 0><<<dim3(2, 784), 256, 0, stream>>>(
      h1_b, tmlp_w2, tmlp_b2, trans_b, nullptr, BTN, Aa, 2 * Aa);
  ln_kernel<<<BTN / 4, 256, 0, stream>>>(trans_b, tnorm_g, tnorm_b);
  // 8. gate
  gate_kernel<<<Bb, Aa, 0, stream>>>(dppart, appart, gate_w1, gate_b1,
                                     gate_w2, gate_b2, gw);
  // 9. fuse + output projections
  fused_kernel<<<BT, Aa, 0, stream>>>(local_b, trans_b, attout, posmap,
                                      anorm_b, gw, fused_b, fmean);
  gemm_mfma<ushortt, float, 0, 1, 2><<<dim3(8, 784), 256, 0, stream>>>(
      fused_b, up_w, up_b, out, x, BTN, Cc, Aa);
  cls_kernel<<<BT, 256, 0, stream>>>(fmean, cls_w, cls_b, x, out);
}

// Round 15
// 579.654 us; speedup vs baseline: 1.9119x; 1.0493x over previous
//
#include <hip/hip_runtime.h>
#include <hip/hip_bf16.h>
#include <math.h>

// ---- fixed problem dims ----
constexpr int Bb  = 16;
constexpr int Tt  = 16;
constexpr int Nn  = 196;   // patches (14x14)
constexpr int Cc  = 768;
constexpr int Aa  = 192;
constexpr int KK  = 8;     // TOPK
constexpr int NCAND = 16;  // fp32 candidates refined in f64
constexpr int BT  = Bb * Tt;            // 256
constexpr int BTN = BT * Nn;            // 50176
constexpr int BKT = Bb * KK * Tt;       // 2048 anchor-token rows
constexpr size_t SZ = (size_t)BTN * Aa; // 9,633,792 floats

typedef unsigned short ushortt;
typedef __attribute__((ext_vector_type(8))) short bf16x8;
typedef __attribute__((ext_vector_type(4))) float f32x4;
typedef __attribute__((ext_vector_type(4))) unsigned short u16x4;
typedef __attribute__((ext_vector_type(8))) unsigned short u16x8;

static __device__ __forceinline__ float gelu_f(float x) {
  return 0.5f * x * (1.0f + erff(x * 0.7071067811865476f));
}
// HARDWARE bf16 convert (v_cvt_pk_bf16_f32 path via HIP cast)
static __device__ __forceinline__ ushortt f2bf(float f) {
  __hip_bfloat16 h = __float2bfloat16(f);
  return *reinterpret_cast<ushortt*>(&h);
}
static __device__ __forceinline__ float bf2f(ushortt u) {
  return __uint_as_float(((unsigned)u) << 16);
}
// async global->LDS, 16B per lane (dest = wave-uniform base + lane*16)
static __device__ __forceinline__ void gload16(const void* g, void* l) {
  __builtin_amdgcn_global_load_lds(
      (const __attribute__((address_space(1))) void*)g,
      (__attribute__((address_space(3))) void*)l, 16, 0, 0);
}

// ---- weight pre-convert: all GEMM weights fp32 -> bf16, one kernel ----
constexpr int S_down   = Aa * Cc;        // 147456
constexpr int S_attnin = 3 * Aa * Aa;    // 110592
constexpr int S_sq     = Aa * Aa;        // 36864
constexpr int S_t      = 2 * Aa * Aa;    // 73728
constexpr int O1 = S_down;               // attn_in
constexpr int O2 = O1 + S_attnin;        // attn_out
constexpr int O3 = O2 + S_sq;            // aproj
constexpr int O4 = O3 + S_sq;            // lpw
constexpr int O5 = O4 + S_sq;            // tpw
constexpr int O6 = O5 + S_sq;            // tmlp1
constexpr int O7 = O6 + S_t;             // tmlp2
constexpr int O8 = O7 + S_t;             // up
constexpr int OTOT = O8 + S_down;        // 700416 (== 2736*256)

__global__ void cvtw_kernel(const float* __restrict__ w0,
                            const float* __restrict__ w1,
                            const float* __restrict__ w2,
                            const float* __restrict__ w3,
                            const float* __restrict__ w4,
                            const float* __restrict__ w5,
                            const float* __restrict__ w6,
                            const float* __restrict__ w7,
                            const float* __restrict__ w8,
                            ushortt* __restrict__ outw) {
  int e = blockIdx.x * 256 + threadIdx.x;
  const float* src;
  int off;
  if (e < O1)      { src = w0; off = 0;  }
  else if (e < O2) { src = w1; off = O1; }
  else if (e < O3) { src = w2; off = O2; }
  else if (e < O4) { src = w3; off = O3; }
  else if (e < O5) { src = w4; off = O4; }
  else if (e < O6) { src = w5; off = O5; }
  else if (e < O7) { src = w6; off = O6; }
  else if (e < O8) { src = w7; off = O7; }
  else             { src = w8; off = O8; }
  outw[e] = f2bf(src[e - off]);
}

// ============================================================
// gemm_lds: bf16 A & bf16 W, staged via global_load_lds (width 16).
// BM=64 BN=96 BK=64; 256 thr = 4 waves (2x2), wave tile 32x48.
// LDS linear (gload req.); 16-way ds_read conflict fixed by BOTH-SIDES
// XOR swizzle: src colchunk 16*((l%8)^(l/8)), read byte ^ ((row&7)<<4).
// 5 gload instrs per wave per K-tile; zero staging VALU.
// EPI: 0 plain, 1 gelu, 2 mapped residual fp32.
// ============================================================
template <typename CT, int BIAS, int EPI>
__global__ __launch_bounds__(256) void gemm_lds(
    const ushortt* __restrict__ Ain, const ushortt* __restrict__ Wb,
    const float* __restrict__ bias, CT* __restrict__ Cout,
    const float* __restrict__ resid, int M, int Nc, int K) {
  // A: 64x64 bf16 = 8192 B; B: 96x64 = 12288 B; x2 dbuf = 40960 B
  __shared__ __align__(16) unsigned char smem[40960];
  ushortt (*As)[64 * 64] = (ushortt(*)[64 * 64])smem;
  ushortt (*Bs)[96 * 64] = (ushortt(*)[96 * 64])(smem + 2 * 64 * 64 * 2);
  const int tid = threadIdx.x;

  const int ncb = gridDim.x;
  const int nwg = ncb * gridDim.y;
  const int bid = blockIdx.y * ncb + blockIdx.x;
  const int cpx = nwg >> 3;
  const int swz = (bid & 7) * cpx + (bid >> 3);
  const int row0 = (swz / ncb) * 64;
  const int col0 = (swz % ncb) * 96;

  const int wid = tid >> 6;
  const int lane = tid & 63;
  const int wr = wid >> 1;       // 0..1 -> +32 rows
  const int wc = wid & 1;        // 0..1 -> +48 cols
  const int l15 = lane & 15;
  const int kgrp = lane >> 4;    // 0..3

  const int lr = lane >> 3;      // 0..7: row within 8-row fill chunk
  const int lc = 8 * ((lane & 7) ^ lr);  // swizzled col (bf16 elems)

  f32x4 acc[2][3];
#pragma unroll
  for (int i = 0; i < 2; ++i)
#pragma unroll
    for (int j = 0; j < 3; ++j) acc[i][j] = (f32x4){0.f, 0.f, 0.f, 0.f};

#define ISSUE(buf, k0)                                                       \
  do {                                                                       \
    _Pragma("unroll") for (int i = 0; i < 2; ++i) {                          \
      int j = 2 * wid + i;                                                   \
      const ushortt* g =                                                     \
          Ain + (size_t)(row0 + 8 * j + lr) * K + (k0) + lc;                 \
      gload16(g, &As[buf][j * 512]);                                         \
    }                                                                        \
    _Pragma("unroll") for (int i = 0; i < 3; ++i) {                          \
      int j = 3 * wid + i;                                                   \
      const ushortt* g =                                                     \
          Wb + (size_t)(col0 + 8 * j + lr) * K + (k0) + lc;                  \
      gload16(g, &Bs[buf][j * 512]);                                         \
    }                                                                        \
  } while (0)

  ISSUE(0, 0);
  __syncthreads();

  const int nsteps = K >> 6;
  int cur = 0;
  for (int step = 0; step < nsteps; ++step) {
    const bool pref = (step + 1 < nsteps);
    if (pref) ISSUE(cur ^ 1, (step + 1) << 6);
#pragma unroll
    for (int kk = 0; kk < 2; ++kk) {
      const int cb = kk * 64 + kgrp * 16;  // byte col within 128B row
      bf16x8 af[2], bfv[3];
#pragma unroll
      for (int fm = 0; fm < 2; ++fm) {
        int r = wr * 32 + fm * 16 + l15;
        af[fm] = *(const bf16x8*)&As[cur][r * 64 +
                                          ((cb ^ ((r & 7) << 4)) >> 1)];
      }
#pragma unroll
      for (int fn = 0; fn < 3; ++fn) {
        int r = wc * 48 + fn * 16 + l15;
        bfv[fn] = *(const bf16x8*)&Bs[cur][r * 64 +
                                           ((cb ^ ((r & 7) << 4)) >> 1)];
      }
#pragma unroll
      for (int fm = 0; fm < 2; ++fm)
#pragma unroll
        for (int fn = 0; fn < 3; ++fn)
          acc[fm][fn] = __builtin_amdgcn_mfma_f32_16x16x32_bf16(
              af[fm], bfv[fn], acc[fm][fn], 0, 0, 0);
    }
    __syncthreads();
    cur ^= 1;
  }
#undef ISSUE

  // ---- single-pass LDS-staged epilogue: coalesced global stores ----
  constexpr int EP = 100;  // fp32 pitch for 96 cols (+4 pad)
  float* epi = (float*)smem;  // 25600 B <= 40960 B
#pragma unroll
  for (int fm = 0; fm < 2; ++fm) {
    int rl = wr * 32 + fm * 16 + kgrp * 4;
#pragma unroll
    for (int fn = 0; fn < 3; ++fn) {
      int cl = wc * 48 + fn * 16 + l15;
#pragma unroll
      for (int j = 0; j < 4; ++j)
        epi[(rl + j) * EP + cl] = acc[fm][fn][j];
    }
  }
  __syncthreads();
#pragma unroll
  for (int it = 0; it < 6; ++it) {
    int f = it * 256 + tid;        // 0..1535 over 64 rows x 24 float4
    int r = f / 24, c4 = f - r * 24;
    float4 v = *(const float4*)&epi[r * EP + c4 * 4];
    int c = col0 + c4 * 4;
    if (BIAS) {
      float4 bv = *(const float4*)(bias + c);
      v.x += bv.x; v.y += bv.y; v.z += bv.z; v.w += bv.w;
    }
    if (EPI == 1) {
      v.x = gelu_f(v.x); v.y = gelu_f(v.y);
      v.z = gelu_f(v.z); v.w = gelu_f(v.w);
    }
    int R = row0 + r;
    if constexpr (EPI == 2) {
      int bt2 = R / Nn, n2 = R - bt2 * Nn;
      size_t off = (size_t)(bt2 * (Nn + 1) + 1 + n2) * Nc + c;
      float4 rv = *(const float4*)(resid + off);
      v.x += rv.x; v.y += rv.y; v.z += rv.z; v.w += rv.w;
      *(float4*)((float*)Cout + off) = v;
    } else if constexpr (sizeof(CT) == 4) {
      *(float4*)((float*)Cout + (size_t)R * Nc + c) = v;
    } else {
      u16x4 ob = {f2bf(v.x), f2bf(v.y), f2bf(v.z), f2bf(v.w)};
      *(u16x4*)((ushortt*)Cout + (size_t)R * Nc + c) = ob;
    }
  }
}

// ============================================================
// gemm_mfma (r13): reg-staged path for fp32-A GEMMs (down, attn fp32)
// ============================================================
template <typename AT, typename CT, int ROWMAP, int BIAS, int EPI>
__global__ __launch_bounds__(256) void gemm_mfma(
    const AT* __restrict__ Ain, const float* __restrict__ W,
    const float* __restrict__ bias, CT* __restrict__ Cout,
    const float* __restrict__ resid, int M, int Nc, int K) {
  constexpr int PIT = 72;
  __shared__ __align__(16) unsigned char smem[(2 * 64 * PIT + 2 * 96 * PIT) * 2];
  ushortt (*As)[64 * PIT] = (ushortt(*)[64 * PIT])smem;
  ushortt (*Bs)[96 * PIT] = (ushortt(*)[96 * PIT])(smem + 2 * 64 * PIT * 2);
  const int tid = threadIdx.x;

  const int ncb = gridDim.x;
  const int nwg = ncb * gridDim.y;
  const int bid = blockIdx.y * ncb + blockIdx.x;
  const int cpx = nwg >> 3;
  const int swz = (bid & 7) * cpx + (bid >> 3);
  const int row0 = (swz / ncb) * 64;
  const int col0 = (swz % ncb) * 96;

  const int wid = tid >> 6;
  const int lane = tid & 63;
  const int wr = wid >> 1;
  const int wc = wid & 1;
  const int l15 = lane & 15;
  const int kgrp = lane >> 4;

  const int q16 = tid & 15;
  const int q8 = tid & 7;

  const int nsteps = K >> 6;

  const float* arowf[4];
  const ushortt* arowb[2];
  if constexpr (sizeof(AT) == 4) {
#pragma unroll
    for (int p = 0; p < 4; ++p) {
      int r = row0 + (tid >> 4) + 16 * p;
      if (ROWMAP) {
        int bt = r / Nn;
        int n = r - bt * Nn;
        arowf[p] = (const float*)Ain + (size_t)(bt * (Nn + 1) + 1 + n) * K;
      } else {
        arowf[p] = (const float*)Ain + (size_t)r * K;
      }
    }
  } else {
#pragma unroll
    for (int p = 0; p < 2; ++p)
      arowb[p] = (const ushortt*)Ain + (size_t)(row0 + (tid >> 3) + 32 * p) * K;
  }
  const float* browp[6];
#pragma unroll
  for (int p = 0; p < 6; ++p)
    browp[p] = W + (size_t)(col0 + (tid >> 4) + 16 * p) * K;

  f32x4 acc[2][3];
#pragma unroll
  for (int i = 0; i < 2; ++i)
#pragma unroll
    for (int j = 0; j < 3; ++j) acc[i][j] = (f32x4){0.f, 0.f, 0.f, 0.f};

  float4 apre[4], bpre[6];
  u16x8 apreb[2];

#define STAGE_LOAD(k0)                                                       \
  if constexpr (sizeof(AT) == 4) {                                           \
    _Pragma("unroll") for (int p = 0; p < 4; ++p)                            \
        apre[p] = *(const float4*)(arowf[p] + (k0) + q16 * 4);               \
  } else {                                                                   \
    _Pragma("unroll") for (int p = 0; p < 2; ++p)                            \
        apreb[p] = *(const u16x8*)(arowb[p] + (k0) + q8 * 8);                \
  }                                                                          \
  _Pragma("unroll") for (int p = 0; p < 6; ++p)                              \
      bpre[p] = *(const float4*)(browp[p] + (k0) + q16 * 4);

#define STAGE_WRITE(buf)                                                     \
  if constexpr (sizeof(AT) == 4) {                                           \
    _Pragma("unroll") for (int p = 0; p < 4; ++p) {                          \
      u16x4 b = {f2bf(apre[p].x), f2bf(apre[p].y), f2bf(apre[p].z),          \
                 f2bf(apre[p].w)};                                           \
      *(u16x4*)&As[buf][((tid >> 4) + 16 * p) * PIT + q16 * 4] = b;          \
    }                                                                        \
  } else {                                                                   \
    _Pragma("unroll") for (int p = 0; p < 2; ++p)                            \
        *(u16x8*)&As[buf][((tid >> 3) + 32 * p) * PIT + q8 * 8] = apreb[p];  \
  }                                                                          \
  _Pragma("unroll") for (int p = 0; p < 6; ++p) {                            \
    u16x4 b = {f2bf(bpre[p].x), f2bf(bpre[p].y), f2bf(bpre[p].z),            \
               f2bf(bpre[p].w)};                                             \
    *(u16x4*)&Bs[buf][((tid >> 4) + 16 * p) * PIT + q16 * 4] = b;            \
  }

  STAGE_LOAD(0);
  STAGE_WRITE(0);
  __syncthreads();

  int cur = 0;
  for (int step = 0; step < nsteps; ++step) {
    const bool pref = (step + 1 < nsteps);
    if (pref) {
      int k0 = (step + 1) << 6;
      STAGE_LOAD(k0);
    }
#pragma unroll
    for (int kk = 0; kk < 2; ++kk) {
      bf16x8 af[2], bfv[3];
#pragma unroll
      for (int fm = 0; fm < 2; ++fm)
        af[fm] = *(const bf16x8*)&As[cur][(wr * 32 + fm * 16 + l15) * PIT +
                                          kk * 32 + kgrp * 8];
#pragma unroll
      for (int fn = 0; fn < 3; ++fn)
        bfv[fn] = *(const bf16x8*)&Bs[cur][(wc * 48 + fn * 16 + l15) * PIT +
                                           kk * 32 + kgrp * 8];
#pragma unroll
      for (int fm = 0; fm < 2; ++fm)
#pragma unroll
        for (int fn = 0; fn < 3; ++fn)
          acc[fm][fn] = __builtin_amdgcn_mfma_f32_16x16x32_bf16(
              af[fm], bfv[fn], acc[fm][fn], 0, 0, 0);
    }
    if (pref) {
      STAGE_WRITE(cur ^ 1);
    }
    __syncthreads();
    cur ^= 1;
  }
#undef STAGE_LOAD
#undef STAGE_WRITE

  constexpr int EP = 100;
  float* epi = (float*)smem;
#pragma unroll
  for (int fm = 0; fm < 2; ++fm) {
    int rl = wr * 32 + fm * 16 + kgrp * 4;
#pragma unroll
    for (int fn = 0; fn < 3; ++fn) {
      int cl = wc * 48 + fn * 16 + l15;
#pragma unroll
      for (int j = 0; j < 4; ++j)
        epi[(rl + j) * EP + cl] = acc[fm][fn][j];
    }
  }
  __syncthreads();
#pragma unroll
  for (int it = 0; it < 6; ++it) {
    int f = it * 256 + tid;
    int r = f / 24, c4 = f - r * 24;
    float4 v = *(const float4*)&epi[r * EP + c4 * 4];
    int c = col0 + c4 * 4;
    if (BIAS) {
      float4 bv = *(const float4*)(bias + c);
      v.x += bv.x; v.y += bv.y; v.z += bv.z; v.w += bv.w;
    }
    if (EPI == 1) {
      v.x = gelu_f(v.x); v.y = gelu_f(v.y);
      v.z = gelu_f(v.z); v.w = gelu_f(v.w);
    }
    int R = row0 + r;
    if constexpr (EPI == 2) {
      int bt2 = R / Nn, n2 = R - bt2 * Nn;
      size_t off = (size_t)(bt2 * (Nn + 1) + 1 + n2) * Nc + c;
      float4 rv = *(const float4*)(resid + off);
      v.x += rv.x; v.y += rv.y; v.z += rv.z; v.w += rv.w;
      *(float4*)((float*)Cout + off) = v;
    } else if constexpr (sizeof(CT) == 4) {
      *(float4*)((float*)Cout + (size_t)R * Nc + c) = v;
    } else {
      u16x4 ob = {f2bf(v.x), f2bf(v.y), f2bf(v.z), f2bf(v.w)};
      *(u16x4*)((ushortt*)Cout + (size_t)R * Nc + c) = ob;
    }
  }
}

// ============================================================
// delta (bf16) + per-(b,t) |delta| partials
// ============================================================
__global__ void delta_kernel(const ushortt* __restrict__ ph,
                             ushortt* __restrict__ delta,
                             float* __restrict__ dppart) {
  int bt = blockIdx.x;
  int t = bt & 15;
  int a = threadIdx.x;
  const ushortt* cur = ph + (size_t)bt * Nn * Aa + a;
  ushortt* dl = delta + (size_t)bt * Nn * Aa + a;
  float acc = 0.f;
  if (t == 0) {
    for (int n = 0; n < Nn; ++n) dl[(size_t)n * Aa] = 0;
  } else {
    const ushortt* prev = cur - (size_t)Nn * Aa;
    for (int n = 0; n < Nn; ++n) {
      float d = bf2f(cur[(size_t)n * Aa]) - bf2f(prev[(size_t)n * Aa]);
      dl[(size_t)n * Aa] = f2bf(d);
      acc += fabsf(d);
    }
  }
  dppart[bt * Aa + a] = acc;
}

// sal[row] = mean_a |delta[row,a]| (fp32, candidate stage only)
__global__ void sal_kernel(const ushortt* __restrict__ delta,
                           float* __restrict__ sal) {
  int row = blockIdx.x * 4 + (threadIdx.x >> 6);
  int lane = threadIdx.x & 63;
  const ushortt* d = delta + (size_t)row * Aa;
  float s = fabsf(bf2f(d[lane])) + fabsf(bf2f(d[lane + 64])) +
            fabsf(bf2f(d[lane + 128]));
#pragma unroll
  for (int off = 32; off > 0; off >>= 1) s += __shfl_xor(s, off, 64);
  if (lane == 0) sal[row] = s * (1.0f / 192.0f);
}

// ============================================================
// top-16 fp32 candidates per (b,t); descending val, ties -> smaller n
// ============================================================
__global__ void topcand_kernel(const float* __restrict__ sal,
                               int* __restrict__ cand) {
  int bt = blockIdx.x;
  int lane = threadIdx.x;
  unsigned long long key[4];
#pragma unroll
  for (int j = 0; j < 4; ++j) {
    int n = lane + 64 * j;
    if (n < Nn) {
      unsigned fb = __float_as_uint(sal[(size_t)bt * Nn + n]);
      key[j] = ((unsigned long long)fb << 32) |
               (unsigned long long)(0xFFFFFFFFu - (unsigned)n);
    } else {
      key[j] = 0ULL;
    }
  }
  for (int r = 0; r < NCAND; ++r) {
    unsigned long long m = key[0];
    if (key[1] > m) m = key[1];
    if (key[2] > m) m = key[2];
    if (key[3] > m) m = key[3];
#pragma unroll
    for (int off = 32; off > 0; off >>= 1) {
      unsigned long long o = __shfl_xor(m, off, 64);
      if (o > m) m = o;
    }
    if (lane == 0)
      cand[bt * NCAND + r] = (int)(0xFFFFFFFFu - (unsigned)(m & 0xFFFFFFFFull));
#pragma unroll
    for (int j = 0; j < 4; ++j)
      if (key[j] == m) key[j] = 0ULL;
  }
}

// one-time transpose: wT[c][a] = down_w[a][c]
__global__ void transpose_w(const float* __restrict__ w,
                            float* __restrict__ wT) {
  int e = blockIdx.x * 256 + threadIdx.x;  // over Cc*Aa
  int c = e / Aa, a = e - c * Aa;
  wT[e] = w[(size_t)a * Cc + c];
}

// ============================================================
// f64 refine, 8 candidates per block (grid BT x 2, 192 thr).
// ============================================================
__global__ __launch_bounds__(192) void refine_kernel(
    const float* __restrict__ x, const float* __restrict__ wT,
    const int* __restrict__ cand, double* __restrict__ sal64) {
  int bt = blockIdx.x;
  int grp = blockIdx.y;
  int t = bt & 15;
  int a = threadIdx.x;
  if (t == 0) {
    if (a < 8) sal64[bt * NCAND + grp * 8 + a] = 0.0;
    return;
  }
  __shared__ double sdiff[8][Cc];  // 49 KB
  const float* xt = x + ((size_t)bt * (Nn + 1) + 1) * Cc;
  const float* xp = xt - (size_t)(Nn + 1) * Cc;
  for (int g = 0; g < 8; ++g) {
    int n = cand[bt * NCAND + grp * 8 + g];
    const float* rt = xt + (size_t)n * Cc;
    const float* rp = xp + (size_t)n * Cc;
    for (int c = a; c < Cc; c += 192)
      sdiff[g][c] = (double)rt[c] - (double)rp[c];
  }
  __syncthreads();
  double acc[8] = {};
  for (int c = 0; c < Cc; ++c) {
    double wv = (double)wT[(size_t)c * Aa + a];  // coalesced across lanes
#pragma unroll
    for (int g = 0; g < 8; ++g) acc[g] = fma(wv, sdiff[g][c], acc[g]);
  }
  __shared__ double part[3][8];
  int wvx = a >> 6, ln = a & 63;
#pragma unroll
  for (int g = 0; g < 8; ++g) {
    double v = fabs(acc[g]);
#pragma unroll
    for (int off = 32; off > 0; off >>= 1) v += __shfl_xor(v, off, 64);
    if (ln == 0) part[wvx][g] = v;
  }
  __syncthreads();
  if (a < 8) {
    double s = part[0][a] + part[1][a] + part[2][a];
    sal64[bt * NCAND + grp * 8 + a] = s * (1.0 / 192.0);
  }
}

// ============================================================
// final top-8 by (sal64 desc, n asc) — wave-parallel, in registers
// ============================================================
__global__ void select_kernel(const double* __restrict__ sal64,
                              const int* __restrict__ cand,
                              int* __restrict__ idx) {
  int bt = blockIdx.x;
  int t = bt & 15;
  int lane = threadIdx.x;  // 64
  if (t == 0) {
    if (lane < KK) idx[bt * KK + lane] = lane;
    return;
  }
  double v = (lane < NCAND) ? sal64[bt * NCAND + lane] : -1.0;
  int n = (lane < NCAND) ? cand[bt * NCAND + lane] : 0x7FFFFFFF;
  for (int r = 0; r < KK; ++r) {
    double bv = v;
    int bn = n, bl = lane;
#pragma unroll
    for (int off = 8; off >= 1; off >>= 1) {
      double ov = __shfl_xor(bv, off, 64);
      int on = __shfl_xor(bn, off, 64);
      int ol = __shfl_xor(bl, off, 64);
      if (ov > bv || (ov == bv && on < bn)) { bv = ov; bn = on; bl = ol; }
    }
    if (lane == 0) idx[bt * KK + r] = bn;
    if (lane == bl) v = -1.0;  // retire winner
  }
}

// ============================================================
// anchor attention: gather(bf16) -> GEMM qkv -> core -> GEMMs
// ============================================================
__global__ void gather_kernel(const ushortt* __restrict__ ph,
                              const ushortt* __restrict__ delta,
                              const int* __restrict__ idx,
                              ushortt* __restrict__ tok) {
  int row = blockIdx.x;  // (b*KK+k)*16+t
  int t = row & 15;
  int bk = row >> 4;
  int b = bk >> 3, k = bk & 7;
  int a = threadIdx.x;
  int n = idx[(b * 16 + t) * KK + k];
  size_t off = ((size_t)(b * 16 + t) * Nn + n) * Aa + a;
  tok[(size_t)row * Aa + a] = f2bf(bf2f(ph[off]) + bf2f(delta[off]));
}

__global__ __launch_bounds__(256) void attn_core(
    const float* __restrict__ qkv, float* __restrict__ o) {
  constexpr int P = 580;
  __shared__ float sq[16 * P];
  __shared__ float ssc[4][16][17];
  int bk = blockIdx.x;
  int tid = threadIdx.x;
  const float* src = qkv + (size_t)bk * 16 * 576;
  for (int e = tid; e < 16 * 144; e += 256) {
    int r = e / 144, c4 = e % 144;
    float4 v = *(const float4*)(src + r * 576 + c4 * 4);
    *(float4*)(&sq[r * P + c4 * 4]) = v;
  }
  __syncthreads();
  int h = tid >> 6, lane = tid & 63;
#pragma unroll
  for (int s4 = 0; s4 < 4; ++s4) {
    int e = lane + 64 * s4;
    int i = e >> 4, j = e & 15;
    const float* q = sq + i * P + h * 48;
    const float* k2 = sq + j * P + 192 + h * 48;
    float s = 0.f;
#pragma unroll
    for (int d = 0; d < 48; ++d) s = fmaf(q[d], k2[d], s);
    ssc[h][i][j] = s * 0.14433756729740643f;  // 1/sqrt(48)
  }
  __syncthreads();
  if (lane < 16) {
    float* r = ssc[h][lane];
    float mx = r[0];
    for (int j = 1; j < 16; ++j) mx = fmaxf(mx, r[j]);
    float sum = 0.f;
    for (int j = 0; j < 16; ++j) {
      float ev = expf(r[j] - mx);
      r[j] = ev;
      sum += ev;
    }
    float inv = 1.0f / sum;
    for (int j = 0; j < 16; ++j) r[j] *= inv;
  }
  __syncthreads();
#pragma unroll
  for (int s4 = 0; s4 < 12; ++s4) {
    int e = lane + 64 * s4;
    int i = e / 48, d = e - i * 48;
    float s = 0.f;
#pragma unroll
    for (int j = 0; j < 16; ++j)
      s = fmaf(ssc[h][i][j], sq[j * P + 384 + h * 48 + d], s);
    o[((size_t)bk * 16 + i) * 192 + h * 48 + d] = s;
  }
}

__global__ void appart_kernel(const float* __restrict__ attout,
                              float* __restrict__ appart) {
  int bk = blockIdx.x;
  int a = threadIdx.x;
  float s = 0.f;
  for (int t = 0; t < Tt; ++t)
    s += attout[((size_t)bk * Tt + t) * Aa + a];
  appart[bk * Aa + a] = s;
}

// in-place fp32 LayerNorm over last dim (192); one wave per row
__global__ void ln32_kernel(float* __restrict__ buf,
                            const float* __restrict__ g,
                            const float* __restrict__ bb) {
  size_t row = (size_t)blockIdx.x * 4 + (threadIdx.x >> 6);
  int lane = threadIdx.x & 63;
  float* p = buf + row * Aa;
  float v0 = p[lane], v1 = p[lane + 64], v2 = p[lane + 128];
  float s = v0 + v1 + v2;
#pragma unroll
  for (int off = 32; off > 0; off >>= 1) s += __shfl_xor(s, off, 64);
  float m = s * (1.0f / 192.0f);
  float d0 = v0 - m, d1 = v1 - m, d2 = v2 - m;
  float ss = d0 * d0 + d1 * d1 + d2 * d2;
#pragma unroll
  for (int off = 32; off > 0; off >>= 1) ss += __shfl_xor(ss, off, 64);
  float inv = rsqrtf(ss * (1.0f / 192.0f) + 1e-5f);
  p[lane] = d0 * inv * g[lane] + bb[lane];
  p[lane + 64] = d1 * inv * g[lane + 64] + bb[lane + 64];
  p[lane + 128] = d2 * inv * g[lane + 128] + bb[lane + 128];
}

// depthwise 3x3 SAME conv over 14x14 + gelu; bf16 in/out
__global__ void conv2d_kernel(const ushortt* __restrict__ ph,
                              const float* __restrict__ ldw,
                              ushortt* __restrict__ og) {
  size_t e = (size_t)blockIdx.x * 256 + threadIdx.x;
  int a = (int)(e % Aa);
  size_t r = e / Aa;
  int n = (int)(r % Nn);
  int bt = (int)(r / Nn);
  int y = n / 14, x = n % 14;
  const ushortt* base = ph + (size_t)bt * Nn * Aa + a;
  const float* w = ldw + a * 9;
  float s = 0.f;
#pragma unroll
  for (int dy = -1; dy <= 1; ++dy) {
    int yy = y + dy;
    if (yy < 0 || yy >= 14) continue;
#pragma unroll
    for (int dx = -1; dx <= 1; ++dx) {
      int xc = x + dx;
      if (xc < 0 || xc >= 14) continue;
      s = fmaf(bf2f(base[(size_t)(yy * 14 + xc) * Aa]),
               w[(dy + 1) * 3 + (dx + 1)], s);
    }
  }
  og[e] = f2bf(gelu_f(s));
}

// depthwise k=3 SAME conv over t + gelu; bf16 in/out
__global__ void conv1d_kernel(const ushortt* __restrict__ delta,
                              const float* __restrict__ tdw,
                              ushortt* __restrict__ og) {
  size_t e = (size_t)blockIdx.x * 256 + threadIdx.x;
  int a = (int)(e % Aa);
  size_t r = e / Aa;
  int n = (int)(r % Nn);
  int bt = (int)(r / Nn);
  int t = bt & 15, b = bt >> 4;
  const float* w = tdw + a * 3;
  float s = 0.f;
#pragma unroll
  for (int j = 0; j < 3; ++j) {
    int tt = t + j - 1;
    if (tt >= 0 && tt < Tt)
      s = fmaf(bf2f(delta[((size_t)(b * Tt + tt) * Nn + n) * Aa + a]), w[j], s);
  }
  og[e] = f2bf(gelu_f(s));
}

// in-place LayerNorm over last dim (192); one wave per row (bf16)
__global__ void ln_kernel(ushortt* __restrict__ buf,
                          const float* __restrict__ g,
                          const float* __restrict__ bb) {
  size_t row = (size_t)blockIdx.x * 4 + (threadIdx.x >> 6);
  int lane = threadIdx.x & 63;
  ushortt* p = buf + row * Aa;
  float v0 = bf2f(p[lane]), v1 = bf2f(p[lane + 64]), v2 = bf2f(p[lane + 128]);
  float s = v0 + v1 + v2;
#pragma unroll
  for (int off = 32; off > 0; off >>= 1) s += __shfl_xor(s, off, 64);
  float m = s * (1.0f / 192.0f);
  float d0 = v0 - m, d1 = v1 - m, d2 = v2 - m;
  float ss = d0 * d0 + d1 * d1 + d2 * d2;
#pragma unroll
  for (int off = 32; off > 0; off >>= 1) ss += __shfl_xor(ss, off, 64);
  float inv = rsqrtf(ss * (1.0f / 192.0f) + 1e-5f);
  p[lane] = f2bf(d0 * inv * g[lane] + bb[lane]);
  p[lane + 64] = f2bf(d1 * inv * g[lane + 64] + bb[lane + 64]);
  p[lane + 128] = f2bf(d2 * inv * g[lane + 128] + bb[lane + 128]);
}

// posmap[bt*Nn + idx[bt,k]] = k+1 (posmap pre-zeroed)
__global__ void scatter_pos(const int* __restrict__ idx,
                            short* __restrict__ posmap) {
  int bt = blockIdx.x;
  int k = threadIdx.x;
  if (k < KK) posmap[bt * Nn + idx[bt * KK + k]] = (short)(k + 1);
}

// gate MLP + 3-way softmax; one block per b, 192 threads
__global__ void gate_kernel(const float* __restrict__ dppart,
                            const float* __restrict__ appart,
                            const float* __restrict__ w1,
                            const float* __restrict__ b1,
                            const float* __restrict__ w2,
                            const float* __restrict__ b2,
                            float* __restrict__ gw) {
  int b = blockIdx.x;
  __shared__ float sg[2 * Aa];
  __shared__ float sh[Aa];
  int tid = threadIdx.x;
  {
    float d = 0.f;
    for (int t2 = 0; t2 < Tt; ++t2) d += dppart[(b * Tt + t2) * Aa + tid];
    sg[tid] = d * (1.0f / 3136.0f);
    float a = 0.f;
    for (int k2 = 0; k2 < KK; ++k2) a += appart[(b * KK + k2) * Aa + tid];
    sg[Aa + tid] = a * (1.0f / 128.0f);
  }
  __syncthreads();
  {
    const float* w = w1 + (size_t)tid * 2 * Aa;
    float s = b1[tid];
#pragma unroll 8
    for (int j = 0; j < 2 * Aa; ++j) s = fmaf(sg[j], w[j], s);
    sh[tid] = gelu_f(s);
  }
  __syncthreads();
  float v[3];
#pragma unroll
  for (int i = 0; i < 3; ++i) {
    const float* w = w2 + (size_t)(i * Aa + tid) * Aa;
    float s = b2[i * Aa + tid];
#pragma unroll 8
    for (int j = 0; j < Aa; ++j) s = fmaf(sh[j], w[j], s);
    v[i] = s;
  }
  float mx = fmaxf(v[0], fmaxf(v[1], v[2]));
  float e0 = expf(v[0] - mx), e1 = expf(v[1] - mx), e2 = expf(v[2] - mx);
  float inv = 1.0f / (e0 + e1 + e2);
  gw[(b * 3 + 0) * Aa + tid] = e0 * inv;
  gw[(b * 3 + 1) * Aa + tid] = e1 * inv;
  gw[(b * 3 + 2) * Aa + tid] = e2 * inv;
}

// fused = gw0*local + gw1*trans + gw2*amap_ln; fmean fp32
__global__ void fused_kernel(const ushortt* __restrict__ local,
                             const ushortt* __restrict__ trans,
                             const float* __restrict__ attln,
                             const short* __restrict__ posmap,
                             const float* __restrict__ anb,
                             const float* __restrict__ gw,
                             ushortt* __restrict__ fused,
                             float* __restrict__ fmean) {
  int bt = blockIdx.x;
  int b = bt >> 4, t = bt & 15;
  int a = threadIdx.x;
  float g0 = gw[(b * 3 + 0) * Aa + a];
  float g1 = gw[(b * 3 + 1) * Aa + a];
  float g2 = gw[(b * 3 + 2) * Aa + a];
  float ab = anb[a];
  size_t base = (size_t)bt * Nn * Aa + a;
  float acc = 0.f;
  for (int n = 0; n < Nn; ++n) {
    size_t o = base + (size_t)n * Aa;
    short pos = posmap[bt * Nn + n];
    float am = pos ? attln[(((size_t)(b * KK + pos - 1) * Tt) + t) * Aa + a]
                   : ab;
    float f = g0 * bf2f(local[o]) + g1 * bf2f(trans[o]) + g2 * am;
    fused[o] = f2bf(f);
    acc += f;
  }
  fmean[bt * Aa + a] = acc;
}

// cls_out = cls_tok + (mean_n fused) @ cls_w.T + cls_b
__global__ void cls_kernel(const float* __restrict__ fmean,
                           const float* __restrict__ cw,
                           const float* __restrict__ cb,
                           const float* __restrict__ x,
                           float* __restrict__ out) {
  int bt = blockIdx.x;
  __shared__ float fm[Aa];
  int tid = threadIdx.x;
  if (tid < Aa) fm[tid] = fmean[bt * Aa + tid] * (1.0f / 196.0f);
  __syncthreads();
  for (int c = tid; c < Cc; c += 256) {
    const float* w = cw + (size_t)c * Aa;
    float s = cb[c];
#pragma unroll 8
    for (int a = 0; a < Aa; ++a) s = fmaf(fm[a], w[a], s);
    size_t off = (size_t)bt * (Nn + 1) * Cc + c;
    out[off] = x[off] + s;
  }
}

// ============================================================
extern "C" void kernel_launch(void* const* d_in, const int* in_sizes, int n_in,
                              void* d_out, int out_size, void* d_ws,
                              size_t ws_size, hipStream_t stream) {
  const float* x = (const float*)d_in[0];
  const float* down_w = (const float*)d_in[1];
  const float* down_b = (const float*)d_in[2];
  const float* ldw_w = (const float*)d_in[3];
  const float* lpw_w = (const float*)d_in[4];
  const float* lnorm_g = (const float*)d_in[5];
  const float* lnorm_b = (const float*)d_in[6];
  const float* tdw_w = (const float*)d_in[7];
  const float* tpw_w = (const float*)d_in[8];
  const float* tmlp_w1 = (const float*)d_in[9];
  const float* tmlp_b1 = (const float*)d_in[10];
  const float* tmlp_w2 = (const float*)d_in[11];
  const float* tmlp_b2 = (const float*)d_in[12];
  const float* tnorm_g = (const float*)d_in[13];
  const float* tnorm_b = (const float*)d_in[14];
  const float* attn_in_w = (const float*)d_in[15];
  const float* attn_in_b = (const float*)d_in[16];
  const float* attn_out_w = (const float*)d_in[17];
  const float* attn_out_b = (const float*)d_in[18];
  const float* aproj_w = (const float*)d_in[19];
  const float* aproj_b = (const float*)d_in[20];
  const float* anorm_g = (const float*)d_in[21];
  const float* anorm_b = (const float*)d_in[22];
  const float* gate_w1 = (const float*)d_in[23];
  const float* gate_b1 = (const float*)d_in[24];
  const float* gate_w2 = (const float*)d_in[25];
  const float* gate_b2 = (const float*)d_in[26];
  const float* up_w = (const float*)d_in[27];
  const float* up_b = (const float*)d_in[28];
  const float* cls_w = (const float*)d_in[29];
  const float* cls_b = (const float*)d_in[30];
  float* out = (float*)d_out;

  float* ws = (float*)d_ws;
  float* W0 = ws;              // ph bf16 -> trp bf16
  float* W1 = W0 + SZ;         // delta bf16 -> transition bf16
  float* W2 = W1 + SZ;         // attn scratch -> locg/trg/h1/fused bf16
  float* W3 = W2 + 2 * SZ;     // local bf16
  float* sal = W3 + SZ;
  float* attout = sal + BTN;
  float* dppart = attout + (size_t)BKT * Aa;
  float* appart = dppart + (size_t)BT * Aa;
  float* gw = appart + (size_t)Bb * KK * Aa;
  float* fmean = gw + (size_t)Bb * 3 * Aa;
  double* sal64 = (double*)(fmean + (size_t)BT * Aa);  // BT*NCAND doubles
  int* cand = (int*)(sal64 + (size_t)BT * NCAND);      // BT*NCAND ints
  int* idx = cand + (size_t)BT * NCAND;                // BT*KK ints
  float* wT = (float*)(idx + (size_t)BT * KK);         // Cc*Aa floats
  short* posmap = (short*)(wT + (size_t)Cc * Aa);      // BT*Nn shorts
  ushortt* wbuf = (ushortt*)(posmap + (size_t)BT * Nn);  // OTOT bf16

  // bf16 weight views
  ushortt* wb_attnin = wbuf + O1;
  ushortt* wb_lpw    = wbuf + O4;
  ushortt* wb_tpw    = wbuf + O5;
  ushortt* wb_t1     = wbuf + O6;
  ushortt* wb_t2     = wbuf + O7;
  ushortt* wb_up     = wbuf + O8;

  // bf16 activation views
  ushortt* ph_b    = (ushortt*)W0;
  ushortt* trp_b   = (ushortt*)W0;
  ushortt* delta_b = (ushortt*)W1;
  ushortt* trans_b = (ushortt*)W1;
  ushortt* locg_b  = (ushortt*)W2;
  ushortt* trg_b   = (ushortt*)W2;
  ushortt* h1_b    = (ushortt*)W2;
  ushortt* fused_b = (ushortt*)W2;
  ushortt* local_b = (ushortt*)W3;

  // attn-phase scratch inside W2 (dead until conv2d)
  ushortt* tok_b = (ushortt*)W2;                       // 2048*192 bf16
  float* qkvb  = W2 + (size_t)BKT * Aa / 2;            // 2048*576 f32
  float* obuf  = qkvb + (size_t)BKT * 3 * Aa;          // 2048*192 f32
  float* proj1 = obuf + (size_t)BKT * Aa;              // 2048*192 f32

  // 0. weights -> bf16 (one pass), wT for refine
  cvtw_kernel<<<OTOT / 256, 256, 0, stream>>>(
      down_w, attn_in_w, attn_out_w, aproj_w, lpw_w, tpw_w, tmlp_w1,
      tmlp_w2, up_w, wbuf);
  transpose_w<<<(Cc * Aa) / 256, 256, 0, stream>>>(down_w, wT);
  // 1. ph = patch @ down_w.T + down_b (bf16 out)  [fp32-A reg path]
  gemm_mfma<float, ushortt, 1, 1, 0><<<dim3(2, 784), 256, 0, stream>>>(
      x, down_w, down_b, ph_b, nullptr, BTN, Aa, Cc);
  // 2. delta + dp partials
  delta_kernel<<<BT, Aa, 0, stream>>>(ph_b, delta_b, dppart);
  // 3. saliency: fp32 candidates -> f64 refine -> exact top-8
  sal_kernel<<<BTN / 4, 256, 0, stream>>>(delta_b, sal);
  topcand_kernel<<<BT, 64, 0, stream>>>(sal, cand);
  refine_kernel<<<dim3(BT, 2), 192, 0, stream>>>(x, wT, cand, sal64);
  select_kernel<<<BT, 64, 0, stream>>>(sal64, cand, idx);
  // 4. anchor attention
  gather_kernel<<<BKT, Aa, 0, stream>>>(ph_b, delta_b, idx, tok_b);
  gemm_lds<float, 1, 0><<<dim3(6, 32), 256, 0, stream>>>(
      tok_b, wb_attnin, attn_in_b, qkvb, nullptr, BKT, 3 * Aa, Aa);
  attn_core<<<Bb * KK, 256, 0, stream>>>(qkvb, obuf);
  gemm_mfma<float, float, 0, 1, 0><<<dim3(2, 32), 256, 0, stream>>>(
      obuf, attn_out_w, attn_out_b, proj1, nullptr, BKT, Aa, Aa);
  gemm_mfma<float, float, 0, 1, 0><<<dim3(2, 32), 256, 0, stream>>>(
      proj1, aproj_w, aproj_b, attout, nullptr, BKT, Aa, Aa);
  appart_kernel<<<Bb * KK, Aa, 0, stream>>>(attout, appart);
  // 4b. LN the 2048 anchor rows in place
  ln32_kernel<<<BKT / 4, 256, 0, stream>>>(attout, anorm_g, anorm_b);
  hipMemsetAsync(posmap, 0, (size_t)BT * Nn * sizeof(short), stream);
  scatter_pos<<<BT, 64, 0, stream>>>(idx, posmap);
  // 5. local branch
  conv2d_kernel<<<(unsigned)(SZ / 256), 256, 0, stream>>>(ph_b, ldw_w, locg_b);
  gemm_lds<ushortt, 0, 0><<<dim3(2, 784), 256, 0, stream>>>(
      locg_b, wb_lpw, nullptr, local_b, nullptr, BTN, Aa, Aa);
  ln_kernel<<<BTN / 4, 256, 0, stream>>>(local_b, lnorm_g, lnorm_b);
  // 6. transition branch
  conv1d_kernel<<<(unsigned)(SZ / 256), 256, 0, stream>>>(delta_b, tdw_w, trg_b);
  gemm_lds<ushortt, 0, 0><<<dim3(2, 784), 256, 0, stream>>>(
      trg_b, wb_tpw, nullptr, trp_b, nullptr, BTN, Aa, Aa);
  gemm_lds<ushortt, 1, 1><<<dim3(4, 784), 256, 0, stream>>>(
      trp_b, wb_t1, tmlp_b1, h1_b, nullptr, BTN, 2 * Aa, Aa);
  gemm_lds<ushortt, 1, 0><<<dim3(2, 784), 256, 0, stream>>>(
      h1_b, wb_t2, tmlp_b2, trans_b, nullptr, BTN, Aa, 2 * Aa);
  ln_kernel<<<BTN / 4, 256, 0, stream>>>(trans_b, tnorm_g, tnorm_b);
  // 8. gate
  gate_kernel<<<Bb, Aa, 0, stream>>>(dppart, appart, gate_w1, gate_b1,
                                     gate_w2, gate_b2, gw);
  // 9. fuse + output projections
  fused_kernel<<<BT, Aa, 0, stream>>>(local_b, trans_b, attout, posmap,
                                      anorm_b, gw, fused_b, fmean);
  gemm_lds<float, 1, 2><<<dim3(8, 784), 256, 0, stream>>>(
      fused_b, wb_up, up_b, out, x, BTN, Cc, Aa);
  cls_kernel<<<BT, 256, 0, stream>>>(fmean, cls_w, cls_b, x, out);
}

// Round 16
// 576.323 us; speedup vs baseline: 1.9229x; 1.0058x over previous
//
#include <hip/hip_runtime.h>
#include <hip/hip_bf16.h>
#include <math.h>

// ---- fixed problem dims ----
constexpr int Bb  = 16;
constexpr int Tt  = 16;
constexpr int Nn  = 196;   // patches (14x14)
constexpr int Cc  = 768;
constexpr int Aa  = 192;
constexpr int KK  = 8;     // TOPK
constexpr int NCAND = 16;  // fp32 candidates refined in f64
constexpr int BT  = Bb * Tt;            // 256
constexpr int BTN = BT * Nn;            // 50176
constexpr int BKT = Bb * KK * Tt;       // 2048 anchor-token rows
constexpr size_t SZ = (size_t)BTN * Aa; // 9,633,792 floats

typedef unsigned short ushortt;
typedef __attribute__((ext_vector_type(8))) short bf16x8;
typedef __attribute__((ext_vector_type(4))) float f32x4;
typedef __attribute__((ext_vector_type(4))) unsigned short u16x4;
typedef __attribute__((ext_vector_type(8))) unsigned short u16x8;

static __device__ __forceinline__ float gelu_f(float x) {
  return 0.5f * x * (1.0f + erff(x * 0.7071067811865476f));
}
// HARDWARE bf16 convert (v_cvt_pk_bf16_f32 path via HIP cast)
static __device__ __forceinline__ ushortt f2bf(float f) {
  __hip_bfloat16 h = __float2bfloat16(f);
  return *reinterpret_cast<ushortt*>(&h);
}
static __device__ __forceinline__ float bf2f(ushortt u) {
  return __uint_as_float(((unsigned)u) << 16);
}
// async global->LDS, 16B per lane (dest = wave-uniform base + lane*16)
static __device__ __forceinline__ void gload16(const void* g, void* l) {
  __builtin_amdgcn_global_load_lds(
      (const __attribute__((address_space(1))) void*)g,
      (__attribute__((address_space(3))) void*)l, 16, 0, 0);
}

// ---- weight pre-convert: all GEMM weights fp32 -> bf16, one kernel ----
constexpr int S_down   = Aa * Cc;        // 147456
constexpr int S_attnin = 3 * Aa * Aa;    // 110592
constexpr int S_sq     = Aa * Aa;        // 36864
constexpr int S_t      = 2 * Aa * Aa;    // 73728
constexpr int O1 = S_down;               // attn_in
constexpr int O2 = O1 + S_attnin;        // attn_out
constexpr int O3 = O2 + S_sq;            // aproj
constexpr int O4 = O3 + S_sq;            // lpw
constexpr int O5 = O4 + S_sq;            // tpw
constexpr int O6 = O5 + S_sq;            // tmlp1
constexpr int O7 = O6 + S_t;             // tmlp2
constexpr int O8 = O7 + S_t;             // up
constexpr int OTOT = O8 + S_down;        // 700416 (== 2736*256)

__global__ void cvtw_kernel(const float* __restrict__ w0,
                            const float* __restrict__ w1,
                            const float* __restrict__ w2,
                            const float* __restrict__ w3,
                            const float* __restrict__ w4,
                            const float* __restrict__ w5,
                            const float* __restrict__ w6,
                            const float* __restrict__ w7,
                            const float* __restrict__ w8,
                            ushortt* __restrict__ outw) {
  int e = blockIdx.x * 256 + threadIdx.x;
  const float* src;
  int off;
  if (e < O1)      { src = w0; off = 0;  }
  else if (e < O2) { src = w1; off = O1; }
  else if (e < O3) { src = w2; off = O2; }
  else if (e < O4) { src = w3; off = O3; }
  else if (e < O5) { src = w4; off = O4; }
  else if (e < O6) { src = w5; off = O5; }
  else if (e < O7) { src = w6; off = O6; }
  else if (e < O8) { src = w7; off = O7; }
  else             { src = w8; off = O8; }
  outw[e] = f2bf(src[e - off]);
}

// ============================================================
// gemm_lds: bf16 A & bf16 W, both staged via global_load_lds (w=16).
// BM=64 BN=96 BK=64; 256 thr = 4 waves (2x2), wave tile 32x48.
// Linear LDS + both-sides XOR swizzle (src colchunk 16*((l%8)^(l/8)),
// read byte ^ ((row&7)<<4)). EPI: 0 plain, 1 gelu, 2 residual fp32.
// ============================================================
template <typename CT, int BIAS, int EPI>
__global__ __launch_bounds__(256) void gemm_lds(
    const ushortt* __restrict__ Ain, const ushortt* __restrict__ Wb,
    const float* __restrict__ bias, CT* __restrict__ Cout,
    const float* __restrict__ resid, int M, int Nc, int K) {
  __shared__ __align__(16) unsigned char smem[40960];
  ushortt (*As)[64 * 64] = (ushortt(*)[64 * 64])smem;
  ushortt (*Bs)[96 * 64] = (ushortt(*)[96 * 64])(smem + 2 * 64 * 64 * 2);
  const int tid = threadIdx.x;

  const int ncb = gridDim.x;
  const int nwg = ncb * gridDim.y;
  const int bid = blockIdx.y * ncb + blockIdx.x;
  const int cpx = nwg >> 3;
  const int swz = (bid & 7) * cpx + (bid >> 3);
  const int row0 = (swz / ncb) * 64;
  const int col0 = (swz % ncb) * 96;

  const int wid = tid >> 6;
  const int lane = tid & 63;
  const int wr = wid >> 1;
  const int wc = wid & 1;
  const int l15 = lane & 15;
  const int kgrp = lane >> 4;

  const int lr = lane >> 3;
  const int lc = 8 * ((lane & 7) ^ lr);

  f32x4 acc[2][3];
#pragma unroll
  for (int i = 0; i < 2; ++i)
#pragma unroll
    for (int j = 0; j < 3; ++j) acc[i][j] = (f32x4){0.f, 0.f, 0.f, 0.f};

#define ISSUE(buf, k0)                                                       \
  do {                                                                       \
    _Pragma("unroll") for (int i = 0; i < 2; ++i) {                          \
      int j = 2 * wid + i;                                                   \
      const ushortt* g =                                                     \
          Ain + (size_t)(row0 + 8 * j + lr) * K + (k0) + lc;                 \
      gload16(g, &As[buf][j * 512]);                                         \
    }                                                                        \
    _Pragma("unroll") for (int i = 0; i < 3; ++i) {                          \
      int j = 3 * wid + i;                                                   \
      const ushortt* g =                                                     \
          Wb + (size_t)(col0 + 8 * j + lr) * K + (k0) + lc;                  \
      gload16(g, &Bs[buf][j * 512]);                                         \
    }                                                                        \
  } while (0)

  ISSUE(0, 0);
  __syncthreads();

  const int nsteps = K >> 6;
  int cur = 0;
  for (int step = 0; step < nsteps; ++step) {
    const bool pref = (step + 1 < nsteps);
    if (pref) ISSUE(cur ^ 1, (step + 1) << 6);
#pragma unroll
    for (int kk = 0; kk < 2; ++kk) {
      const int cb = kk * 64 + kgrp * 16;
      bf16x8 af[2], bfv[3];
#pragma unroll
      for (int fm = 0; fm < 2; ++fm) {
        int r = wr * 32 + fm * 16 + l15;
        af[fm] = *(const bf16x8*)&As[cur][r * 64 +
                                          ((cb ^ ((r & 7) << 4)) >> 1)];
      }
#pragma unroll
      for (int fn = 0; fn < 3; ++fn) {
        int r = wc * 48 + fn * 16 + l15;
        bfv[fn] = *(const bf16x8*)&Bs[cur][r * 64 +
                                           ((cb ^ ((r & 7) << 4)) >> 1)];
      }
#pragma unroll
      for (int fm = 0; fm < 2; ++fm)
#pragma unroll
        for (int fn = 0; fn < 3; ++fn)
          acc[fm][fn] = __builtin_amdgcn_mfma_f32_16x16x32_bf16(
              af[fm], bfv[fn], acc[fm][fn], 0, 0, 0);
    }
    __syncthreads();
    cur ^= 1;
  }
#undef ISSUE

  constexpr int EP = 100;
  float* epi = (float*)smem;
#pragma unroll
  for (int fm = 0; fm < 2; ++fm) {
    int rl = wr * 32 + fm * 16 + kgrp * 4;
#pragma unroll
    for (int fn = 0; fn < 3; ++fn) {
      int cl = wc * 48 + fn * 16 + l15;
#pragma unroll
      for (int j = 0; j < 4; ++j)
        epi[(rl + j) * EP + cl] = acc[fm][fn][j];
    }
  }
  __syncthreads();
#pragma unroll
  for (int it = 0; it < 6; ++it) {
    int f = it * 256 + tid;
    int r = f / 24, c4 = f - r * 24;
    float4 v = *(const float4*)&epi[r * EP + c4 * 4];
    int c = col0 + c4 * 4;
    if (BIAS) {
      float4 bv = *(const float4*)(bias + c);
      v.x += bv.x; v.y += bv.y; v.z += bv.z; v.w += bv.w;
    }
    if (EPI == 1) {
      v.x = gelu_f(v.x); v.y = gelu_f(v.y);
      v.z = gelu_f(v.z); v.w = gelu_f(v.w);
    }
    int R = row0 + r;
    if constexpr (EPI == 2) {
      int bt2 = R / Nn, n2 = R - bt2 * Nn;
      size_t off = (size_t)(bt2 * (Nn + 1) + 1 + n2) * Nc + c;
      float4 rv = *(const float4*)(resid + off);
      v.x += rv.x; v.y += rv.y; v.z += rv.z; v.w += rv.w;
      *(float4*)((float*)Cout + off) = v;
    } else if constexpr (sizeof(CT) == 4) {
      *(float4*)((float*)Cout + (size_t)R * Nc + c) = v;
    } else {
      u16x4 ob = {f2bf(v.x), f2bf(v.y), f2bf(v.z), f2bf(v.w)};
      *(u16x4*)((ushortt*)Cout + (size_t)R * Nc + c) = ob;
    }
  }
}

// ============================================================
// gemm_hyb (r16): fp32 A reg-staged into PITCHED LDS (r13 path),
// bf16 W via global_load_lds into LINEAR LDS + XOR-swizzle read
// (r15 path). Per-thread staging drops from 10 loads/40 cvt/10
// ds_writes to 4/16/4 + 3 gload instrs. Same math, bit-identical.
// ============================================================
template <int ROWMAP, typename CT, int BIAS, int EPI>
__global__ __launch_bounds__(256) void gemm_hyb(
    const float* __restrict__ Ain, const ushortt* __restrict__ Wb,
    const float* __restrict__ bias, CT* __restrict__ Cout,
    const float* __restrict__ resid, int M, int Nc, int K) {
  constexpr int PIT = 72;  // A pitch (64+8) bf16
  // A: 2*64*72*2 = 18432 B ; B: 2*96*64*2 = 24576 B ; total 43008 B
  __shared__ __align__(16) unsigned char smem[43008];
  ushortt (*As)[64 * PIT] = (ushortt(*)[64 * PIT])smem;
  ushortt (*Bs)[96 * 64] = (ushortt(*)[96 * 64])(smem + 18432);
  const int tid = threadIdx.x;

  const int ncb = gridDim.x;
  const int nwg = ncb * gridDim.y;
  const int bid = blockIdx.y * ncb + blockIdx.x;
  const int cpx = nwg >> 3;
  const int swz = (bid & 7) * cpx + (bid >> 3);
  const int row0 = (swz / ncb) * 64;
  const int col0 = (swz % ncb) * 96;

  const int wid = tid >> 6;
  const int lane = tid & 63;
  const int wr = wid >> 1;
  const int wc = wid & 1;
  const int l15 = lane & 15;
  const int kgrp = lane >> 4;

  const int q16 = tid & 15;
  const int lr = lane >> 3;
  const int lc = 8 * ((lane & 7) ^ lr);

  const int nsteps = K >> 6;

  const float* arowf[4];
#pragma unroll
  for (int p = 0; p < 4; ++p) {
    int r = row0 + (tid >> 4) + 16 * p;
    if (ROWMAP) {
      int bt = r / Nn;
      int n = r - bt * Nn;
      arowf[p] = Ain + (size_t)(bt * (Nn + 1) + 1 + n) * K;
    } else {
      arowf[p] = Ain + (size_t)r * K;
    }
  }

  f32x4 acc[2][3];
#pragma unroll
  for (int i = 0; i < 2; ++i)
#pragma unroll
    for (int j = 0; j < 3; ++j) acc[i][j] = (f32x4){0.f, 0.f, 0.f, 0.f};

  float4 apre[4];

#define ISSUE_B(buf, k0)                                                     \
  do {                                                                       \
    _Pragma("unroll") for (int i = 0; i < 3; ++i) {                          \
      int j = 3 * wid + i;                                                   \
      const ushortt* g =                                                     \
          Wb + (size_t)(col0 + 8 * j + lr) * K + (k0) + lc;                  \
      gload16(g, &Bs[buf][j * 512]);                                         \
    }                                                                        \
  } while (0)

#define STAGE_LOAD_A(k0)                                                     \
  _Pragma("unroll") for (int p = 0; p < 4; ++p)                              \
      apre[p] = *(const float4*)(arowf[p] + (k0) + q16 * 4);

#define STAGE_WRITE_A(buf)                                                   \
  _Pragma("unroll") for (int p = 0; p < 4; ++p) {                            \
    u16x4 b = {f2bf(apre[p].x), f2bf(apre[p].y), f2bf(apre[p].z),            \
               f2bf(apre[p].w)};                                             \
    *(u16x4*)&As[buf][((tid >> 4) + 16 * p) * PIT + q16 * 4] = b;            \
  }

  ISSUE_B(0, 0);
  STAGE_LOAD_A(0);
  STAGE_WRITE_A(0);
  __syncthreads();

  int cur = 0;
  for (int step = 0; step < nsteps; ++step) {
    const bool pref = (step + 1 < nsteps);
    if (pref) {
      int k0 = (step + 1) << 6;
      ISSUE_B(cur ^ 1, k0);
      STAGE_LOAD_A(k0);
    }
#pragma unroll
    for (int kk = 0; kk < 2; ++kk) {
      const int cb = kk * 64 + kgrp * 16;
      bf16x8 af[2], bfv[3];
#pragma unroll
      for (int fm = 0; fm < 2; ++fm)
        af[fm] = *(const bf16x8*)&As[cur][(wr * 32 + fm * 16 + l15) * PIT +
                                          kk * 32 + kgrp * 8];
#pragma unroll
      for (int fn = 0; fn < 3; ++fn) {
        int r = wc * 48 + fn * 16 + l15;
        bfv[fn] = *(const bf16x8*)&Bs[cur][r * 64 +
                                           ((cb ^ ((r & 7) << 4)) >> 1)];
      }
#pragma unroll
      for (int fm = 0; fm < 2; ++fm)
#pragma unroll
        for (int fn = 0; fn < 3; ++fn)
          acc[fm][fn] = __builtin_amdgcn_mfma_f32_16x16x32_bf16(
              af[fm], bfv[fn], acc[fm][fn], 0, 0, 0);
    }
    if (pref) {
      STAGE_WRITE_A(cur ^ 1);
    }
    __syncthreads();
    cur ^= 1;
  }
#undef ISSUE_B
#undef STAGE_LOAD_A
#undef STAGE_WRITE_A

  constexpr int EP = 100;
  float* epi = (float*)smem;
#pragma unroll
  for (int fm = 0; fm < 2; ++fm) {
    int rl = wr * 32 + fm * 16 + kgrp * 4;
#pragma unroll
    for (int fn = 0; fn < 3; ++fn) {
      int cl = wc * 48 + fn * 16 + l15;
#pragma unroll
      for (int j = 0; j < 4; ++j)
        epi[(rl + j) * EP + cl] = acc[fm][fn][j];
    }
  }
  __syncthreads();
#pragma unroll
  for (int it = 0; it < 6; ++it) {
    int f = it * 256 + tid;
    int r = f / 24, c4 = f - r * 24;
    float4 v = *(const float4*)&epi[r * EP + c4 * 4];
    int c = col0 + c4 * 4;
    if (BIAS) {
      float4 bv = *(const float4*)(bias + c);
      v.x += bv.x; v.y += bv.y; v.z += bv.z; v.w += bv.w;
    }
    if (EPI == 1) {
      v.x = gelu_f(v.x); v.y = gelu_f(v.y);
      v.z = gelu_f(v.z); v.w = gelu_f(v.w);
    }
    int R = row0 + r;
    if constexpr (EPI == 2) {
      int bt2 = R / Nn, n2 = R - bt2 * Nn;
      size_t off = (size_t)(bt2 * (Nn + 1) + 1 + n2) * Nc + c;
      float4 rv = *(const float4*)(resid + off);
      v.x += rv.x; v.y += rv.y; v.z += rv.z; v.w += rv.w;
      *(float4*)((float*)Cout + off) = v;
    } else if constexpr (sizeof(CT) == 4) {
      *(float4*)((float*)Cout + (size_t)R * Nc + c) = v;
    } else {
      u16x4 ob = {f2bf(v.x), f2bf(v.y), f2bf(v.z), f2bf(v.w)};
      *(u16x4*)((ushortt*)Cout + (size_t)R * Nc + c) = ob;
    }
  }
}

// ============================================================
// delta (bf16) + per-(b,t) |delta| partials
// ============================================================
__global__ void delta_kernel(const ushortt* __restrict__ ph,
                             ushortt* __restrict__ delta,
                             float* __restrict__ dppart) {
  int bt = blockIdx.x;
  int t = bt & 15;
  int a = threadIdx.x;
  const ushortt* cur = ph + (size_t)bt * Nn * Aa + a;
  ushortt* dl = delta + (size_t)bt * Nn * Aa + a;
  float acc = 0.f;
  if (t == 0) {
    for (int n = 0; n < Nn; ++n) dl[(size_t)n * Aa] = 0;
  } else {
    const ushortt* prev = cur - (size_t)Nn * Aa;
    for (int n = 0; n < Nn; ++n) {
      float d = bf2f(cur[(size_t)n * Aa]) - bf2f(prev[(size_t)n * Aa]);
      dl[(size_t)n * Aa] = f2bf(d);
      acc += fabsf(d);
    }
  }
  dppart[bt * Aa + a] = acc;
}

// sal[row] = mean_a |delta[row,a]| (fp32, candidate stage only)
__global__ void sal_kernel(const ushortt* __restrict__ delta,
                           float* __restrict__ sal) {
  int row = blockIdx.x * 4 + (threadIdx.x >> 6);
  int lane = threadIdx.x & 63;
  const ushortt* d = delta + (size_t)row * Aa;
  float s = fabsf(bf2f(d[lane])) + fabsf(bf2f(d[lane + 64])) +
            fabsf(bf2f(d[lane + 128]));
#pragma unroll
  for (int off = 32; off > 0; off >>= 1) s += __shfl_xor(s, off, 64);
  if (lane == 0) sal[row] = s * (1.0f / 192.0f);
}

// ============================================================
// top-16 fp32 candidates per (b,t); descending val, ties -> smaller n
// ============================================================
__global__ void topcand_kernel(const float* __restrict__ sal,
                               int* __restrict__ cand) {
  int bt = blockIdx.x;
  int lane = threadIdx.x;
  unsigned long long key[4];
#pragma unroll
  for (int j = 0; j < 4; ++j) {
    int n = lane + 64 * j;
    if (n < Nn) {
      unsigned fb = __float_as_uint(sal[(size_t)bt * Nn + n]);
      key[j] = ((unsigned long long)fb << 32) |
               (unsigned long long)(0xFFFFFFFFu - (unsigned)n);
    } else {
      key[j] = 0ULL;
    }
  }
  for (int r = 0; r < NCAND; ++r) {
    unsigned long long m = key[0];
    if (key[1] > m) m = key[1];
    if (key[2] > m) m = key[2];
    if (key[3] > m) m = key[3];
#pragma unroll
    for (int off = 32; off > 0; off >>= 1) {
      unsigned long long o = __shfl_xor(m, off, 64);
      if (o > m) m = o;
    }
    if (lane == 0)
      cand[bt * NCAND + r] = (int)(0xFFFFFFFFu - (unsigned)(m & 0xFFFFFFFFull));
#pragma unroll
    for (int j = 0; j < 4; ++j)
      if (key[j] == m) key[j] = 0ULL;
  }
}

// one-time transpose: wT[c][a] = down_w[a][c]
__global__ void transpose_w(const float* __restrict__ w,
                            float* __restrict__ wT) {
  int e = blockIdx.x * 256 + threadIdx.x;  // over Cc*Aa
  int c = e / Aa, a = e - c * Aa;
  wT[e] = w[(size_t)a * Cc + c];
}

// ============================================================
// f64 refine, 8 candidates per block (grid BT x 2, 192 thr).
// ============================================================
__global__ __launch_bounds__(192) void refine_kernel(
    const float* __restrict__ x, const float* __restrict__ wT,
    const int* __restrict__ cand, double* __restrict__ sal64) {
  int bt = blockIdx.x;
  int grp = blockIdx.y;
  int t = bt & 15;
  int a = threadIdx.x;
  if (t == 0) {
    if (a < 8) sal64[bt * NCAND + grp * 8 + a] = 0.0;
    return;
  }
  __shared__ double sdiff[8][Cc];  // 49 KB
  const float* xt = x + ((size_t)bt * (Nn + 1) + 1) * Cc;
  const float* xp = xt - (size_t)(Nn + 1) * Cc;
  for (int g = 0; g < 8; ++g) {
    int n = cand[bt * NCAND + grp * 8 + g];
    const float* rt = xt + (size_t)n * Cc;
    const float* rp = xp + (size_t)n * Cc;
    for (int c = a; c < Cc; c += 192)
      sdiff[g][c] = (double)rt[c] - (double)rp[c];
  }
  __syncthreads();
  double acc[8] = {};
  for (int c = 0; c < Cc; ++c) {
    double wv = (double)wT[(size_t)c * Aa + a];  // coalesced across lanes
#pragma unroll
    for (int g = 0; g < 8; ++g) acc[g] = fma(wv, sdiff[g][c], acc[g]);
  }
  __shared__ double part[3][8];
  int wvx = a >> 6, ln = a & 63;
#pragma unroll
  for (int g = 0; g < 8; ++g) {
    double v = fabs(acc[g]);
#pragma unroll
    for (int off = 32; off > 0; off >>= 1) v += __shfl_xor(v, off, 64);
    if (ln == 0) part[wvx][g] = v;
  }
  __syncthreads();
  if (a < 8) {
    double s = part[0][a] + part[1][a] + part[2][a];
    sal64[bt * NCAND + grp * 8 + a] = s * (1.0 / 192.0);
  }
}

// ============================================================
// final top-8 by (sal64 desc, n asc) — wave-parallel, in registers
// ============================================================
__global__ void select_kernel(const double* __restrict__ sal64,
                              const int* __restrict__ cand,
                              int* __restrict__ idx) {
  int bt = blockIdx.x;
  int t = bt & 15;
  int lane = threadIdx.x;  // 64
  if (t == 0) {
    if (lane < KK) idx[bt * KK + lane] = lane;
    return;
  }
  double v = (lane < NCAND) ? sal64[bt * NCAND + lane] : -1.0;
  int n = (lane < NCAND) ? cand[bt * NCAND + lane] : 0x7FFFFFFF;
  for (int r = 0; r < KK; ++r) {
    double bv = v;
    int bn = n, bl = lane;
#pragma unroll
    for (int off = 8; off >= 1; off >>= 1) {
      double ov = __shfl_xor(bv, off, 64);
      int on = __shfl_xor(bn, off, 64);
      int ol = __shfl_xor(bl, off, 64);
      if (ov > bv || (ov == bv && on < bn)) { bv = ov; bn = on; bl = ol; }
    }
    if (lane == 0) idx[bt * KK + r] = bn;
    if (lane == bl) v = -1.0;  // retire winner
  }
}

// ============================================================
// anchor attention: gather(bf16) -> GEMM qkv -> core -> GEMMs
// ============================================================
__global__ void gather_kernel(const ushortt* __restrict__ ph,
                              const ushortt* __restrict__ delta,
                              const int* __restrict__ idx,
                              ushortt* __restrict__ tok) {
  int row = blockIdx.x;  // (b*KK+k)*16+t
  int t = row & 15;
  int bk = row >> 4;
  int b = bk >> 3, k = bk & 7;
  int a = threadIdx.x;
  int n = idx[(b * 16 + t) * KK + k];
  size_t off = ((size_t)(b * 16 + t) * Nn + n) * Aa + a;
  tok[(size_t)row * Aa + a] = f2bf(bf2f(ph[off]) + bf2f(delta[off]));
}

__global__ __launch_bounds__(256) void attn_core(
    const float* __restrict__ qkv, float* __restrict__ o) {
  constexpr int P = 580;
  __shared__ float sq[16 * P];
  __shared__ float ssc[4][16][17];
  int bk = blockIdx.x;
  int tid = threadIdx.x;
  const float* src = qkv + (size_t)bk * 16 * 576;
  for (int e = tid; e < 16 * 144; e += 256) {
    int r = e / 144, c4 = e % 144;
    float4 v = *(const float4*)(src + r * 576 + c4 * 4);
    *(float4*)(&sq[r * P + c4 * 4]) = v;
  }
  __syncthreads();
  int h = tid >> 6, lane = tid & 63;
#pragma unroll
  for (int s4 = 0; s4 < 4; ++s4) {
    int e = lane + 64 * s4;
    int i = e >> 4, j = e & 15;
    const float* q = sq + i * P + h * 48;
    const float* k2 = sq + j * P + 192 + h * 48;
    float s = 0.f;
#pragma unroll
    for (int d = 0; d < 48; ++d) s = fmaf(q[d], k2[d], s);
    ssc[h][i][j] = s * 0.14433756729740643f;  // 1/sqrt(48)
  }
  __syncthreads();
  if (lane < 16) {
    float* r = ssc[h][lane];
    float mx = r[0];
    for (int j = 1; j < 16; ++j) mx = fmaxf(mx, r[j]);
    float sum = 0.f;
    for (int j = 0; j < 16; ++j) {
      float ev = expf(r[j] - mx);
      r[j] = ev;
      sum += ev;
    }
    float inv = 1.0f / sum;
    for (int j = 0; j < 16; ++j) r[j] *= inv;
  }
  __syncthreads();
#pragma unroll
  for (int s4 = 0; s4 < 12; ++s4) {
    int e = lane + 64 * s4;
    int i = e / 48, d = e - i * 48;
    float s = 0.f;
#pragma unroll
    for (int j = 0; j < 16; ++j)
      s = fmaf(ssc[h][i][j], sq[j * P + 384 + h * 48 + d], s);
    o[((size_t)bk * 16 + i) * 192 + h * 48 + d] = s;
  }
}

__global__ void appart_kernel(const float* __restrict__ attout,
                              float* __restrict__ appart) {
  int bk = blockIdx.x;
  int a = threadIdx.x;
  float s = 0.f;
  for (int t = 0; t < Tt; ++t)
    s += attout[((size_t)bk * Tt + t) * Aa + a];
  appart[bk * Aa + a] = s;
}

// in-place fp32 LayerNorm over last dim (192); one wave per row
__global__ void ln32_kernel(float* __restrict__ buf,
                            const float* __restrict__ g,
                            const float* __restrict__ bb) {
  size_t row = (size_t)blockIdx.x * 4 + (threadIdx.x >> 6);
  int lane = threadIdx.x & 63;
  float* p = buf + row * Aa;
  float v0 = p[lane], v1 = p[lane + 64], v2 = p[lane + 128];
  float s = v0 + v1 + v2;
#pragma unroll
  for (int off = 32; off > 0; off >>= 1) s += __shfl_xor(s, off, 64);
  float m = s * (1.0f / 192.0f);
  float d0 = v0 - m, d1 = v1 - m, d2 = v2 - m;
  float ss = d0 * d0 + d1 * d1 + d2 * d2;
#pragma unroll
  for (int off = 32; off > 0; off >>= 1) ss += __shfl_xor(ss, off, 64);
  float inv = rsqrtf(ss * (1.0f / 192.0f) + 1e-5f);
  p[lane] = d0 * inv * g[lane] + bb[lane];
  p[lane + 64] = d1 * inv * g[lane + 64] + bb[lane + 64];
  p[lane + 128] = d2 * inv * g[lane + 128] + bb[lane + 128];
}

// depthwise 3x3 SAME conv over 14x14 + gelu; bf16 in/out
__global__ void conv2d_kernel(const ushortt* __restrict__ ph,
                              const float* __restrict__ ldw,
                              ushortt* __restrict__ og) {
  size_t e = (size_t)blockIdx.x * 256 + threadIdx.x;
  int a = (int)(e % Aa);
  size_t r = e / Aa;
  int n = (int)(r % Nn);
  int bt = (int)(r / Nn);
  int y = n / 14, x = n % 14;
  const ushortt* base = ph + (size_t)bt * Nn * Aa + a;
  const float* w = ldw + a * 9;
  float s = 0.f;
#pragma unroll
  for (int dy = -1; dy <= 1; ++dy) {
    int yy = y + dy;
    if (yy < 0 || yy >= 14) continue;
#pragma unroll
    for (int dx = -1; dx <= 1; ++dx) {
      int xc = x + dx;
      if (xc < 0 || xc >= 14) continue;
      s = fmaf(bf2f(base[(size_t)(yy * 14 + xc) * Aa]),
               w[(dy + 1) * 3 + (dx + 1)], s);
    }
  }
  og[e] = f2bf(gelu_f(s));
}

// depthwise k=3 SAME conv over t + gelu; bf16 in/out
__global__ void conv1d_kernel(const ushortt* __restrict__ delta,
                              const float* __restrict__ tdw,
                              ushortt* __restrict__ og) {
  size_t e = (size_t)blockIdx.x * 256 + threadIdx.x;
  int a = (int)(e % Aa);
  size_t r = e / Aa;
  int n = (int)(r % Nn);
  int bt = (int)(r / Nn);
  int t = bt & 15, b = bt >> 4;
  const float* w = tdw + a * 3;
  float s = 0.f;
#pragma unroll
  for (int j = 0; j < 3; ++j) {
    int tt = t + j - 1;
    if (tt >= 0 && tt < Tt)
      s = fmaf(bf2f(delta[((size_t)(b * Tt + tt) * Nn + n) * Aa + a]), w[j], s);
  }
  og[e] = f2bf(gelu_f(s));
}

// in-place LayerNorm over last dim (192); one wave per row (bf16)
__global__ void ln_kernel(ushortt* __restrict__ buf,
                          const float* __restrict__ g,
                          const float* __restrict__ bb) {
  size_t row = (size_t)blockIdx.x * 4 + (threadIdx.x >> 6);
  int lane = threadIdx.x & 63;
  ushortt* p = buf + row * Aa;
  float v0 = bf2f(p[lane]), v1 = bf2f(p[lane + 64]), v2 = bf2f(p[lane + 128]);
  float s = v0 + v1 + v2;
#pragma unroll
  for (int off = 32; off > 0; off >>= 1) s += __shfl_xor(s, off, 64);
  float m = s * (1.0f / 192.0f);
  float d0 = v0 - m, d1 = v1 - m, d2 = v2 - m;
  float ss = d0 * d0 + d1 * d1 + d2 * d2;
#pragma unroll
  for (int off = 32; off > 0; off >>= 1) ss += __shfl_xor(ss, off, 64);
  float inv = rsqrtf(ss * (1.0f / 192.0f) + 1e-5f);
  p[lane] = f2bf(d0 * inv * g[lane] + bb[lane]);
  p[lane + 64] = f2bf(d1 * inv * g[lane + 64] + bb[lane + 64]);
  p[lane + 128] = f2bf(d2 * inv * g[lane + 128] + bb[lane + 128]);
}

// posmap[bt*Nn + idx[bt,k]] = k+1 (posmap pre-zeroed)
__global__ void scatter_pos(const int* __restrict__ idx,
                            short* __restrict__ posmap) {
  int bt = blockIdx.x;
  int k = threadIdx.x;
  if (k < KK) posmap[bt * Nn + idx[bt * KK + k]] = (short)(k + 1);
}

// gate MLP + 3-way softmax; one block per b, 192 threads
__global__ void gate_kernel(const float* __restrict__ dppart,
                            const float* __restrict__ appart,
                            const float* __restrict__ w1,
                            const float* __restrict__ b1,
                            const float* __restrict__ w2,
                            const float* __restrict__ b2,
                            float* __restrict__ gw) {
  int b = blockIdx.x;
  __shared__ float sg[2 * Aa];
  __shared__ float sh[Aa];
  int tid = threadIdx.x;
  {
    float d = 0.f;
    for (int t2 = 0; t2 < Tt; ++t2) d += dppart[(b * Tt + t2) * Aa + tid];
    sg[tid] = d * (1.0f / 3136.0f);
    float a = 0.f;
    for (int k2 = 0; k2 < KK; ++k2) a += appart[(b * KK + k2) * Aa + tid];
    sg[Aa + tid] = a * (1.0f / 128.0f);
  }
  __syncthreads();
  {
    const float* w = w1 + (size_t)tid * 2 * Aa;
    float s = b1[tid];
#pragma unroll 8
    for (int j = 0; j < 2 * Aa; ++j) s = fmaf(sg[j], w[j], s);
    sh[tid] = gelu_f(s);
  }
  __syncthreads();
  float v[3];
#pragma unroll
  for (int i = 0; i < 3; ++i) {
    const float* w = w2 + (size_t)(i * Aa + tid) * Aa;
    float s = b2[i * Aa + tid];
#pragma unroll 8
    for (int j = 0; j < Aa; ++j) s = fmaf(sh[j], w[j], s);
    v[i] = s;
  }
  float mx = fmaxf(v[0], fmaxf(v[1], v[2]));
  float e0 = expf(v[0] - mx), e1 = expf(v[1] - mx), e2 = expf(v[2] - mx);
  float inv = 1.0f / (e0 + e1 + e2);
  gw[(b * 3 + 0) * Aa + tid] = e0 * inv;
  gw[(b * 3 + 1) * Aa + tid] = e1 * inv;
  gw[(b * 3 + 2) * Aa + tid] = e2 * inv;
}

// fused = gw0*local + gw1*trans + gw2*amap_ln; fmean fp32
__global__ void fused_kernel(const ushortt* __restrict__ local,
                             const ushortt* __restrict__ trans,
                             const float* __restrict__ attln,
                             const short* __restrict__ posmap,
                             const float* __restrict__ anb,
                             const float* __restrict__ gw,
                             ushortt* __restrict__ fused,
                             float* __restrict__ fmean) {
  int bt = blockIdx.x;
  int b = bt >> 4, t = bt & 15;
  int a = threadIdx.x;
  float g0 = gw[(b * 3 + 0) * Aa + a];
  float g1 = gw[(b * 3 + 1) * Aa + a];
  float g2 = gw[(b * 3 + 2) * Aa + a];
  float ab = anb[a];
  size_t base = (size_t)bt * Nn * Aa + a;
  float acc = 0.f;
  for (int n = 0; n < Nn; ++n) {
    size_t o = base + (size_t)n * Aa;
    short pos = posmap[bt * Nn + n];
    float am = pos ? attln[(((size_t)(b * KK + pos - 1) * Tt) + t) * Aa + a]
                   : ab;
    float f = g0 * bf2f(local[o]) + g1 * bf2f(trans[o]) + g2 * am;
    fused[o] = f2bf(f);
    acc += f;
  }
  fmean[bt * Aa + a] = acc;
}

// cls_out = cls_tok + (mean_n fused) @ cls_w.T + cls_b
__global__ void cls_kernel(const float* __restrict__ fmean,
                           const float* __restrict__ cw,
                           const float* __restrict__ cb,
                           const float* __restrict__ x,
                           float* __restrict__ out) {
  int bt = blockIdx.x;
  __shared__ float fm[Aa];
  int tid = threadIdx.x;
  if (tid < Aa) fm[tid] = fmean[bt * Aa + tid] * (1.0f / 196.0f);
  __syncthreads();
  for (int c = tid; c < Cc; c += 256) {
    const float* w = cw + (size_t)c * Aa;
    float s = cb[c];
#pragma unroll 8
    for (int a = 0; a < Aa; ++a) s = fmaf(fm[a], w[a], s);
    size_t off = (size_t)bt * (Nn + 1) * Cc + c;
    out[off] = x[off] + s;
  }
}

// ============================================================
extern "C" void kernel_launch(void* const* d_in, const int* in_sizes, int n_in,
                              void* d_out, int out_size, void* d_ws,
                              size_t ws_size, hipStream_t stream) {
  const float* x = (const float*)d_in[0];
  const float* down_w = (const float*)d_in[1];
  const float* down_b = (const float*)d_in[2];
  const float* ldw_w = (const float*)d_in[3];
  const float* lpw_w = (const float*)d_in[4];
  const float* lnorm_g = (const float*)d_in[5];
  const float* lnorm_b = (const float*)d_in[6];
  const float* tdw_w = (const float*)d_in[7];
  const float* tpw_w = (const float*)d_in[8];
  const float* tmlp_w1 = (const float*)d_in[9];
  const float* tmlp_b1 = (const float*)d_in[10];
  const float* tmlp_w2 = (const float*)d_in[11];
  const float* tmlp_b2 = (const float*)d_in[12];
  const float* tnorm_g = (const float*)d_in[13];
  const float* tnorm_b = (const float*)d_in[14];
  const float* attn_in_w = (const float*)d_in[15];
  const float* attn_in_b = (const float*)d_in[16];
  const float* attn_out_w = (const float*)d_in[17];
  const float* attn_out_b = (const float*)d_in[18];
  const float* aproj_w = (const float*)d_in[19];
  const float* aproj_b = (const float*)d_in[20];
  const float* anorm_g = (const float*)d_in[21];
  const float* anorm_b = (const float*)d_in[22];
  const float* gate_w1 = (const float*)d_in[23];
  const float* gate_b1 = (const float*)d_in[24];
  const float* gate_w2 = (const float*)d_in[25];
  const float* gate_b2 = (const float*)d_in[26];
  const float* up_w = (const float*)d_in[27];
  const float* up_b = (const float*)d_in[28];
  const float* cls_w = (const float*)d_in[29];
  const float* cls_b = (const float*)d_in[30];
  float* out = (float*)d_out;

  float* ws = (float*)d_ws;
  float* W0 = ws;              // ph bf16 -> trp bf16
  float* W1 = W0 + SZ;         // delta bf16 -> transition bf16
  float* W2 = W1 + SZ;         // attn scratch -> locg/trg/h1/fused bf16
  float* W3 = W2 + 2 * SZ;     // local bf16
  float* sal = W3 + SZ;
  float* attout = sal + BTN;
  float* dppart = attout + (size_t)BKT * Aa;
  float* appart = dppart + (size_t)BT * Aa;
  float* gw = appart + (size_t)Bb * KK * Aa;
  float* fmean = gw + (size_t)Bb * 3 * Aa;
  double* sal64 = (double*)(fmean + (size_t)BT * Aa);  // BT*NCAND doubles
  int* cand = (int*)(sal64 + (size_t)BT * NCAND);      // BT*NCAND ints
  int* idx = cand + (size_t)BT * NCAND;                // BT*KK ints
  float* wT = (float*)(idx + (size_t)BT * KK);         // Cc*Aa floats
  short* posmap = (short*)(wT + (size_t)Cc * Aa);      // BT*Nn shorts
  ushortt* wbuf = (ushortt*)(posmap + (size_t)BT * Nn);  // OTOT bf16

  // bf16 weight views
  ushortt* wb_down   = wbuf;
  ushortt* wb_attnin = wbuf + O1;
  ushortt* wb_attnout= wbuf + O2;
  ushortt* wb_aproj  = wbuf + O3;
  ushortt* wb_lpw    = wbuf + O4;
  ushortt* wb_tpw    = wbuf + O5;
  ushortt* wb_t1     = wbuf + O6;
  ushortt* wb_t2     = wbuf + O7;
  ushortt* wb_up     = wbuf + O8;

  // bf16 activation views
  ushortt* ph_b    = (ushortt*)W0;
  ushortt* trp_b   = (ushortt*)W0;
  ushortt* delta_b = (ushortt*)W1;
  ushortt* trans_b = (ushortt*)W1;
  ushortt* locg_b  = (ushortt*)W2;
  ushortt* trg_b   = (ushortt*)W2;
  ushortt* h1_b    = (ushortt*)W2;
  ushortt* fused_b = (ushortt*)W2;
  ushortt* local_b = (ushortt*)W3;

  // attn-phase scratch inside W2 (dead until conv2d)
  ushortt* tok_b = (ushortt*)W2;                       // 2048*192 bf16
  float* qkvb  = W2 + (size_t)BKT * Aa / 2;            // 2048*576 f32
  float* obuf  = qkvb + (size_t)BKT * 3 * Aa;          // 2048*192 f32
  float* proj1 = obuf + (size_t)BKT * Aa;              // 2048*192 f32

  // 0. weights -> bf16 (one pass), wT for refine
  cvtw_kernel<<<OTOT / 256, 256, 0, stream>>>(
      down_w, attn_in_w, attn_out_w, aproj_w, lpw_w, tpw_w, tmlp_w1,
      tmlp_w2, up_w, wbuf);
  transpose_w<<<(Cc * Aa) / 256, 256, 0, stream>>>(down_w, wT);
  // 1. ph = patch @ down_w.T + down_b (bf16 out) [hybrid: B via gload]
  gemm_hyb<1, ushortt, 1, 0><<<dim3(2, 784), 256, 0, stream>>>(
      x, wb_down, down_b, ph_b, nullptr, BTN, Aa, Cc);
  // 2. delta + dp partials
  delta_kernel<<<BT, Aa, 0, stream>>>(ph_b, delta_b, dppart);
  // 3. saliency: fp32 candidates -> f64 refine -> exact top-8
  sal_kernel<<<BTN / 4, 256, 0, stream>>>(delta_b, sal);
  topcand_kernel<<<BT, 64, 0, stream>>>(sal, cand);
  refine_kernel<<<dim3(BT, 2), 192, 0, stream>>>(x, wT, cand, sal64);
  select_kernel<<<BT, 64, 0, stream>>>(sal64, cand, idx);
  // 4. anchor attention
  gather_kernel<<<BKT, Aa, 0, stream>>>(ph_b, delta_b, idx, tok_b);
  gemm_lds<float, 1, 0><<<dim3(6, 32), 256, 0, stream>>>(
      tok_b, wb_attnin, attn_in_b, qkvb, nullptr, BKT, 3 * Aa, Aa);
  attn_core<<<Bb * KK, 256, 0, stream>>>(qkvb, obuf);
  gemm_hyb<0, float, 1, 0><<<dim3(2, 32), 256, 0, stream>>>(
      obuf, wb_attnout, attn_out_b, proj1, nullptr, BKT, Aa, Aa);
  gemm_hyb<0, float, 1, 0><<<dim3(2, 32), 256, 0, stream>>>(
      proj1, wb_aproj, aproj_b, attout, nullptr, BKT, Aa, Aa);
  appart_kernel<<<Bb * KK, Aa, 0, stream>>>(attout, appart);
  // 4b. LN the 2048 anchor rows in place
  ln32_kernel<<<BKT / 4, 256, 0, stream>>>(attout, anorm_g, anorm_b);
  hipMemsetAsync(posmap, 0, (size_t)BT * Nn * sizeof(short), stream);
  scatter_pos<<<BT, 64, 0, stream>>>(idx, posmap);
  // 5. local branch
  conv2d_kernel<<<(unsigned)(SZ / 256), 256, 0, stream>>>(ph_b, ldw_w, locg_b);
  gemm_lds<ushortt, 0, 0><<<dim3(2, 784), 256, 0, stream>>>(
      locg_b, wb_lpw, nullptr, local_b, nullptr, BTN, Aa, Aa);
  ln_kernel<<<BTN / 4, 256, 0, stream>>>(local_b, lnorm_g, lnorm_b);
  // 6. transition branch
  conv1d_kernel<<<(unsigned)(SZ / 256), 256, 0, stream>>>(delta_b, tdw_w, trg_b);
  gemm_lds<ushortt, 0, 0><<<dim3(2, 784), 256, 0, stream>>>(
      trg_b, wb_tpw, nullptr, trp_b, nullptr, BTN, Aa, Aa);
  gemm_lds<ushortt, 1, 1><<<dim3(4, 784), 256, 0, stream>>>(
      trp_b, wb_t1, tmlp_b1, h1_b, nullptr, BTN, 2 * Aa, Aa);
  gemm_lds<ushortt, 1, 0><<<dim3(2, 784), 256, 0, stream>>>(
      h1_b, wb_t2, tmlp_b2, trans_b, nullptr, BTN, Aa, 2 * Aa);
  ln_kernel<<<BTN / 4, 256, 0, stream>>>(trans_b, tnorm_g, tnorm_b);
  // 8. gate
  gate_kernel<<<Bb, Aa, 0, stream>>>(dppart, appart, gate_w1, gate_b1,
                                     gate_w2, gate_b2, gw);
  // 9. fuse + output projections
  fused_kernel<<<BT, Aa, 0, stream>>>(local_b, trans_b, attout, posmap,
                                      anorm_b, gw, fused_b, fmean);
  gemm_lds<float, 1, 2><<<dim3(8, 784), 256, 0, stream>>>(
      fused_b, wb_up, up_b, out, x, BTN, Cc, Aa);
  cls_kernel<<<BT, 256, 0, stream>>>(fmean, cls_w, cls_b, x, out);
}

// Round 17
// 524.791 us; speedup vs baseline: 2.1118x; 1.0982x over previous
//
#include <hip/hip_runtime.h>
#include <hip/hip_bf16.h>
#include <math.h>

// ---- fixed problem dims ----
constexpr int Bb  = 16;
constexpr int Tt  = 16;
constexpr int Nn  = 196;   // patches (14x14)
constexpr int Cc  = 768;
constexpr int Aa  = 192;
constexpr int KK  = 8;     // TOPK
constexpr int NCAND = 16;  // fp32 candidates refined in f64
constexpr int NCH = 14;    // n-chunks for delta/fused parallelism
constexpr int BT  = Bb * Tt;            // 256
constexpr int BTN = BT * Nn;            // 50176
constexpr int BKT = Bb * KK * Tt;       // 2048 anchor-token rows
constexpr size_t SZ = (size_t)BTN * Aa; // 9,633,792 floats

typedef unsigned short ushortt;
typedef __attribute__((ext_vector_type(8))) short bf16x8;
typedef __attribute__((ext_vector_type(4))) float f32x4;
typedef __attribute__((ext_vector_type(4))) unsigned short u16x4;
typedef __attribute__((ext_vector_type(8))) unsigned short u16x8;

static __device__ __forceinline__ float gelu_f(float x) {
  return 0.5f * x * (1.0f + erff(x * 0.7071067811865476f));
}
static __device__ __forceinline__ ushortt f2bf(float f) {
  __hip_bfloat16 h = __float2bfloat16(f);
  return *reinterpret_cast<ushortt*>(&h);
}
static __device__ __forceinline__ float bf2f(ushortt u) {
  return __uint_as_float(((unsigned)u) << 16);
}
static __device__ __forceinline__ void gload16(const void* g, void* l) {
  __builtin_amdgcn_global_load_lds(
      (const __attribute__((address_space(1))) void*)g,
      (__attribute__((address_space(3))) void*)l, 16, 0, 0);
}

// ---- weight pre-convert offsets ----
constexpr int S_down   = Aa * Cc;
constexpr int S_attnin = 3 * Aa * Aa;
constexpr int S_sq     = Aa * Aa;
constexpr int S_t      = 2 * Aa * Aa;
constexpr int O1 = S_down;
constexpr int O2 = O1 + S_attnin;
constexpr int O3 = O2 + S_sq;
constexpr int O4 = O3 + S_sq;
constexpr int O5 = O4 + S_sq;
constexpr int O6 = O5 + S_sq;
constexpr int O7 = O6 + S_t;
constexpr int O8 = O7 + S_t;
constexpr int OTOT = O8 + S_down;  // 700416

__global__ void cvtw_kernel(const float* __restrict__ w0,
                            const float* __restrict__ w1,
                            const float* __restrict__ w2,
                            const float* __restrict__ w3,
                            const float* __restrict__ w4,
                            const float* __restrict__ w5,
                            const float* __restrict__ w6,
                            const float* __restrict__ w7,
                            const float* __restrict__ w8,
                            ushortt* __restrict__ outw) {
  int e = blockIdx.x * 256 + threadIdx.x;
  const float* src;
  int off;
  if (e < O1)      { src = w0; off = 0;  }
  else if (e < O2) { src = w1; off = O1; }
  else if (e < O3) { src = w2; off = O2; }
  else if (e < O4) { src = w3; off = O3; }
  else if (e < O5) { src = w4; off = O4; }
  else if (e < O6) { src = w5; off = O5; }
  else if (e < O7) { src = w6; off = O6; }
  else if (e < O8) { src = w7; off = O7; }
  else             { src = w8; off = O8; }
  outw[e] = f2bf(src[e - off]);
}

// ============================================================
// gemm_lds (r15): bf16 A & W via global_load_lds, XOR swizzle.
// ============================================================
template <typename CT, int BIAS, int EPI>
__global__ __launch_bounds__(256) void gemm_lds(
    const ushortt* __restrict__ Ain, const ushortt* __restrict__ Wb,
    const float* __restrict__ bias, CT* __restrict__ Cout,
    const float* __restrict__ resid, int M, int Nc, int K) {
  __shared__ __align__(16) unsigned char smem[40960];
  ushortt (*As)[64 * 64] = (ushortt(*)[64 * 64])smem;
  ushortt (*Bs)[96 * 64] = (ushortt(*)[96 * 64])(smem + 2 * 64 * 64 * 2);
  const int tid = threadIdx.x;

  const int ncb = gridDim.x;
  const int nwg = ncb * gridDim.y;
  const int bid = blockIdx.y * ncb + blockIdx.x;
  const int cpx = nwg >> 3;
  const int swz = (bid & 7) * cpx + (bid >> 3);
  const int row0 = (swz / ncb) * 64;
  const int col0 = (swz % ncb) * 96;

  const int wid = tid >> 6;
  const int lane = tid & 63;
  const int wr = wid >> 1;
  const int wc = wid & 1;
  const int l15 = lane & 15;
  const int kgrp = lane >> 4;

  const int lr = lane >> 3;
  const int lc = 8 * ((lane & 7) ^ lr);

  f32x4 acc[2][3];
#pragma unroll
  for (int i = 0; i < 2; ++i)
#pragma unroll
    for (int j = 0; j < 3; ++j) acc[i][j] = (f32x4){0.f, 0.f, 0.f, 0.f};

#define ISSUE(buf, k0)                                                       \
  do {                                                                       \
    _Pragma("unroll") for (int i = 0; i < 2; ++i) {                          \
      int j = 2 * wid + i;                                                   \
      const ushortt* g =                                                     \
          Ain + (size_t)(row0 + 8 * j + lr) * K + (k0) + lc;                 \
      gload16(g, &As[buf][j * 512]);                                         \
    }                                                                        \
    _Pragma("unroll") for (int i = 0; i < 3; ++i) {                          \
      int j = 3 * wid + i;                                                   \
      const ushortt* g =                                                     \
          Wb + (size_t)(col0 + 8 * j + lr) * K + (k0) + lc;                  \
      gload16(g, &Bs[buf][j * 512]);                                         \
    }                                                                        \
  } while (0)

  ISSUE(0, 0);
  __syncthreads();

  const int nsteps = K >> 6;
  int cur = 0;
  for (int step = 0; step < nsteps; ++step) {
    const bool pref = (step + 1 < nsteps);
    if (pref) ISSUE(cur ^ 1, (step + 1) << 6);
#pragma unroll
    for (int kk = 0; kk < 2; ++kk) {
      const int cb = kk * 64 + kgrp * 16;
      bf16x8 af[2], bfv[3];
#pragma unroll
      for (int fm = 0; fm < 2; ++fm) {
        int r = wr * 32 + fm * 16 + l15;
        af[fm] = *(const bf16x8*)&As[cur][r * 64 +
                                          ((cb ^ ((r & 7) << 4)) >> 1)];
      }
#pragma unroll
      for (int fn = 0; fn < 3; ++fn) {
        int r = wc * 48 + fn * 16 + l15;
        bfv[fn] = *(const bf16x8*)&Bs[cur][r * 64 +
                                           ((cb ^ ((r & 7) << 4)) >> 1)];
      }
#pragma unroll
      for (int fm = 0; fm < 2; ++fm)
#pragma unroll
        for (int fn = 0; fn < 3; ++fn)
          acc[fm][fn] = __builtin_amdgcn_mfma_f32_16x16x32_bf16(
              af[fm], bfv[fn], acc[fm][fn], 0, 0, 0);
    }
    __syncthreads();
    cur ^= 1;
  }
#undef ISSUE

  constexpr int EP = 100;
  float* epi = (float*)smem;
#pragma unroll
  for (int fm = 0; fm < 2; ++fm) {
    int rl = wr * 32 + fm * 16 + kgrp * 4;
#pragma unroll
    for (int fn = 0; fn < 3; ++fn) {
      int cl = wc * 48 + fn * 16 + l15;
#pragma unroll
      for (int j = 0; j < 4; ++j)
        epi[(rl + j) * EP + cl] = acc[fm][fn][j];
    }
  }
  __syncthreads();
#pragma unroll
  for (int it = 0; it < 6; ++it) {
    int f = it * 256 + tid;
    int r = f / 24, c4 = f - r * 24;
    float4 v = *(const float4*)&epi[r * EP + c4 * 4];
    int c = col0 + c4 * 4;
    if (BIAS) {
      float4 bv = *(const float4*)(bias + c);
      v.x += bv.x; v.y += bv.y; v.z += bv.z; v.w += bv.w;
    }
    if (EPI == 1) {
      v.x = gelu_f(v.x); v.y = gelu_f(v.y);
      v.z = gelu_f(v.z); v.w = gelu_f(v.w);
    }
    int R = row0 + r;
    if constexpr (EPI == 2) {
      int bt2 = R / Nn, n2 = R - bt2 * Nn;
      size_t off = (size_t)(bt2 * (Nn + 1) + 1 + n2) * Nc + c;
      float4 rv = *(const float4*)(resid + off);
      v.x += rv.x; v.y += rv.y; v.z += rv.z; v.w += rv.w;
      *(float4*)((float*)Cout + off) = v;
    } else if constexpr (sizeof(CT) == 4) {
      *(float4*)((float*)Cout + (size_t)R * Nc + c) = v;
    } else {
      u16x4 ob = {f2bf(v.x), f2bf(v.y), f2bf(v.z), f2bf(v.w)};
      *(u16x4*)((ushortt*)Cout + (size_t)R * Nc + c) = ob;
    }
  }
}

// ============================================================
// gemm_hyb (r16): fp32 A reg-staged (pitched), bf16 W via gload.
// ============================================================
template <int ROWMAP, typename CT, int BIAS, int EPI>
__global__ __launch_bounds__(256) void gemm_hyb(
    const float* __restrict__ Ain, const ushortt* __restrict__ Wb,
    const float* __restrict__ bias, CT* __restrict__ Cout,
    const float* __restrict__ resid, int M, int Nc, int K) {
  constexpr int PIT = 72;
  __shared__ __align__(16) unsigned char smem[43008];
  ushortt (*As)[64 * PIT] = (ushortt(*)[64 * PIT])smem;
  ushortt (*Bs)[96 * 64] = (ushortt(*)[96 * 64])(smem + 18432);
  const int tid = threadIdx.x;

  const int ncb = gridDim.x;
  const int nwg = ncb * gridDim.y;
  const int bid = blockIdx.y * ncb + blockIdx.x;
  const int cpx = nwg >> 3;
  const int swz = (bid & 7) * cpx + (bid >> 3);
  const int row0 = (swz / ncb) * 64;
  const int col0 = (swz % ncb) * 96;

  const int wid = tid >> 6;
  const int lane = tid & 63;
  const int wr = wid >> 1;
  const int wc = wid & 1;
  const int l15 = lane & 15;
  const int kgrp = lane >> 4;

  const int q16 = tid & 15;
  const int lr = lane >> 3;
  const int lc = 8 * ((lane & 7) ^ lr);

  const int nsteps = K >> 6;

  const float* arowf[4];
#pragma unroll
  for (int p = 0; p < 4; ++p) {
    int r = row0 + (tid >> 4) + 16 * p;
    if (ROWMAP) {
      int bt = r / Nn;
      int n = r - bt * Nn;
      arowf[p] = Ain + (size_t)(bt * (Nn + 1) + 1 + n) * K;
    } else {
      arowf[p] = Ain + (size_t)r * K;
    }
  }

  f32x4 acc[2][3];
#pragma unroll
  for (int i = 0; i < 2; ++i)
#pragma unroll
    for (int j = 0; j < 3; ++j) acc[i][j] = (f32x4){0.f, 0.f, 0.f, 0.f};

  float4 apre[4];

#define ISSUE_B(buf, k0)                                                     \
  do {                                                                       \
    _Pragma("unroll") for (int i = 0; i < 3; ++i) {                          \
      int j = 3 * wid + i;                                                   \
      const ushortt* g =                                                     \
          Wb + (size_t)(col0 + 8 * j + lr) * K + (k0) + lc;                  \
      gload16(g, &Bs[buf][j * 512]);                                         \
    }                                                                        \
  } while (0)

#define STAGE_LOAD_A(k0)                                                     \
  _Pragma("unroll") for (int p = 0; p < 4; ++p)                              \
      apre[p] = *(const float4*)(arowf[p] + (k0) + q16 * 4);

#define STAGE_WRITE_A(buf)                                                   \
  _Pragma("unroll") for (int p = 0; p < 4; ++p) {                            \
    u16x4 b = {f2bf(apre[p].x), f2bf(apre[p].y), f2bf(apre[p].z),            \
               f2bf(apre[p].w)};                                             \
    *(u16x4*)&As[buf][((tid >> 4) + 16 * p) * PIT + q16 * 4] = b;            \
  }

  ISSUE_B(0, 0);
  STAGE_LOAD_A(0);
  STAGE_WRITE_A(0);
  __syncthreads();

  int cur = 0;
  for (int step = 0; step < nsteps; ++step) {
    const bool pref = (step + 1 < nsteps);
    if (pref) {
      int k0 = (step + 1) << 6;
      ISSUE_B(cur ^ 1, k0);
      STAGE_LOAD_A(k0);
    }
#pragma unroll
    for (int kk = 0; kk < 2; ++kk) {
      const int cb = kk * 64 + kgrp * 16;
      bf16x8 af[2], bfv[3];
#pragma unroll
      for (int fm = 0; fm < 2; ++fm)
        af[fm] = *(const bf16x8*)&As[cur][(wr * 32 + fm * 16 + l15) * PIT +
                                          kk * 32 + kgrp * 8];
#pragma unroll
      for (int fn = 0; fn < 3; ++fn) {
        int r = wc * 48 + fn * 16 + l15;
        bfv[fn] = *(const bf16x8*)&Bs[cur][r * 64 +
                                           ((cb ^ ((r & 7) << 4)) >> 1)];
      }
#pragma unroll
      for (int fm = 0; fm < 2; ++fm)
#pragma unroll
        for (int fn = 0; fn < 3; ++fn)
          acc[fm][fn] = __builtin_amdgcn_mfma_f32_16x16x32_bf16(
              af[fm], bfv[fn], acc[fm][fn], 0, 0, 0);
    }
    if (pref) {
      STAGE_WRITE_A(cur ^ 1);
    }
    __syncthreads();
    cur ^= 1;
  }
#undef ISSUE_B
#undef STAGE_LOAD_A
#undef STAGE_WRITE_A

  constexpr int EP = 100;
  float* epi = (float*)smem;
#pragma unroll
  for (int fm = 0; fm < 2; ++fm) {
    int rl = wr * 32 + fm * 16 + kgrp * 4;
#pragma unroll
    for (int fn = 0; fn < 3; ++fn) {
      int cl = wc * 48 + fn * 16 + l15;
#pragma unroll
      for (int j = 0; j < 4; ++j)
        epi[(rl + j) * EP + cl] = acc[fm][fn][j];
    }
  }
  __syncthreads();
#pragma unroll
  for (int it = 0; it < 6; ++it) {
    int f = it * 256 + tid;
    int r = f / 24, c4 = f - r * 24;
    float4 v = *(const float4*)&epi[r * EP + c4 * 4];
    int c = col0 + c4 * 4;
    if (BIAS) {
      float4 bv = *(const float4*)(bias + c);
      v.x += bv.x; v.y += bv.y; v.z += bv.z; v.w += bv.w;
    }
    if (EPI == 1) {
      v.x = gelu_f(v.x); v.y = gelu_f(v.y);
      v.z = gelu_f(v.z); v.w = gelu_f(v.w);
    }
    int R = row0 + r;
    if constexpr (EPI == 2) {
      int bt2 = R / Nn, n2 = R - bt2 * Nn;
      size_t off = (size_t)(bt2 * (Nn + 1) + 1 + n2) * Nc + c;
      float4 rv = *(const float4*)(resid + off);
      v.x += rv.x; v.y += rv.y; v.z += rv.z; v.w += rv.w;
      *(float4*)((float*)Cout + off) = v;
    } else if constexpr (sizeof(CT) == 4) {
      *(float4*)((float*)Cout + (size_t)R * Nc + c) = v;
    } else {
      u16x4 ob = {f2bf(v.x), f2bf(v.y), f2bf(v.z), f2bf(v.w)};
      *(u16x4*)((ushortt*)Cout + (size_t)R * Nc + c) = ob;
    }
  }
}

// ============================================================
// delta14 (r17): grid BT*NCH; 14 rows per block, 192 thr.
// Writes delta, dppart2 partials, AND per-row sal (fused).
// ============================================================
__global__ __launch_bounds__(192) void delta14_kernel(
    const ushortt* __restrict__ ph, ushortt* __restrict__ delta,
    float* __restrict__ dppart2, float* __restrict__ sal) {
  int blk = blockIdx.x;
  int bt = blk / NCH, chunk = blk - bt * NCH;
  int t = bt & 15;
  int a = threadIdx.x;
  int n0 = chunk * 14;
  __shared__ float spart[3][14];
  const ushortt* cur = ph + ((size_t)bt * Nn + n0) * Aa + a;
  ushortt* dl = delta + ((size_t)bt * Nn + n0) * Aa + a;
  int wv = a >> 6, ln = a & 63;
  float acc = 0.f;
  if (t == 0) {
    for (int i = 0; i < 14; ++i) dl[(size_t)i * Aa] = 0;
    if (a < 14) sal[(size_t)bt * Nn + n0 + a] = 0.f;
    if (a == 0)
      for (int q = 0; q < Aa; ++q) ;  // no-op
    dppart2[(size_t)blk * Aa + a] = 0.f;
    return;
  }
  const ushortt* prev = cur - (size_t)Nn * Aa;
  for (int i = 0; i < 14; ++i) {
    float d = bf2f(cur[(size_t)i * Aa]) - bf2f(prev[(size_t)i * Aa]);
    dl[(size_t)i * Aa] = f2bf(d);
    float ad = fabsf(d);
    acc += ad;
    float s = ad;
#pragma unroll
    for (int off = 32; off > 0; off >>= 1) s += __shfl_xor(s, off, 64);
    if (ln == 0) spart[wv][i] = s;
  }
  dppart2[(size_t)blk * Aa + a] = acc;
  __syncthreads();
  if (a < 14)
    sal[(size_t)bt * Nn + n0 + a] =
        (spart[0][a] + spart[1][a] + spart[2][a]) * (1.0f / 192.0f);
}

// ============================================================
// top-16 fp32 candidates per (b,t)
// ============================================================
__global__ void topcand_kernel(const float* __restrict__ sal,
                               int* __restrict__ cand) {
  int bt = blockIdx.x;
  int lane = threadIdx.x;
  unsigned long long key[4];
#pragma unroll
  for (int j = 0; j < 4; ++j) {
    int n = lane + 64 * j;
    if (n < Nn) {
      unsigned fb = __float_as_uint(sal[(size_t)bt * Nn + n]);
      key[j] = ((unsigned long long)fb << 32) |
               (unsigned long long)(0xFFFFFFFFu - (unsigned)n);
    } else {
      key[j] = 0ULL;
    }
  }
  for (int r = 0; r < NCAND; ++r) {
    unsigned long long m = key[0];
    if (key[1] > m) m = key[1];
    if (key[2] > m) m = key[2];
    if (key[3] > m) m = key[3];
#pragma unroll
    for (int off = 32; off > 0; off >>= 1) {
      unsigned long long o = __shfl_xor(m, off, 64);
      if (o > m) m = o;
    }
    if (lane == 0)
      cand[bt * NCAND + r] = (int)(0xFFFFFFFFu - (unsigned)(m & 0xFFFFFFFFull));
#pragma unroll
    for (int j = 0; j < 4; ++j)
      if (key[j] == m) key[j] = 0ULL;
  }
}

// one-time transpose: wT[c][a] = down_w[a][c]
__global__ void transpose_w(const float* __restrict__ w,
                            float* __restrict__ wT) {
  int e = blockIdx.x * 256 + threadIdx.x;
  int c = e / Aa, a = e - c * Aa;
  wT[e] = w[(size_t)a * Cc + c];
}

// ============================================================
// f64 refine (r7)
// ============================================================
__global__ __launch_bounds__(192) void refine_kernel(
    const float* __restrict__ x, const float* __restrict__ wT,
    const int* __restrict__ cand, double* __restrict__ sal64) {
  int bt = blockIdx.x;
  int grp = blockIdx.y;
  int t = bt & 15;
  int a = threadIdx.x;
  if (t == 0) {
    if (a < 8) sal64[bt * NCAND + grp * 8 + a] = 0.0;
    return;
  }
  __shared__ double sdiff[8][Cc];
  const float* xt = x + ((size_t)bt * (Nn + 1) + 1) * Cc;
  const float* xp = xt - (size_t)(Nn + 1) * Cc;
  for (int g = 0; g < 8; ++g) {
    int n = cand[bt * NCAND + grp * 8 + g];
    const float* rt = xt + (size_t)n * Cc;
    const float* rp = xp + (size_t)n * Cc;
    for (int c = a; c < Cc; c += 192)
      sdiff[g][c] = (double)rt[c] - (double)rp[c];
  }
  __syncthreads();
  double acc[8] = {};
  for (int c = 0; c < Cc; ++c) {
    double wv = (double)wT[(size_t)c * Aa + a];
#pragma unroll
    for (int g = 0; g < 8; ++g) acc[g] = fma(wv, sdiff[g][c], acc[g]);
  }
  __shared__ double part[3][8];
  int wvx = a >> 6, ln = a & 63;
#pragma unroll
  for (int g = 0; g < 8; ++g) {
    double v = fabs(acc[g]);
#pragma unroll
    for (int off = 32; off > 0; off >>= 1) v += __shfl_xor(v, off, 64);
    if (ln == 0) part[wvx][g] = v;
  }
  __syncthreads();
  if (a < 8) {
    double s = part[0][a] + part[1][a] + part[2][a];
    sal64[bt * NCAND + grp * 8 + a] = s * (1.0 / 192.0);
  }
}

// final top-8 (r14 wave-parallel)
__global__ void select_kernel(const double* __restrict__ sal64,
                              const int* __restrict__ cand,
                              int* __restrict__ idx) {
  int bt = blockIdx.x;
  int t = bt & 15;
  int lane = threadIdx.x;
  if (t == 0) {
    if (lane < KK) idx[bt * KK + lane] = lane;
    return;
  }
  double v = (lane < NCAND) ? sal64[bt * NCAND + lane] : -1.0;
  int n = (lane < NCAND) ? cand[bt * NCAND + lane] : 0x7FFFFFFF;
  for (int r = 0; r < KK; ++r) {
    double bv = v;
    int bn = n, bl = lane;
#pragma unroll
    for (int off = 8; off >= 1; off >>= 1) {
      double ov = __shfl_xor(bv, off, 64);
      int on = __shfl_xor(bn, off, 64);
      int ol = __shfl_xor(bl, off, 64);
      if (ov > bv || (ov == bv && on < bn)) { bv = ov; bn = on; bl = ol; }
    }
    if (lane == 0) idx[bt * KK + r] = bn;
    if (lane == bl) v = -1.0;
  }
}

// ============================================================
// anchor attention pieces
// ============================================================
__global__ void gather_kernel(const ushortt* __restrict__ ph,
                              const ushortt* __restrict__ delta,
                              const int* __restrict__ idx,
                              ushortt* __restrict__ tok) {
  int row = blockIdx.x;
  int t = row & 15;
  int bk = row >> 4;
  int b = bk >> 3, k = bk & 7;
  int a = threadIdx.x;
  int n = idx[(b * 16 + t) * KK + k];
  size_t off = ((size_t)(b * 16 + t) * Nn + n) * Aa + a;
  tok[(size_t)row * Aa + a] = f2bf(bf2f(ph[off]) + bf2f(delta[off]));
}

__global__ __launch_bounds__(256) void attn_core(
    const float* __restrict__ qkv, float* __restrict__ o) {
  constexpr int P = 580;
  __shared__ float sq[16 * P];
  __shared__ float ssc[4][16][17];
  int bk = blockIdx.x;
  int tid = threadIdx.x;
  const float* src = qkv + (size_t)bk * 16 * 576;
  for (int e = tid; e < 16 * 144; e += 256) {
    int r = e / 144, c4 = e % 144;
    float4 v = *(const float4*)(src + r * 576 + c4 * 4);
    *(float4*)(&sq[r * P + c4 * 4]) = v;
  }
  __syncthreads();
  int h = tid >> 6, lane = tid & 63;
#pragma unroll
  for (int s4 = 0; s4 < 4; ++s4) {
    int e = lane + 64 * s4;
    int i = e >> 4, j = e & 15;
    const float* q = sq + i * P + h * 48;
    const float* k2 = sq + j * P + 192 + h * 48;
    float s = 0.f;
#pragma unroll
    for (int d = 0; d < 48; ++d) s = fmaf(q[d], k2[d], s);
    ssc[h][i][j] = s * 0.14433756729740643f;
  }
  __syncthreads();
  if (lane < 16) {
    float* r = ssc[h][lane];
    float mx = r[0];
    for (int j = 1; j < 16; ++j) mx = fmaxf(mx, r[j]);
    float sum = 0.f;
    for (int j = 0; j < 16; ++j) {
      float ev = expf(r[j] - mx);
      r[j] = ev;
      sum += ev;
    }
    float inv = 1.0f / sum;
    for (int j = 0; j < 16; ++j) r[j] *= inv;
  }
  __syncthreads();
#pragma unroll
  for (int s4 = 0; s4 < 12; ++s4) {
    int e = lane + 64 * s4;
    int i = e / 48, d = e - i * 48;
    float s = 0.f;
#pragma unroll
    for (int j = 0; j < 16; ++j)
      s = fmaf(ssc[h][i][j], sq[j * P + 384 + h * 48 + d], s);
    o[((size_t)bk * 16 + i) * 192 + h * 48 + d] = s;
  }
}

__global__ void appart_kernel(const float* __restrict__ attout,
                              float* __restrict__ appart) {
  int bk = blockIdx.x;
  int a = threadIdx.x;
  float s = 0.f;
  for (int t = 0; t < Tt; ++t)
    s += attout[((size_t)bk * Tt + t) * Aa + a];
  appart[bk * Aa + a] = s;
}

__global__ void ln32_kernel(float* __restrict__ buf,
                            const float* __restrict__ g,
                            const float* __restrict__ bb) {
  size_t row = (size_t)blockIdx.x * 4 + (threadIdx.x >> 6);
  int lane = threadIdx.x & 63;
  float* p = buf + row * Aa;
  float v0 = p[lane], v1 = p[lane + 64], v2 = p[lane + 128];
  float s = v0 + v1 + v2;
#pragma unroll
  for (int off = 32; off > 0; off >>= 1) s += __shfl_xor(s, off, 64);
  float m = s * (1.0f / 192.0f);
  float d0 = v0 - m, d1 = v1 - m, d2 = v2 - m;
  float ss = d0 * d0 + d1 * d1 + d2 * d2;
#pragma unroll
  for (int off = 32; off > 0; off >>= 1) ss += __shfl_xor(ss, off, 64);
  float inv = rsqrtf(ss * (1.0f / 192.0f) + 1e-5f);
  p[lane] = d0 * inv * g[lane] + bb[lane];
  p[lane + 64] = d1 * inv * g[lane + 64] + bb[lane + 64];
  p[lane + 128] = d2 * inv * g[lane + 128] + bb[lane + 128];
}

// depthwise 3x3 SAME conv + gelu; bf16
__global__ void conv2d_kernel(const ushortt* __restrict__ ph,
                              const float* __restrict__ ldw,
                              ushortt* __restrict__ og) {
  size_t e = (size_t)blockIdx.x * 256 + threadIdx.x;
  int a = (int)(e % Aa);
  size_t r = e / Aa;
  int n = (int)(r % Nn);
  int bt = (int)(r / Nn);
  int y = n / 14, x = n % 14;
  const ushortt* base = ph + (size_t)bt * Nn * Aa + a;
  const float* w = ldw + a * 9;
  float s = 0.f;
#pragma unroll
  for (int dy = -1; dy <= 1; ++dy) {
    int yy = y + dy;
    if (yy < 0 || yy >= 14) continue;
#pragma unroll
    for (int dx = -1; dx <= 1; ++dx) {
      int xc = x + dx;
      if (xc < 0 || xc >= 14) continue;
      s = fmaf(bf2f(base[(size_t)(yy * 14 + xc) * Aa]),
               w[(dy + 1) * 3 + (dx + 1)], s);
    }
  }
  og[e] = f2bf(gelu_f(s));
}

// depthwise k=3 conv over t + gelu; bf16
__global__ void conv1d_kernel(const ushortt* __restrict__ delta,
                              const float* __restrict__ tdw,
                              ushortt* __restrict__ og) {
  size_t e = (size_t)blockIdx.x * 256 + threadIdx.x;
  int a = (int)(e % Aa);
  size_t r = e / Aa;
  int n = (int)(r % Nn);
  int bt = (int)(r / Nn);
  int t = bt & 15, b = bt >> 4;
  const float* w = tdw + a * 3;
  float s = 0.f;
#pragma unroll
  for (int j = 0; j < 3; ++j) {
    int tt = t + j - 1;
    if (tt >= 0 && tt < Tt)
      s = fmaf(bf2f(delta[((size_t)(b * Tt + tt) * Nn + n) * Aa + a]), w[j], s);
  }
  og[e] = f2bf(gelu_f(s));
}

// in-place bf16 LayerNorm; one wave per row
__global__ void ln_kernel(ushortt* __restrict__ buf,
                          const float* __restrict__ g,
                          const float* __restrict__ bb) {
  size_t row = (size_t)blockIdx.x * 4 + (threadIdx.x >> 6);
  int lane = threadIdx.x & 63;
  ushortt* p = buf + row * Aa;
  float v0 = bf2f(p[lane]), v1 = bf2f(p[lane + 64]), v2 = bf2f(p[lane + 128]);
  float s = v0 + v1 + v2;
#pragma unroll
  for (int off = 32; off > 0; off >>= 1) s += __shfl_xor(s, off, 64);
  float m = s * (1.0f / 192.0f);
  float d0 = v0 - m, d1 = v1 - m, d2 = v2 - m;
  float ss = d0 * d0 + d1 * d1 + d2 * d2;
#pragma unroll
  for (int off = 32; off > 0; off >>= 1) ss += __shfl_xor(ss, off, 64);
  float inv = rsqrtf(ss * (1.0f / 192.0f) + 1e-5f);
  p[lane] = f2bf(d0 * inv * g[lane] + bb[lane]);
  p[lane + 64] = f2bf(d1 * inv * g[lane + 64] + bb[lane + 64]);
  p[lane + 128] = f2bf(d2 * inv * g[lane + 128] + bb[lane + 128]);
}

// posmap[bt*Nn + idx[bt,k]] = k+1
__global__ void scatter_pos(const int* __restrict__ idx,
                            short* __restrict__ posmap) {
  int bt = blockIdx.x;
  int k = threadIdx.x;
  if (k < KK) posmap[bt * Nn + idx[bt * KK + k]] = (short)(k + 1);
}

// gate MLP + 3-way softmax; dppart2 has NCH partials per bt
__global__ void gate_kernel(const float* __restrict__ dppart2,
                            const float* __restrict__ appart,
                            const float* __restrict__ w1,
                            const float* __restrict__ b1,
                            const float* __restrict__ w2,
                            const float* __restrict__ b2,
                            float* __restrict__ gw) {
  int b = blockIdx.x;
  __shared__ float sg[2 * Aa];
  __shared__ float sh[Aa];
  int tid = threadIdx.x;
  {
    float d = 0.f;
    for (int t2 = 0; t2 < Tt * NCH; ++t2)
      d += dppart2[(size_t)(b * Tt * NCH + t2) * Aa + tid];
    sg[tid] = d * (1.0f / 3136.0f);
    float a = 0.f;
    for (int k2 = 0; k2 < KK; ++k2) a += appart[(b * KK + k2) * Aa + tid];
    sg[Aa + tid] = a * (1.0f / 128.0f);
  }
  __syncthreads();
  {
    const float* w = w1 + (size_t)tid * 2 * Aa;
    float s = b1[tid];
#pragma unroll 8
    for (int j = 0; j < 2 * Aa; ++j) s = fmaf(sg[j], w[j], s);
    sh[tid] = gelu_f(s);
  }
  __syncthreads();
  float v[3];
#pragma unroll
  for (int i = 0; i < 3; ++i) {
    const float* w = w2 + (size_t)(i * Aa + tid) * Aa;
    float s = b2[i * Aa + tid];
#pragma unroll 8
    for (int j = 0; j < Aa; ++j) s = fmaf(sh[j], w[j], s);
    v[i] = s;
  }
  float mx = fmaxf(v[0], fmaxf(v[1], v[2]));
  float e0 = expf(v[0] - mx), e1 = expf(v[1] - mx), e2 = expf(v[2] - mx);
  float inv = 1.0f / (e0 + e1 + e2);
  gw[(b * 3 + 0) * Aa + tid] = e0 * inv;
  gw[(b * 3 + 1) * Aa + tid] = e1 * inv;
  gw[(b * 3 + 2) * Aa + tid] = e2 * inv;
}

// ============================================================
// fused14 (r17): grid BT*NCH; 14 rows per block; fpart partials
// ============================================================
__global__ __launch_bounds__(192) void fused14_kernel(
    const ushortt* __restrict__ local, const ushortt* __restrict__ trans,
    const float* __restrict__ attln, const short* __restrict__ posmap,
    const float* __restrict__ anb, const float* __restrict__ gw,
    ushortt* __restrict__ fused, float* __restrict__ fpart) {
  int blk = blockIdx.x;
  int bt = blk / NCH, chunk = blk - bt * NCH;
  int b = bt >> 4, t = bt & 15;
  int a = threadIdx.x;
  int n0 = chunk * 14;
  float g0 = gw[(b * 3 + 0) * Aa + a];
  float g1 = gw[(b * 3 + 1) * Aa + a];
  float g2 = gw[(b * 3 + 2) * Aa + a];
  float ab = anb[a];
  size_t base = ((size_t)bt * Nn + n0) * Aa + a;
  float acc = 0.f;
  for (int i = 0; i < 14; ++i) {
    size_t o = base + (size_t)i * Aa;
    short pos = posmap[bt * Nn + n0 + i];
    float am = pos ? attln[(((size_t)(b * KK + pos - 1) * Tt) + t) * Aa + a]
                   : ab;
    float f = g0 * bf2f(local[o]) + g1 * bf2f(trans[o]) + g2 * am;
    fused[o] = f2bf(f);
    acc += f;
  }
  fpart[(size_t)blk * Aa + a] = acc;
}

// cls_out = cls_tok + (mean_n fused) @ cls_w.T + cls_b; fpart NCH partials
__global__ void cls_kernel(const float* __restrict__ fpart,
                           const float* __restrict__ cw,
                           const float* __restrict__ cb,
                           const float* __restrict__ x,
                           float* __restrict__ out) {
  int bt = blockIdx.x;
  __shared__ float fm[Aa];
  int tid = threadIdx.x;
  if (tid < Aa) {
    float s = 0.f;
    for (int ch = 0; ch < NCH; ++ch)
      s += fpart[(size_t)(bt * NCH + ch) * Aa + tid];
    fm[tid] = s * (1.0f / 196.0f);
  }
  __syncthreads();
  for (int c = tid; c < Cc; c += 256) {
    const float* w = cw + (size_t)c * Aa;
    float s = cb[c];
#pragma unroll 8
    for (int a = 0; a < Aa; ++a) s = fmaf(fm[a], w[a], s);
    size_t off = (size_t)bt * (Nn + 1) * Cc + c;
    out[off] = x[off] + s;
  }
}

// ============================================================
extern "C" void kernel_launch(void* const* d_in, const int* in_sizes, int n_in,
                              void* d_out, int out_size, void* d_ws,
                              size_t ws_size, hipStream_t stream) {
  const float* x = (const float*)d_in[0];
  const float* down_w = (const float*)d_in[1];
  const float* down_b = (const float*)d_in[2];
  const float* ldw_w = (const float*)d_in[3];
  const float* lpw_w = (const float*)d_in[4];
  const float* lnorm_g = (const float*)d_in[5];
  const float* lnorm_b = (const float*)d_in[6];
  const float* tdw_w = (const float*)d_in[7];
  const float* tpw_w = (const float*)d_in[8];
  const float* tmlp_w1 = (const float*)d_in[9];
  const float* tmlp_b1 = (const float*)d_in[10];
  const float* tmlp_w2 = (const float*)d_in[11];
  const float* tmlp_b2 = (const float*)d_in[12];
  const float* tnorm_g = (const float*)d_in[13];
  const float* tnorm_b = (const float*)d_in[14];
  const float* attn_in_w = (const float*)d_in[15];
  const float* attn_in_b = (const float*)d_in[16];
  const float* attn_out_w = (const float*)d_in[17];
  const float* attn_out_b = (const float*)d_in[18];
  const float* aproj_w = (const float*)d_in[19];
  const float* aproj_b = (const float*)d_in[20];
  const float* anorm_g = (const float*)d_in[21];
  const float* anorm_b = (const float*)d_in[22];
  const float* gate_w1 = (const float*)d_in[23];
  const float* gate_b1 = (const float*)d_in[24];
  const float* gate_w2 = (const float*)d_in[25];
  const float* gate_b2 = (const float*)d_in[26];
  const float* up_w = (const float*)d_in[27];
  const float* up_b = (const float*)d_in[28];
  const float* cls_w = (const float*)d_in[29];
  const float* cls_b = (const float*)d_in[30];
  float* out = (float*)d_out;

  float* ws = (float*)d_ws;
  float* W0 = ws;              // ph bf16 -> trp bf16
  float* W1 = W0 + SZ;         // delta bf16 -> transition bf16
  float* W2 = W1 + SZ;         // attn scratch -> locg/trg/h1/fused bf16
  float* W3 = W2 + 2 * SZ;     // local bf16
  float* sal = W3 + SZ;
  float* attout = sal + BTN;
  float* dppart2 = attout + (size_t)BKT * Aa;          // BT*NCH*Aa
  float* appart = dppart2 + (size_t)BT * NCH * Aa;
  float* gw = appart + (size_t)Bb * KK * Aa;
  float* fpart = gw + (size_t)Bb * 3 * Aa;             // BT*NCH*Aa
  double* sal64 = (double*)(fpart + (size_t)BT * NCH * Aa);
  int* cand = (int*)(sal64 + (size_t)BT * NCAND);
  int* idx = cand + (size_t)BT * NCAND;
  float* wT = (float*)(idx + (size_t)BT * KK);
  short* posmap = (short*)(wT + (size_t)Cc * Aa);
  ushortt* wbuf = (ushortt*)(posmap + (size_t)BT * Nn);

  // bf16 weight views
  ushortt* wb_down   = wbuf;
  ushortt* wb_attnin = wbuf + O1;
  ushortt* wb_attnout= wbuf + O2;
  ushortt* wb_aproj  = wbuf + O3;
  ushortt* wb_lpw    = wbuf + O4;
  ushortt* wb_tpw    = wbuf + O5;
  ushortt* wb_t1     = wbuf + O6;
  ushortt* wb_t2     = wbuf + O7;
  ushortt* wb_up     = wbuf + O8;

  // bf16 activation views
  ushortt* ph_b    = (ushortt*)W0;
  ushortt* trp_b   = (ushortt*)W0;
  ushortt* delta_b = (ushortt*)W1;
  ushortt* trans_b = (ushortt*)W1;
  ushortt* locg_b  = (ushortt*)W2;
  ushortt* trg_b   = (ushortt*)W2;
  ushortt* h1_b    = (ushortt*)W2;
  ushortt* fused_b = (ushortt*)W2;
  ushortt* local_b = (ushortt*)W3;

  // attn-phase scratch inside W2 (dead until conv2d)
  ushortt* tok_b = (ushortt*)W2;
  float* qkvb  = W2 + (size_t)BKT * Aa / 2;
  float* obuf  = qkvb + (size_t)BKT * 3 * Aa;
  float* proj1 = obuf + (size_t)BKT * Aa;

  // 0. weights -> bf16, wT for refine
  cvtw_kernel<<<OTOT / 256, 256, 0, stream>>>(
      down_w, attn_in_w, attn_out_w, aproj_w, lpw_w, tpw_w, tmlp_w1,
      tmlp_w2, up_w, wbuf);
  transpose_w<<<(Cc * Aa) / 256, 256, 0, stream>>>(down_w, wT);
  // 1. ph = patch @ down_w.T + down_b (hybrid)
  gemm_hyb<1, ushortt, 1, 0><<<dim3(2, 784), 256, 0, stream>>>(
      x, wb_down, down_b, ph_b, nullptr, BTN, Aa, Cc);
  // 2+3a. delta + dp partials + sal (fused, 14-way parallel)
  delta14_kernel<<<BT * NCH, 192, 0, stream>>>(ph_b, delta_b, dppart2, sal);
  // 3b. candidates -> f64 refine -> exact top-8
  topcand_kernel<<<BT, 64, 0, stream>>>(sal, cand);
  refine_kernel<<<dim3(BT, 2), 192, 0, stream>>>(x, wT, cand, sal64);
  select_kernel<<<BT, 64, 0, stream>>>(sal64, cand, idx);
  // 4. anchor attention
  gather_kernel<<<BKT, Aa, 0, stream>>>(ph_b, delta_b, idx, tok_b);
  gemm_lds<float, 1, 0><<<dim3(6, 32), 256, 0, stream>>>(
      tok_b, wb_attnin, attn_in_b, qkvb, nullptr, BKT, 3 * Aa, Aa);
  attn_core<<<Bb * KK, 256, 0, stream>>>(qkvb, obuf);
  gemm_hyb<0, float, 1, 0><<<dim3(2, 32), 256, 0, stream>>>(
      obuf, wb_attnout, attn_out_b, proj1, nullptr, BKT, Aa, Aa);
  gemm_hyb<0, float, 1, 0><<<dim3(2, 32), 256, 0, stream>>>(
      proj1, wb_aproj, aproj_b, attout, nullptr, BKT, Aa, Aa);
  appart_kernel<<<Bb * KK, Aa, 0, stream>>>(attout, appart);
  // 4b. LN the 2048 anchor rows in place
  ln32_kernel<<<BKT / 4, 256, 0, stream>>>(attout, anorm_g, anorm_b);
  hipMemsetAsync(posmap, 0, (size_t)BT * Nn * sizeof(short), stream);
  scatter_pos<<<BT, 64, 0, stream>>>(idx, posmap);
  // 5. local branch
  conv2d_kernel<<<(unsigned)(SZ / 256), 256, 0, stream>>>(ph_b, ldw_w, locg_b);
  gemm_lds<ushortt, 0, 0><<<dim3(2, 784), 256, 0, stream>>>(
      locg_b, wb_lpw, nullptr, local_b, nullptr, BTN, Aa, Aa);
  ln_kernel<<<BTN / 4, 256, 0, stream>>>(local_b, lnorm_g, lnorm_b);
  // 6. transition branch
  conv1d_kernel<<<(unsigned)(SZ / 256), 256, 0, stream>>>(delta_b, tdw_w, trg_b);
  gemm_lds<ushortt, 0, 0><<<dim3(2, 784), 256, 0, stream>>>(
      trg_b, wb_tpw, nullptr, trp_b, nullptr, BTN, Aa, Aa);
  gemm_lds<ushortt, 1, 1><<<dim3(4, 784), 256, 0, stream>>>(
      trp_b, wb_t1, tmlp_b1, h1_b, nullptr, BTN, 2 * Aa, Aa);
  gemm_lds<ushortt, 1, 0><<<dim3(2, 784), 256, 0, stream>>>(
      h1_b, wb_t2, tmlp_b2, trans_b, nullptr, BTN, Aa, 2 * Aa);
  ln_kernel<<<BTN / 4, 256, 0, stream>>>(trans_b, tnorm_g, tnorm_b);
  // 8. gate
  gate_kernel<<<Bb, Aa, 0, stream>>>(dppart2, appart, gate_w1, gate_b1,
                                     gate_w2, gate_b2, gw);
  // 9. fuse (14-way parallel) + output projections
  fused14_kernel<<<BT * NCH, 192, 0, stream>>>(local_b, trans_b, attout,
                                               posmap, anorm_b, gw, fused_b,
                                               fpart);
  gemm_lds<float, 1, 2><<<dim3(8, 784), 256, 0, stream>>>(
      fused_b, wb_up, up_b, out, x, BTN, Cc, Aa);
  cls_kernel<<<BT, 256, 0, stream>>>(fpart, cls_w, cls_b, x, out);
}